// Round 2
// baseline (389.840 us; speedup 1.0000x reference)
//
#include <hip/hip_runtime.h>
#include <hip/hip_bf16.h>
#include <math.h>

typedef __bf16 bf16s;
typedef __attribute__((ext_vector_type(8))) __bf16 bf16x8;
typedef __attribute__((ext_vector_type(4))) __bf16 bf16x4;
typedef __attribute__((ext_vector_type(4))) float f32x4;

#define B_   16
#define S_   1024
#define H_   768
#define T_   64
#define L_   4
#define LE_  32
#define NPAD 4096
#define BS   (B_*S_)    // 16384
#define BNR  (B_*NPAD)  // 65536 rows of X/Y
#define N3   (3*H_)     // 2304

static __device__ __forceinline__ void gload_lds16(const void* g, void* l) {
  __builtin_amdgcn_global_load_lds(
      (const __attribute__((address_space(1))) void*)g,
      (__attribute__((address_space(3))) void*)l, 16, 0, 0);
}

// ---------------- span construction (1 block) ----------------
__global__ __launch_bounds__(1024) void k_build_spans(
    const int* __restrict__ text_mask,   // row 0 used
    int* __restrict__ R, int* __restrict__ pos, int* __restrict__ spoff,
    int* __restrict__ starts, int* __restrict__ ends, int* __restrict__ lens,
    int* __restrict__ meta)
{
  __shared__ int buf[S_];
  int t = threadIdx.x;
  int m = text_mask[t] ? 1 : 0;
  buf[t] = m;
  __syncthreads();
  for (int off = 1; off < S_; off <<= 1) {
    int v = buf[t];
    if (t >= off) v += buf[t - off];
    __syncthreads();
    buf[t] = v;
    __syncthreads();
  }
  int incl = buf[t];
  R[t] = incl;
  if (m) pos[incl - 1] = t;
  int n = buf[S_ - 1];
  __syncthreads();
  int cnt = (t < n) ? min(L_, n - t) : 0;
  buf[t] = cnt;
  __syncthreads();
  for (int off = 1; off < S_; off <<= 1) {
    int v = buf[t];
    if (t >= off) v += buf[t - off];
    __syncthreads();
    buf[t] = v;
    __syncthreads();
  }
  int inc2 = buf[t];
  int base = inc2 - cnt;
  spoff[t] = base;
  if (t == 0) { meta[0] = buf[S_ - 1]; meta[1] = n; }
  __syncthreads();
  if (t < n) {
    int p0 = pos[t];
    for (int k = 0; k < cnt; k++) {
      starts[base + k] = p0;
      ends[base + k]   = pos[t + k];
      lens[base + k]   = k + 1;
    }
  }
}

// ---------------- casts ----------------
__global__ __launch_bounds__(256) void k_cast_bf16(const float* __restrict__ src,
                                                   bf16s* __restrict__ dst, int n4) {
  int i = blockIdx.x * 256 + threadIdx.x;
  if (i >= n4) return;
  f32x4 v = ((const f32x4*)src)[i];
  bf16x4 o;
  o[0] = (__bf16)v[0]; o[1] = (__bf16)v[1]; o[2] = (__bf16)v[2]; o[3] = (__bf16)v[3];
  ((bf16x4*)dst)[i] = o;
}

// out[nn][k] = in[k][nn], 768x768 chunk, f32 -> bf16
__global__ __launch_bounds__(256) void k_transpose_cast(const float* __restrict__ in,
                                                        bf16s* __restrict__ out) {
  __shared__ float tile[64][65];
  int r0 = blockIdx.x * 64, c0 = blockIdx.y * 64;
  int t = threadIdx.x;
  int tr = t >> 4;          // 0..15
  int tc = (t & 15) * 4;    // 0..60
#pragma unroll
  for (int i = 0; i < 4; i++) {
    int row = tr + i * 16;
    f32x4 v = *(const f32x4*)(in + (long)(r0 + row) * H_ + c0 + tc);
    tile[row][tc+0] = v[0]; tile[row][tc+1] = v[1];
    tile[row][tc+2] = v[2]; tile[row][tc+3] = v[3];
  }
  __syncthreads();
#pragma unroll
  for (int i = 0; i < 4; i++) {
    int cc = tr + i * 16;
    bf16x4 o;
    o[0] = (__bf16)tile[tc+0][cc]; o[1] = (__bf16)tile[tc+1][cc];
    o[2] = (__bf16)tile[tc+2][cc]; o[3] = (__bf16)tile[tc+3][cc];
    *(bf16x4*)(out + (long)(c0 + cc) * H_ + r0 + tc) = o;
  }
}

// LT[l][h] = sum_e len_emb[l][e] * W1[N3+e][h]
__global__ __launch_bounds__(256) void k_lt(const float* __restrict__ len_emb,
                                            const float* __restrict__ W1,
                                            float* __restrict__ LT) {
  int idx = blockIdx.x * 256 + threadIdx.x;
  if (idx >= (L_ + 1) * H_) return;
  int l = idx / H_, h = idx % H_;
  float acc = 0.f;
#pragma unroll
  for (int e = 0; e < LE_; e++) acc += len_emb[l * LE_ + e] * W1[(long)(N3 + e) * H_ + h];
  LT[idx] = acc;
}

// ---------------- GEMM: C(MxN) = A(MxK) * Bt(NxK)^T, bf16 in/out, f32 acc ----
__global__ __launch_bounds__(256) void k_gemm_bt(
    const bf16s* __restrict__ A, const bf16s* __restrict__ Bt,
    bf16s* __restrict__ C, const float* __restrict__ bias,
    int M, int N, int K)
{
  __shared__ bf16s sA[128 * 32];
  __shared__ bf16s sB[128 * 32];
  int tid = threadIdx.x;
  int wid = tid >> 6, l = tid & 63;
  long a0 = (long)blockIdx.x * 128;
  long b0 = (long)blockIdx.y * 128;
  int wr = wid >> 1, wc = wid & 1;
  f32x4 acc[4][4];
#pragma unroll
  for (int i = 0; i < 4; i++)
#pragma unroll
    for (int j = 0; j < 4; j++) acc[i][j] = (f32x4){0.f, 0.f, 0.f, 0.f};

  int srow = l >> 2, skc = (l & 3) * 8;
  for (int k0 = 0; k0 < K; k0 += 32) {
#pragma unroll
    for (int c = wid; c < 8; c += 4) {
      gload_lds16(A  + (a0 + c * 16 + srow) * K + k0 + skc, sA + c * 512);
      gload_lds16(Bt + (b0 + c * 16 + srow) * K + k0 + skc, sB + c * 512);
    }
    __syncthreads();
    bf16x8 af[4], bfv[4];
#pragma unroll
    for (int i = 0; i < 4; i++) {
      af[i]  = *(const bf16x8*)(sA + (wr * 64 + i * 16 + (l & 15)) * 32 + (l >> 4) * 8);
      bfv[i] = *(const bf16x8*)(sB + (wc * 64 + i * 16 + (l & 15)) * 32 + (l >> 4) * 8);
    }
#pragma unroll
    for (int i = 0; i < 4; i++)
#pragma unroll
      for (int j = 0; j < 4; j++)
        acc[i][j] = __builtin_amdgcn_mfma_f32_16x16x32_bf16(af[i], bfv[j], acc[i][j], 0, 0, 0);
    __syncthreads();
  }
#pragma unroll
  for (int i = 0; i < 4; i++) {
    int row = wr * 64 + i * 16 + (l >> 4) * 4;
#pragma unroll
    for (int j = 0; j < 4; j++) {
      int col = wc * 64 + j * 16 + (l & 15);
      float bv = bias ? bias[b0 + col] : 0.f;
#pragma unroll
      for (int r = 0; r < 4; r++)
        C[(a0 + row + r) * N + b0 + col] = (__bf16)(acc[i][j][r] + bv);
    }
  }
}

// ---------------- z1 assemble + GELU -> X (mean computed directly, len<=4) ---
__global__ __launch_bounds__(256) void k_z1(
    const bf16s* __restrict__ P,
    const float* __restrict__ LT, const float* __restrict__ b1,
    const int* __restrict__ starts, const int* __restrict__ ends,
    const int* __restrict__ lens, const int* __restrict__ meta,
    bf16s* __restrict__ X)
{
  int idx = blockIdx.x * 256 + threadIdx.x;  // B*NPAD*(H/4)
  int h4 = idx % (H_ / 4); int rest = idx / (H_ / 4);
  int nid = rest % NPAD; int b = rest / NPAD;
  int h = h4 * 4;
  int N = meta[0];
  long orow = (long)(b * NPAD + nid) * H_ + h;
  if (nid >= N) {
    bf16x4 z; z[0] = z[1] = z[2] = z[3] = (__bf16)0.f;
    *(bf16x4*)(X + orow) = z;
    return;
  }
  int sa = starts[nid], se = ends[nid], ln = lens[nid];
  float il = 1.0f / (float)ln;
  bf16x4 vs = *(const bf16x4*)(P + (long)(b * S_ + sa) * N3 + h);
  bf16x4 ve = *(const bf16x4*)(P + (long)(b * S_ + se) * N3 + H_ + h);
  float mv[4] = {0.f, 0.f, 0.f, 0.f};
  for (int i = sa; i <= se; i++) {
    bf16x4 vc = *(const bf16x4*)(P + (long)(b * S_ + i) * N3 + 2 * H_ + h);
#pragma unroll
    for (int j = 0; j < 4; j++) mv[j] += (float)vc[j];
  }
  f32x4 lt = *(const f32x4*)(LT + (long)ln * H_ + h);
  f32x4 bb = *(const f32x4*)(b1 + h);
  bf16x4 o;
#pragma unroll
  for (int j = 0; j < 4; j++) {
    float x = (float)vs[j] + (float)ve[j] + mv[j] * il + lt[j] + bb[j];
    float g = 0.5f * x * (1.0f + erff(x * 0.70710678118654752f));
    o[j] = (__bf16)g;
  }
  *(bf16x4*)(X + orow) = o;
}

// ---------------- per-row inverse norms of Y ----------------
__global__ __launch_bounds__(256) void k_rnorm(const bf16s* __restrict__ Y,
                                               float* __restrict__ rnorm) {
  int gtid = blockIdx.x * 256 + threadIdx.x;
  int w = gtid >> 6;  // row
  int l = threadIdx.x & 63;
  const bf16s* row = Y + (long)w * H_;
  float s = 0.f;
  for (int i = l; i < H_ / 8; i += 64) {
    bf16x8 v = *(const bf16x8*)(row + i * 8);
#pragma unroll
    for (int j = 0; j < 8; j++) { float f = (float)v[j]; s += f * f; }
  }
#pragma unroll
  for (int off = 32; off; off >>= 1) s += __shfl_xor(s, off);
  if (l == 0) rnorm[w] = 1.0f / fmaxf(sqrtf(s), 1e-12f);
}

// ---------------- normalize topics -> bf16 ----------------
__global__ __launch_bounds__(256) void k_topicn(const float* __restrict__ TH,
                                                bf16s* __restrict__ TN) {
  __shared__ float red[256];
  int r = blockIdx.x; int t = threadIdx.x;
  const float* row = TH + (long)r * H_;
  float v0 = row[t], v1 = row[t + 256], v2 = row[t + 512];
  red[t] = v0 * v0 + v1 * v1 + v2 * v2;
  __syncthreads();
  for (int off = 128; off; off >>= 1) {
    if (t < off) red[t] += red[t + off];
    __syncthreads();
  }
  float rn = 1.0f / fmaxf(sqrtf(red[0]), 1e-12f);
  bf16s* o = TN + (long)r * H_;
  o[t] = (__bf16)(v0 * rn); o[t + 256] = (__bf16)(v1 * rn); o[t + 512] = (__bf16)(v2 * rn);
}

// ---------------- sim (span x topic) + max over topics ----------------
__global__ __launch_bounds__(256) void k_sim(
    const bf16s* __restrict__ Y, const bf16s* __restrict__ TN,
    const float* __restrict__ rnorm, const int* __restrict__ tmask,
    float* __restrict__ scores)
{
  int b = blockIdx.y;
  int wid = threadIdx.x >> 6, l = threadIdx.x & 63;
  int st = blockIdx.x * 4 + wid;
  int span = st * 16 + (l & 15);
  const bf16s* yrow = Y + (long)(b * NPAD + span) * H_ + (l >> 4) * 8;
  const bf16s* tbase = TN + (long)b * T_ * H_ + (l >> 4) * 8;
  f32x4 acc[4];
#pragma unroll
  for (int tt = 0; tt < 4; tt++) acc[tt] = (f32x4){0.f, 0.f, 0.f, 0.f};
  for (int kk = 0; kk < H_ / 32; kk++) {
    bf16x8 av = *(const bf16x8*)(yrow + kk * 32);
#pragma unroll
    for (int tt = 0; tt < 4; tt++) {
      bf16x8 bv = *(const bf16x8*)(tbase + (long)(tt * 16 + (l & 15)) * H_ + kk * 32);
      acc[tt] = __builtin_amdgcn_mfma_f32_16x16x32_bf16(av, bv, acc[tt], 0, 0, 0);
    }
  }
  const int* tm = tmask + b * T_;
  bool msk[4];
#pragma unroll
  for (int tt = 0; tt < 4; tt++) msk[tt] = tm[tt * 16 + (l & 15)] != 0;
  float best[4];
#pragma unroll
  for (int r = 0; r < 4; r++) {
    float v = -INFINITY;
#pragma unroll
    for (int tt = 0; tt < 4; tt++) if (msk[tt]) v = fmaxf(v, acc[tt][r]);
    best[r] = v;
  }
#pragma unroll
  for (int off = 8; off; off >>= 1)
#pragma unroll
    for (int r = 0; r < 4; r++) best[r] = fmaxf(best[r], __shfl_xor(best[r], off));
  if ((l & 15) == 0) {
    int srow = st * 16 + (l >> 4) * 4;
#pragma unroll
    for (int r = 0; r < 4; r++)
      scores[b * NPAD + srow + r] = best[r] * rnorm[b * NPAD + srow + r];
  }
}

// ---------------- token max ----------------
__global__ __launch_bounds__(256) void k_token(
    const int* __restrict__ text_mask,
    const int* __restrict__ R, const int* __restrict__ spoff,
    const int* __restrict__ meta, const float* __restrict__ scores,
    float* __restrict__ out)
{
  int idx = blockIdx.x * 256 + threadIdx.x;  // B*S
  int s = idx % S_, b = idx / S_;
  if (!text_mask[b * S_ + s]) { out[idx] = -INFINITY; return; }
  int n = meta[1];
  int r1 = R[s];
  int le = r1 - 1;                         // largest i with pos[i] <= s
  int ge = text_mask[s] ? (r1 - 1) : r1;   // smallest j with pos[j] >= s (row 0)
  float best = -INFINITY;
  if (le >= 0 && ge < n) {
    int i0 = max(0, ge - (L_ - 1));
    for (int i = i0; i <= le; i++) {
      int jmax = min(i + L_ - 1, n - 1);
      int off = spoff[i];
      for (int j = max(i, ge); j <= jmax; j++)
        best = fmaxf(best, scores[b * NPAD + off + (j - i)]);
    }
  }
  out[idx] = best;
}

// ---------------- ws-too-small sentinel ----------------
__global__ __launch_bounds__(256) void k_sentinel(float* __restrict__ out) {
  int i = blockIdx.x * 256 + threadIdx.x;
  if (i < BS) out[i] = 12345.0f;
}

// ---------------- launch ----------------
extern "C" void kernel_launch(void* const* d_in, const int* in_sizes, int n_in,
                              void* d_out, int out_size, void* d_ws, size_t ws_size,
                              hipStream_t stream) {
  const float* hid = (const float*)d_in[0];
  const float* th  = (const float*)d_in[1];
  const int* tmask = (const int*)d_in[2];
  const int* xmask = (const int*)d_in[3];
  const float* lemb = (const float*)d_in[4];
  const float* W1   = (const float*)d_in[5];
  const float* b1   = (const float*)d_in[6];
  const float* W2   = (const float*)d_in[7];
  const float* b2   = (const float*)d_in[8];
  float* out = (float*)d_out;

  char* w = (char*)d_ws;
  auto alloc = [&](size_t bytes) {
    char* p = w; w += (bytes + 255) & ~(size_t)255; return p;
  };
  // small buffers (~7 MB)
  bf16s* wbt   = (bf16s*)alloc((size_t)N3 * H_ * 2);
  bf16s* w2t   = (bf16s*)alloc((size_t)H_ * H_ * 2);
  float* LT    = (float*)alloc((size_t)(L_ + 1) * H_ * 4);
  bf16s* topn  = (bf16s*)alloc((size_t)B_ * T_ * H_ * 2);
  float* rnorm = (float*)alloc((size_t)BNR * 4);
  float* scores= (float*)alloc((size_t)B_ * NPAD * 4);
  int* R       = (int*)alloc(S_ * 4);
  int* pos     = (int*)alloc(S_ * 4);
  int* spoff   = (int*)alloc(S_ * 4);
  int* starts  = (int*)alloc(NPAD * 4);
  int* ends    = (int*)alloc(NPAD * 4);
  int* lens    = (int*)alloc(NPAD * 4);
  int* meta    = (int*)alloc(2 * 4);
  // region A: [hidb | P] (100.66 MB), later aliased by Y (100.66 MB)
  char* regionA = alloc((size_t)BS * H_ * 2 + (size_t)BS * N3 * 2);
  bf16s* hidb  = (bf16s*)regionA;
  bf16s* P     = (bf16s*)(regionA + (size_t)BS * H_ * 2);
  bf16s* Y     = (bf16s*)regionA;   // alias: valid after hidb & P are dead
  // region B: X (100.66 MB)
  bf16s* X     = (bf16s*)alloc((size_t)BNR * H_ * 2);

  size_t required = (size_t)(w - (char*)d_ws);
  if (required > ws_size) {
    k_sentinel<<<(BS + 255) / 256, 256, 0, stream>>>(out);
    return;
  }

  k_build_spans<<<1, 1024, 0, stream>>>(xmask, R, pos, spoff, starts, ends, lens, meta);
  k_cast_bf16<<<(BS * H_ / 4 + 255) / 256, 256, 0, stream>>>(hid, hidb, BS * H_ / 4);
  for (int c = 0; c < 3; c++)
    k_transpose_cast<<<dim3(12, 12), 256, 0, stream>>>(W1 + (size_t)c * H_ * H_, wbt + (size_t)c * H_ * H_);
  k_transpose_cast<<<dim3(12, 12), 256, 0, stream>>>(W2, w2t);
  k_lt<<<((L_ + 1) * H_ + 255) / 256, 256, 0, stream>>>(lemb, W1, LT);

  k_gemm_bt<<<dim3(BS / 128, N3 / 128), 256, 0, stream>>>(hidb, wbt, P, nullptr, BS, N3, H_);

  k_z1<<<(B_ * NPAD * (H_ / 4)) / 256, 256, 0, stream>>>(P, LT, b1, starts, ends, lens, meta, X);

  k_gemm_bt<<<dim3(BNR / 128, H_ / 128), 256, 0, stream>>>(X, w2t, Y, b2, BNR, H_, H_);

  k_rnorm<<<BNR / 4, 256, 0, stream>>>(Y, rnorm);
  k_topicn<<<B_ * T_, 256, 0, stream>>>(th, topn);
  k_sim<<<dim3(NPAD / 64, B_), 256, 0, stream>>>(Y, topn, rnorm, tmask, scores);
  k_token<<<(B_ * S_) / 256, 256, 0, stream>>>(xmask, R, spoff, meta, scores, out);
  (void)in_sizes; (void)n_in; (void)out_size;
}

// Round 3
// 387.788 us; speedup vs baseline: 1.0053x; 1.0053x over previous
//
#include <hip/hip_runtime.h>
#include <hip/hip_bf16.h>
#include <math.h>

typedef __bf16 bf16s;
typedef __attribute__((ext_vector_type(8))) __bf16 bf16x8;
typedef __attribute__((ext_vector_type(4))) __bf16 bf16x4;
typedef __attribute__((ext_vector_type(4))) float f32x4;

#define B_   16
#define S_   1024
#define H_   768
#define T_   64
#define L_   4
#define LE_  32
#define NPAD 4096
#define BS   (B_*S_)    // 16384
#define BNR  (B_*NPAD)  // 65536 rows of X/Y
#define N3   (3*H_)     // 2304

static __device__ __forceinline__ void gload_lds16(const void* g, void* l) {
  __builtin_amdgcn_global_load_lds(
      (const __attribute__((address_space(1))) void*)g,
      (__attribute__((address_space(3))) void*)l, 16, 0, 0);
}

// ---------------- span construction (1 block) ----------------
__global__ __launch_bounds__(1024) void k_build_spans(
    const int* __restrict__ text_mask,   // row 0 used
    int* __restrict__ R, int* __restrict__ pos, int* __restrict__ spoff,
    int* __restrict__ starts, int* __restrict__ ends, int* __restrict__ lens,
    int* __restrict__ meta)
{
  __shared__ int buf[S_];
  int t = threadIdx.x;
  int m = text_mask[t] ? 1 : 0;
  buf[t] = m;
  __syncthreads();
  for (int off = 1; off < S_; off <<= 1) {
    int v = buf[t];
    if (t >= off) v += buf[t - off];
    __syncthreads();
    buf[t] = v;
    __syncthreads();
  }
  int incl = buf[t];
  R[t] = incl;
  if (m) pos[incl - 1] = t;
  int n = buf[S_ - 1];
  __syncthreads();
  int cnt = (t < n) ? min(L_, n - t) : 0;
  buf[t] = cnt;
  __syncthreads();
  for (int off = 1; off < S_; off <<= 1) {
    int v = buf[t];
    if (t >= off) v += buf[t - off];
    __syncthreads();
    buf[t] = v;
    __syncthreads();
  }
  int inc2 = buf[t];
  int base = inc2 - cnt;
  spoff[t] = base;
  if (t == 0) { meta[0] = buf[S_ - 1]; meta[1] = n; }
  __syncthreads();
  if (t < n) {
    int p0 = pos[t];
    for (int k = 0; k < cnt; k++) {
      starts[base + k] = p0;
      ends[base + k]   = pos[t + k];
      lens[base + k]   = k + 1;
    }
  }
}

// ---------------- casts ----------------
__global__ __launch_bounds__(256) void k_cast_bf16(const float* __restrict__ src,
                                                   bf16s* __restrict__ dst, int n4) {
  int i = blockIdx.x * 256 + threadIdx.x;
  if (i >= n4) return;
  f32x4 v = ((const f32x4*)src)[i];
  bf16x4 o;
  o[0] = (__bf16)v[0]; o[1] = (__bf16)v[1]; o[2] = (__bf16)v[2]; o[3] = (__bf16)v[3];
  ((bf16x4*)dst)[i] = o;
}

// out[nn][k] = in[k][nn], 768x768 chunk, f32 -> bf16
__global__ __launch_bounds__(256) void k_transpose_cast(const float* __restrict__ in,
                                                        bf16s* __restrict__ out) {
  __shared__ float tile[64][65];
  int r0 = blockIdx.x * 64, c0 = blockIdx.y * 64;
  int t = threadIdx.x;
  int tr = t >> 4;          // 0..15
  int tc = (t & 15) * 4;    // 0..60
#pragma unroll
  for (int i = 0; i < 4; i++) {
    int row = tr + i * 16;
    f32x4 v = *(const f32x4*)(in + (long)(r0 + row) * H_ + c0 + tc);
    tile[row][tc+0] = v[0]; tile[row][tc+1] = v[1];
    tile[row][tc+2] = v[2]; tile[row][tc+3] = v[3];
  }
  __syncthreads();
#pragma unroll
  for (int i = 0; i < 4; i++) {
    int cc = tr + i * 16;
    bf16x4 o;
    o[0] = (__bf16)tile[tc+0][cc]; o[1] = (__bf16)tile[tc+1][cc];
    o[2] = (__bf16)tile[tc+2][cc]; o[3] = (__bf16)tile[tc+3][cc];
    *(bf16x4*)(out + (long)(c0 + cc) * H_ + r0 + tc) = o;
  }
}

// LT[l][h] = sum_e len_emb[l][e] * W1[N3+e][h]
__global__ __launch_bounds__(256) void k_lt(const float* __restrict__ len_emb,
                                            const float* __restrict__ W1,
                                            float* __restrict__ LT) {
  int idx = blockIdx.x * 256 + threadIdx.x;
  if (idx >= (L_ + 1) * H_) return;
  int l = idx / H_, h = idx % H_;
  float acc = 0.f;
#pragma unroll
  for (int e = 0; e < LE_; e++) acc += len_emb[l * LE_ + e] * W1[(long)(N3 + e) * H_ + h];
  LT[idx] = acc;
}

// ====== 256x256 GEMM, BK=32, 4-buffer counted-vmcnt pipeline ======
// C(MxN) = A(MxK) * Bt(NxK)^T (+bias), bf16 in/out, f32 acc.
// LDS layout per tile: [256 rows][4 x 16B slots], slot swizzled s' = s ^ (row&3).
// Staged via global_load_lds with inverse-swizzled global source (both-sides rule).
#define BMT 256
#define BKT 32
__global__ __launch_bounds__(512, 2) void k_gemm256(
    const bf16s* __restrict__ A, const bf16s* __restrict__ Bt,
    bf16s* __restrict__ C, const float* __restrict__ bias,
    int M, int N, int K, int NTN)
{
  __shared__ __align__(16) bf16s sA[4 * BMT * BKT];   // 64 KB
  __shared__ __align__(16) bf16s sB[4 * BMT * BKT];   // 64 KB
  char* sAc = (char*)sA;
  char* sBc = (char*)sB;

  // XCD-chunked bijective swizzle: each XCD gets contiguous block ids.
  int nwg = gridDim.x;
  int bid = blockIdx.x;
  int q = nwg >> 3, rr = nwg & 7;
  int xcd = bid & 7, idx = bid >> 3;
  int nid = (xcd < rr ? xcd * (q + 1) : rr * (q + 1) + (xcd - rr) * q) + idx;
  long a0 = (long)(nid / NTN) * BMT;
  long b0 = (long)(nid % NTN) * BMT;

  int tid = threadIdx.x;
  int wid = tid >> 6, l = tid & 63;
  int wr = wid >> 2, wc = wid & 3;     // 2 x 4 waves; wave tile 128x64
  int NT = K / BKT;

  // staging: round covers 128 rows; thread t -> row (t>>2), stored slot (t&3),
  // which holds logical slot (t&3) ^ (row&3)
  int srow = tid >> 2;
  int sslot = (tid & 3) ^ (srow & 3);
  const bf16s* gA = A + (a0 + srow) * (long)K + sslot * 8;
  const bf16s* gB = Bt + (b0 + srow) * (long)K + sslot * 8;

#define STAGE_A(kt_, bb_) do { \
    long ko_ = (long)(kt_) * BKT; \
    gload_lds16(gA + ko_,               sAc + (bb_) * 16384 + wid * 1024); \
    gload_lds16(gA + ko_ + 128L * K,    sAc + (bb_) * 16384 + 8192 + wid * 1024); \
  } while (0)
#define STAGE_B(kt_, bb_) do { \
    long ko_ = (long)(kt_) * BKT; \
    gload_lds16(gB + ko_,               sBc + (bb_) * 16384 + wid * 1024); \
    gload_lds16(gB + ko_ + 128L * K,    sBc + (bb_) * 16384 + 8192 + wid * 1024); \
  } while (0)

  // fragment read offsets (swizzled): logical slot (l>>4) at row r stored at (l>>4)^(r&3); r&3 == l&3
  int aoff = (wr * 128 + (l & 15)) * 64 + (((l >> 4) ^ (l & 3)) * 16);
  int boff = (wc * 64 + (l & 15)) * 64 + (((l >> 4) ^ (l & 3)) * 16);

  f32x4 acc[8][4];
#pragma unroll
  for (int i = 0; i < 8; i++)
#pragma unroll
    for (int j = 0; j < 4; j++) acc[i][j] = (f32x4){0.f, 0.f, 0.f, 0.f};

  // prologue: stage tiles 0,1,2 into bufs 0,1,2 (12 loads/thread)
  STAGE_A(0, 0); STAGE_B(0, 0);
  STAGE_A(1, 1); STAGE_B(1, 1);
  STAGE_A(2, 2); STAGE_B(2, 2);
  asm volatile("s_waitcnt vmcnt(8)" ::: "memory");   // tile 0 landed
  __builtin_amdgcn_s_barrier();

  for (int kt = 0; kt < NT; ++kt) {
    int b = kt & 3;
    const char* bufA = sAc + b * 16384;
    const char* bufB = sBc + b * 16384;
    // ---- phase 0: read A frags + B frags 0,1; stage A of kt+3 ----
    bf16x8 af[8];
#pragma unroll
    for (int fr = 0; fr < 8; fr++)
      af[fr] = *(const bf16x8*)(bufA + aoff + fr * 1024);
    bf16x8 bf0 = *(const bf16x8*)(bufB + boff);
    bf16x8 bf1 = *(const bf16x8*)(bufB + boff + 1024);
    if (kt + 3 < NT) STAGE_A(kt + 3, (kt + 3) & 3);
    __builtin_amdgcn_s_barrier();
    asm volatile("s_waitcnt lgkmcnt(0)" ::: "memory");
    __builtin_amdgcn_s_setprio(1);
#pragma unroll
    for (int fr = 0; fr < 8; fr++)
      acc[fr][0] = __builtin_amdgcn_mfma_f32_16x16x32_bf16(bf0, af[fr], acc[fr][0], 0, 0, 0);
#pragma unroll
    for (int fr = 0; fr < 8; fr++)
      acc[fr][1] = __builtin_amdgcn_mfma_f32_16x16x32_bf16(bf1, af[fr], acc[fr][1], 0, 0, 0);
    __builtin_amdgcn_s_setprio(0);
    __builtin_amdgcn_s_barrier();
    // ---- phase 1: read B frags 2,3; stage B of kt+3; counted vmcnt ----
    bf16x8 bf2 = *(const bf16x8*)(bufB + boff + 2048);
    bf16x8 bf3 = *(const bf16x8*)(bufB + boff + 3072);
    if (kt + 3 < NT) STAGE_B(kt + 3, (kt + 3) & 3);
    if (kt < NT - 3)      { asm volatile("s_waitcnt vmcnt(8)" ::: "memory"); }
    else if (kt == NT - 3){ asm volatile("s_waitcnt vmcnt(4)" ::: "memory"); }
    else                  { asm volatile("s_waitcnt vmcnt(0)" ::: "memory"); }
    __builtin_amdgcn_s_barrier();
    asm volatile("s_waitcnt lgkmcnt(0)" ::: "memory");
    __builtin_amdgcn_s_setprio(1);
#pragma unroll
    for (int fr = 0; fr < 8; fr++)
      acc[fr][2] = __builtin_amdgcn_mfma_f32_16x16x32_bf16(bf2, af[fr], acc[fr][2], 0, 0, 0);
#pragma unroll
    for (int fr = 0; fr < 8; fr++)
      acc[fr][3] = __builtin_amdgcn_mfma_f32_16x16x32_bf16(bf3, af[fr], acc[fr][3], 0, 0, 0);
    __builtin_amdgcn_s_setprio(0);
    __builtin_amdgcn_s_barrier();
  }

  // epilogue: lane l holds C[m = a0+wr*128+fr*16+(l&15)][n0..n0+3], n0 = b0+wc*64+fc*16+(l>>4)*4
#pragma unroll
  for (int fc = 0; fc < 4; fc++) {
    long n0 = b0 + wc * 64 + fc * 16 + (l >> 4) * 4;
    f32x4 bb;
    if (bias) bb = *(const f32x4*)(bias + n0);
    else      bb = (f32x4){0.f, 0.f, 0.f, 0.f};
#pragma unroll
    for (int fr = 0; fr < 8; fr++) {
      long mrow = a0 + wr * 128 + fr * 16 + (l & 15);
      bf16x4 o;
#pragma unroll
      for (int r = 0; r < 4; r++) o[r] = (__bf16)(acc[fr][fc][r] + bb[r]);
      *(bf16x4*)(C + mrow * (long)N + n0) = o;
    }
  }
#undef STAGE_A
#undef STAGE_B
}

// ---------------- z1 assemble + GELU -> X (mean computed directly, len<=4) ---
__global__ __launch_bounds__(256) void k_z1(
    const bf16s* __restrict__ P,
    const float* __restrict__ LT, const float* __restrict__ b1,
    const int* __restrict__ starts, const int* __restrict__ ends,
    const int* __restrict__ lens, const int* __restrict__ meta,
    bf16s* __restrict__ X)
{
  int idx = blockIdx.x * 256 + threadIdx.x;  // B*NPAD*(H/4)
  int h4 = idx % (H_ / 4); int rest = idx / (H_ / 4);
  int nid = rest % NPAD; int b = rest / NPAD;
  int h = h4 * 4;
  int N = meta[0];
  long orow = (long)(b * NPAD + nid) * H_ + h;
  if (nid >= N) {
    bf16x4 z; z[0] = z[1] = z[2] = z[3] = (__bf16)0.f;
    *(bf16x4*)(X + orow) = z;
    return;
  }
  int sa = starts[nid], se = ends[nid], ln = lens[nid];
  float il = 1.0f / (float)ln;
  bf16x4 vs = *(const bf16x4*)(P + (long)(b * S_ + sa) * N3 + h);
  bf16x4 ve = *(const bf16x4*)(P + (long)(b * S_ + se) * N3 + H_ + h);
  float mv[4] = {0.f, 0.f, 0.f, 0.f};
  for (int i = sa; i <= se; i++) {
    bf16x4 vc = *(const bf16x4*)(P + (long)(b * S_ + i) * N3 + 2 * H_ + h);
#pragma unroll
    for (int j = 0; j < 4; j++) mv[j] += (float)vc[j];
  }
  f32x4 lt = *(const f32x4*)(LT + (long)ln * H_ + h);
  f32x4 bb = *(const f32x4*)(b1 + h);
  bf16x4 o;
#pragma unroll
  for (int j = 0; j < 4; j++) {
    float x = (float)vs[j] + (float)ve[j] + mv[j] * il + lt[j] + bb[j];
    float g = 0.5f * x * (1.0f + erff(x * 0.70710678118654752f));
    o[j] = (__bf16)g;
  }
  *(bf16x4*)(X + orow) = o;
}

// ---------------- normalize topics -> bf16 ----------------
__global__ __launch_bounds__(256) void k_topicn(const float* __restrict__ TH,
                                                bf16s* __restrict__ TN) {
  __shared__ float red[256];
  int r = blockIdx.x; int t = threadIdx.x;
  const float* row = TH + (long)r * H_;
  float v0 = row[t], v1 = row[t + 256], v2 = row[t + 512];
  red[t] = v0 * v0 + v1 * v1 + v2 * v2;
  __syncthreads();
  for (int off = 128; off; off >>= 1) {
    if (t < off) red[t] += red[t + off];
    __syncthreads();
  }
  float rn = 1.0f / fmaxf(sqrtf(red[0]), 1e-12f);
  bf16s* o = TN + (long)r * H_;
  o[t] = (__bf16)(v0 * rn); o[t + 256] = (__bf16)(v1 * rn); o[t + 512] = (__bf16)(v2 * rn);
}

// ------- sim (span x topic) + max over topics, with fused span rnorm -------
__global__ __launch_bounds__(256) void k_sim(
    const bf16s* __restrict__ Y, const bf16s* __restrict__ TN,
    const int* __restrict__ tmask, float* __restrict__ scores)
{
  int b = blockIdx.y;
  int wid = threadIdx.x >> 6, l = threadIdx.x & 63;
  int st = blockIdx.x * 4 + wid;
  int span = st * 16 + (l & 15);
  const bf16s* yrow = Y + (long)(b * NPAD + span) * H_ + (l >> 4) * 8;
  const bf16s* tbase = TN + (long)b * T_ * H_ + (l >> 4) * 8;
  f32x4 acc[4];
#pragma unroll
  for (int tt = 0; tt < 4; tt++) acc[tt] = (f32x4){0.f, 0.f, 0.f, 0.f};
  float ss = 0.f;
  for (int kk = 0; kk < H_ / 32; kk++) {
    bf16x8 av = *(const bf16x8*)(yrow + kk * 32);
#pragma unroll
    for (int j = 0; j < 8; j++) { float f = (float)av[j]; ss += f * f; }
#pragma unroll
    for (int tt = 0; tt < 4; tt++) {
      bf16x8 bv = *(const bf16x8*)(tbase + (long)(tt * 16 + (l & 15)) * H_ + kk * 32);
      acc[tt] = __builtin_amdgcn_mfma_f32_16x16x32_bf16(av, bv, acc[tt], 0, 0, 0);
    }
  }
  // full-row sumsq for span st*16+(l&15): combine the 4 k-groups
  ss += __shfl_xor(ss, 16);
  ss += __shfl_xor(ss, 32);
  float invn = 1.0f / fmaxf(sqrtf(ss), 1e-12f);
  const int* tm = tmask + b * T_;
  bool msk[4];
#pragma unroll
  for (int tt = 0; tt < 4; tt++) msk[tt] = tm[tt * 16 + (l & 15)] != 0;
  float best[4];
#pragma unroll
  for (int r = 0; r < 4; r++) {
    float v = -INFINITY;
#pragma unroll
    for (int tt = 0; tt < 4; tt++) if (msk[tt]) v = fmaxf(v, acc[tt][r]);
    best[r] = v;
  }
#pragma unroll
  for (int off = 8; off; off >>= 1)
#pragma unroll
    for (int r = 0; r < 4; r++) best[r] = fmaxf(best[r], __shfl_xor(best[r], off));
  // rnorm for output rows (l>>4)*4+r lives on lane ((l>>4)*4+r) of this wave's group 0..15
  float rr[4];
#pragma unroll
  for (int r = 0; r < 4; r++) rr[r] = __shfl(invn, (l >> 4) * 4 + r);
  if ((l & 15) == 0) {
    int srow = st * 16 + (l >> 4) * 4;
#pragma unroll
    for (int r = 0; r < 4; r++)
      scores[b * NPAD + srow + r] = best[r] * rr[r];
  }
}

// ---------------- token max ----------------
__global__ __launch_bounds__(256) void k_token(
    const int* __restrict__ text_mask,
    const int* __restrict__ R, const int* __restrict__ spoff,
    const int* __restrict__ meta, const float* __restrict__ scores,
    float* __restrict__ out)
{
  int idx = blockIdx.x * 256 + threadIdx.x;  // B*S
  int s = idx % S_, b = idx / S_;
  if (!text_mask[b * S_ + s]) { out[idx] = -INFINITY; return; }
  int n = meta[1];
  int r1 = R[s];
  int le = r1 - 1;                         // largest i with pos[i] <= s
  int ge = text_mask[s] ? (r1 - 1) : r1;   // smallest j with pos[j] >= s (row 0)
  float best = -INFINITY;
  if (le >= 0 && ge < n) {
    int i0 = max(0, ge - (L_ - 1));
    for (int i = i0; i <= le; i++) {
      int jmax = min(i + L_ - 1, n - 1);
      int off = spoff[i];
      for (int j = max(i, ge); j <= jmax; j++)
        best = fmaxf(best, scores[b * NPAD + off + (j - i)]);
    }
  }
  out[idx] = best;
}

// ---------------- ws-too-small sentinel ----------------
__global__ __launch_bounds__(256) void k_sentinel(float* __restrict__ out) {
  int i = blockIdx.x * 256 + threadIdx.x;
  if (i < BS) out[i] = 12345.0f;
}

// ---------------- launch ----------------
extern "C" void kernel_launch(void* const* d_in, const int* in_sizes, int n_in,
                              void* d_out, int out_size, void* d_ws, size_t ws_size,
                              hipStream_t stream) {
  const float* hid = (const float*)d_in[0];
  const float* th  = (const float*)d_in[1];
  const int* tmask = (const int*)d_in[2];
  const int* xmask = (const int*)d_in[3];
  const float* lemb = (const float*)d_in[4];
  const float* W1   = (const float*)d_in[5];
  const float* b1   = (const float*)d_in[6];
  const float* W2   = (const float*)d_in[7];
  const float* b2   = (const float*)d_in[8];
  float* out = (float*)d_out;

  char* w = (char*)d_ws;
  auto alloc = [&](size_t bytes) {
    char* p = w; w += (bytes + 255) & ~(size_t)255; return p;
  };
  // small buffers (~7 MB)
  bf16s* wbt   = (bf16s*)alloc((size_t)N3 * H_ * 2);
  bf16s* w2t   = (bf16s*)alloc((size_t)H_ * H_ * 2);
  float* LT    = (float*)alloc((size_t)(L_ + 1) * H_ * 4);
  bf16s* topn  = (bf16s*)alloc((size_t)B_ * T_ * H_ * 2);
  float* scores= (float*)alloc((size_t)B_ * NPAD * 4);
  int* R       = (int*)alloc(S_ * 4);
  int* pos     = (int*)alloc(S_ * 4);
  int* spoff   = (int*)alloc(S_ * 4);
  int* starts  = (int*)alloc(NPAD * 4);
  int* ends    = (int*)alloc(NPAD * 4);
  int* lens    = (int*)alloc(NPAD * 4);
  int* meta    = (int*)alloc(2 * 4);
  // region A: [hidb | P] (100.66 MB), later aliased by Y (100.66 MB)
  char* regionA = alloc((size_t)BS * H_ * 2 + (size_t)BS * N3 * 2);
  bf16s* hidb  = (bf16s*)regionA;
  bf16s* P     = (bf16s*)(regionA + (size_t)BS * H_ * 2);
  bf16s* Y     = (bf16s*)regionA;   // alias: valid after hidb & P are dead
  // region B: X (100.66 MB)
  bf16s* X     = (bf16s*)alloc((size_t)BNR * H_ * 2);

  size_t required = (size_t)(w - (char*)d_ws);
  if (required > ws_size) {
    k_sentinel<<<(BS + 255) / 256, 256, 0, stream>>>(out);
    return;
  }

  k_build_spans<<<1, 1024, 0, stream>>>(xmask, R, pos, spoff, starts, ends, lens, meta);
  k_cast_bf16<<<(BS * H_ / 4 + 255) / 256, 256, 0, stream>>>(hid, hidb, BS * H_ / 4);
  for (int c = 0; c < 3; c++)
    k_transpose_cast<<<dim3(12, 12), 256, 0, stream>>>(W1 + (size_t)c * H_ * H_, wbt + (size_t)c * H_ * H_);
  k_transpose_cast<<<dim3(12, 12), 256, 0, stream>>>(W2, w2t);
  k_lt<<<((L_ + 1) * H_ + 255) / 256, 256, 0, stream>>>(lemb, W1, LT);

  // GEMM1: P = hidb * wbt^T  (16384 x 2304, K=768)
  k_gemm256<<<(BS / 256) * (N3 / 256), 512, 0, stream>>>(hidb, wbt, P, nullptr, BS, N3, H_, N3 / 256);

  k_z1<<<(B_ * NPAD * (H_ / 4)) / 256, 256, 0, stream>>>(P, LT, b1, starts, ends, lens, meta, X);

  // GEMM2: Y = X * w2t^T + b2  (65536 x 768, K=768)
  k_gemm256<<<(BNR / 256) * (H_ / 256), 512, 0, stream>>>(X, w2t, Y, b2, BNR, H_, H_, H_ / 256);

  k_topicn<<<B_ * T_, 256, 0, stream>>>(th, topn);
  k_sim<<<dim3(NPAD / 64, B_), 256, 0, stream>>>(Y, topn, tmask, scores);
  k_token<<<(B_ * S_) / 256, 256, 0, stream>>>(xmask, R, spoff, meta, scores, out);
  (void)in_sizes; (void)n_in; (void)out_size;
}

// Round 4
// 365.346 us; speedup vs baseline: 1.0670x; 1.0614x over previous
//
#include <hip/hip_runtime.h>
#include <hip/hip_bf16.h>
#include <math.h>

typedef __bf16 bf16s;
typedef __attribute__((ext_vector_type(8))) __bf16 bf16x8;
typedef __attribute__((ext_vector_type(4))) __bf16 bf16x4;
typedef __attribute__((ext_vector_type(4))) float f32x4;

#define B_   16
#define S_   1024
#define H_   768
#define T_   64
#define L_   4
#define LE_  32
#define NPAD 4096
#define BS   (B_*S_)    // 16384
#define BNR  (B_*NPAD)  // 65536 rows of X/Y
#define N3   (3*H_)     // 2304

static __device__ __forceinline__ void gload_lds16(const void* g, void* l) {
  __builtin_amdgcn_global_load_lds(
      (const __attribute__((address_space(1))) void*)g,
      (__attribute__((address_space(3))) void*)l, 16, 0, 0);
}

// ---------------- span construction (1 block) ----------------
__global__ __launch_bounds__(1024) void k_build_spans(
    const int* __restrict__ text_mask,   // row 0 used
    int* __restrict__ R, int* __restrict__ pos, int* __restrict__ spoff,
    int* __restrict__ starts, int* __restrict__ ends, int* __restrict__ lens,
    int* __restrict__ meta)
{
  __shared__ int buf[S_];
  int t = threadIdx.x;
  int m = text_mask[t] ? 1 : 0;
  buf[t] = m;
  __syncthreads();
  for (int off = 1; off < S_; off <<= 1) {
    int v = buf[t];
    if (t >= off) v += buf[t - off];
    __syncthreads();
    buf[t] = v;
    __syncthreads();
  }
  int incl = buf[t];
  R[t] = incl;
  if (m) pos[incl - 1] = t;
  int n = buf[S_ - 1];
  __syncthreads();
  int cnt = (t < n) ? min(L_, n - t) : 0;
  buf[t] = cnt;
  __syncthreads();
  for (int off = 1; off < S_; off <<= 1) {
    int v = buf[t];
    if (t >= off) v += buf[t - off];
    __syncthreads();
    buf[t] = v;
    __syncthreads();
  }
  int inc2 = buf[t];
  int base = inc2 - cnt;
  spoff[t] = base;
  if (t == 0) { meta[0] = buf[S_ - 1]; meta[1] = n; }
  __syncthreads();
  if (t < n) {
    int p0 = pos[t];
    for (int k = 0; k < cnt; k++) {
      starts[base + k] = p0;
      ends[base + k]   = pos[t + k];
      lens[base + k]   = k + 1;
    }
  }
}

// ---------------- casts ----------------
__global__ __launch_bounds__(256) void k_cast_bf16(const float* __restrict__ src,
                                                   bf16s* __restrict__ dst, int n4) {
  int i = blockIdx.x * 256 + threadIdx.x;
  if (i >= n4) return;
  f32x4 v = ((const f32x4*)src)[i];
  bf16x4 o;
  o[0] = (__bf16)v[0]; o[1] = (__bf16)v[1]; o[2] = (__bf16)v[2]; o[3] = (__bf16)v[3];
  ((bf16x4*)dst)[i] = o;
}

// out[nn][k] = in[k][nn], 768x768 chunk, f32 -> bf16
__global__ __launch_bounds__(256) void k_transpose_cast(const float* __restrict__ in,
                                                        bf16s* __restrict__ out) {
  __shared__ float tile[64][65];
  int r0 = blockIdx.x * 64, c0 = blockIdx.y * 64;
  int t = threadIdx.x;
  int tr = t >> 4;          // 0..15
  int tc = (t & 15) * 4;    // 0..60
#pragma unroll
  for (int i = 0; i < 4; i++) {
    int row = tr + i * 16;
    f32x4 v = *(const f32x4*)(in + (long)(r0 + row) * H_ + c0 + tc);
    tile[row][tc+0] = v[0]; tile[row][tc+1] = v[1];
    tile[row][tc+2] = v[2]; tile[row][tc+3] = v[3];
  }
  __syncthreads();
#pragma unroll
  for (int i = 0; i < 4; i++) {
    int cc = tr + i * 16;
    bf16x4 o;
    o[0] = (__bf16)tile[tc+0][cc]; o[1] = (__bf16)tile[tc+1][cc];
    o[2] = (__bf16)tile[tc+2][cc]; o[3] = (__bf16)tile[tc+3][cc];
    *(bf16x4*)(out + (long)(c0 + cc) * H_ + r0 + tc) = o;
  }
}

// LT[l][h] = sum_e len_emb[l][e] * W1[N3+e][h]
__global__ __launch_bounds__(256) void k_lt(const float* __restrict__ len_emb,
                                            const float* __restrict__ W1,
                                            float* __restrict__ LT) {
  int idx = blockIdx.x * 256 + threadIdx.x;
  if (idx >= (L_ + 1) * H_) return;
  int l = idx / H_, h = idx % H_;
  float acc = 0.f;
#pragma unroll
  for (int e = 0; e < LE_; e++) acc += len_emb[l * LE_ + e] * W1[(long)(N3 + e) * H_ + h];
  LT[idx] = acc;
}

// ====== 256x256 GEMM, BK=64, 8-phase / 2-K-tile counted-vmcnt pipeline ======
// C(MxN) = A(MxK) * Bt(NxK)^T (+bias), bf16 in/out, f32 acc.
// LDS per matrix: [2 buf][2 half][128 rows][8 x 16B slots], stored slot = s ^ (row&7).
// Staged via global_load_lds with inverse-swizzled global source (both-sides rule).
#define BKT 64
__global__ __launch_bounds__(512, 2) void k_gemm8p(
    const bf16s* __restrict__ A, const bf16s* __restrict__ Bt,
    bf16s* __restrict__ C, const float* __restrict__ bias,
    int N, int K, int NTN)
{
  __shared__ __align__(16) char sA[65536];
  __shared__ __align__(16) char sB[65536];

  // XCD-chunked bijective block swizzle
  int nwg = gridDim.x, bid = blockIdx.x;
  int q = nwg >> 3, rr = nwg & 7;
  int xcd = bid & 7, ix = bid >> 3;
  int nid = (xcd < rr ? xcd * (q + 1) : rr * (q + 1) + (xcd - rr) * q) + ix;
  long a0 = (long)(nid / NTN) * 256;
  long b0 = (long)(nid % NTN) * 256;

  int tid = threadIdx.x;
  int wid = tid >> 6, l = tid & 63;
  int wr = wid >> 2, wc = wid & 3;          // 2x4 waves; wave tile 128x64

  // ---- staging addresses: thread t covers row (t>>3) of a 64-row block,
  // stored slot (t&7) holding logical slot (t&7)^(row&7)  (inverse-swizzled src)
  int srow = tid >> 3;
  int sslot = (tid & 7) ^ (srow & 7);
  const bf16s* gA = A + (a0 + srow) * (long)K + sslot * 8;
  const bf16s* gB = Bt + (b0 + srow) * (long)K + sslot * 8;

#define STG_A(kt_, h_) do { \
    const bf16s* s_ = gA + (long)(h_) * 128 * K + (long)(kt_) * BKT; \
    char* d_ = sA + ((kt_) & 1) * 32768 + (h_) * 16384 + wid * 1024; \
    gload_lds16(s_, d_); \
    gload_lds16(s_ + 64L * K, d_ + 8192); \
  } while (0)
#define STG_B(kt_, h_) do { \
    const bf16s* s_ = gB + (long)(h_) * 128 * K + (long)(kt_) * BKT; \
    char* d_ = sB + ((kt_) & 1) * 32768 + (h_) * 16384 + wid * 1024; \
    gload_lds16(s_, d_); \
    gload_lds16(s_ + 64L * K, d_ + 8192); \
  } while (0)

  // ---- fragment read bases (swizzled): row stride 128B, slot = (ks*4+(l>>4)) ^ (l&7)
  const char* aP0 = sA + wr * 16384;
  const char* aP1 = aP0 + 32768;
  const char* bP0 = sB + (wc >> 1) * 16384 + (wc & 1) * 8192;
  const char* bP1 = bP0 + 32768;
  int lrow = (l & 15) * 128;
  int ls0 = (((l >> 4) ^ (l & 7)) * 16);
  // ks=1: slot ^= 4  -> byte ^= 64

  f32x4 acc[8][4];
#pragma unroll
  for (int i = 0; i < 8; i++)
#pragma unroll
    for (int j = 0; j < 4; j++) acc[i][j] = (f32x4){0.f, 0.f, 0.f, 0.f};

  int NT = K / BKT;        // 12 for K=768
  int NITER = NT / 2;      // 6

  // ---- prologue: tile0 {B0,B1,A0,A1}, tile1 {B0,B1,A0}; wait tile0 (8 oldest loads)
  STG_B(0, 0); STG_B(0, 1); STG_A(0, 0); STG_A(0, 1);
  STG_B(1, 0); STG_B(1, 1); STG_A(1, 0);
  asm volatile("s_waitcnt vmcnt(6)" ::: "memory");
  __builtin_amdgcn_s_barrier();

#define MFMA_Q(AF_, FR0_, FC_) do { \
    _Pragma("unroll") \
    for (int f_ = 0; f_ < 4; ++f_) { \
      acc[FR0_+f_][FC_] = __builtin_amdgcn_mfma_f32_16x16x32_bf16(bfv[FC_][0], AF_[f_][0], acc[FR0_+f_][FC_], 0, 0, 0); \
      acc[FR0_+f_][FC_] = __builtin_amdgcn_mfma_f32_16x16x32_bf16(bfv[FC_][1], AF_[f_][1], acc[FR0_+f_][FC_], 0, 0, 0); \
    } } while (0)

#define PH_PRE()  __builtin_amdgcn_s_barrier(); \
                  asm volatile("s_waitcnt lgkmcnt(0)" ::: "memory"); \
                  __builtin_amdgcn_s_setprio(1)
#define PH_POST() __builtin_amdgcn_s_setprio(0); \
                  __builtin_amdgcn_s_barrier()

  for (int it = 0; it < NITER; ++it) {
    int t0 = 2 * it, t1 = t0 + 1;
    bool nl = (it != NITER - 1);   // not-last
    bf16x8 af0[4][2], af1[4][2], bfv[4][2];

    // ---- phase 1: read af0(fr0-3) + all bfv from buf0; stage t1.A1
#pragma unroll
    for (int f = 0; f < 4; ++f) {
      af0[f][0] = *(const bf16x8*)(aP0 + f * 2048 + lrow + ls0);
      af0[f][1] = *(const bf16x8*)(aP0 + f * 2048 + lrow + (ls0 ^ 64));
    }
#pragma unroll
    for (int c = 0; c < 4; ++c) {
      bfv[c][0] = *(const bf16x8*)(bP0 + c * 2048 + lrow + ls0);
      bfv[c][1] = *(const bf16x8*)(bP0 + c * 2048 + lrow + (ls0 ^ 64));
    }
    STG_A(t1, 1);
    PH_PRE();
    MFMA_Q(af0, 0, 0); MFMA_Q(af0, 0, 1);
    PH_POST();

    // ---- phase 2: no reads; stage (t0+2).B0
    if (nl) STG_B(t0 + 2, 0);
    PH_PRE();
    MFMA_Q(af0, 0, 2); MFMA_Q(af0, 0, 3);
    PH_POST();

    // ---- phase 3: read af1(fr4-7) from buf0; stage (t0+2).B1
#pragma unroll
    for (int f = 0; f < 4; ++f) {
      af1[f][0] = *(const bf16x8*)(aP0 + (f + 4) * 2048 + lrow + ls0);
      af1[f][1] = *(const bf16x8*)(aP0 + (f + 4) * 2048 + lrow + (ls0 ^ 64));
    }
    if (nl) STG_B(t0 + 2, 1);
    PH_PRE();
    MFMA_Q(af1, 4, 0); MFMA_Q(af1, 4, 1);
    PH_POST();

    // ---- phase 4: stage (t0+2).A0; counted vmcnt (t1 fully landed)
    if (nl) { STG_A(t0 + 2, 0); asm volatile("s_waitcnt vmcnt(6)" ::: "memory"); }
    else    { asm volatile("s_waitcnt vmcnt(0)" ::: "memory"); }
    PH_PRE();
    MFMA_Q(af1, 4, 2); MFMA_Q(af1, 4, 3);
    PH_POST();

    // ---- phase 5: read af0 + bfv from buf1 (tile t1); stage (t0+2).A1
#pragma unroll
    for (int f = 0; f < 4; ++f) {
      af0[f][0] = *(const bf16x8*)(aP1 + f * 2048 + lrow + ls0);
      af0[f][1] = *(const bf16x8*)(aP1 + f * 2048 + lrow + (ls0 ^ 64));
    }
#pragma unroll
    for (int c = 0; c < 4; ++c) {
      bfv[c][0] = *(const bf16x8*)(bP1 + c * 2048 + lrow + ls0);
      bfv[c][1] = *(const bf16x8*)(bP1 + c * 2048 + lrow + (ls0 ^ 64));
    }
    if (nl) STG_A(t0 + 2, 1);
    PH_PRE();
    MFMA_Q(af0, 0, 0); MFMA_Q(af0, 0, 1);
    PH_POST();

    // ---- phase 6: stage (t1+2).B0
    if (nl) STG_B(t1 + 2, 0);
    PH_PRE();
    MFMA_Q(af0, 0, 2); MFMA_Q(af0, 0, 3);
    PH_POST();

    // ---- phase 7: read af1 from buf1; stage (t1+2).B1
#pragma unroll
    for (int f = 0; f < 4; ++f) {
      af1[f][0] = *(const bf16x8*)(aP1 + (f + 4) * 2048 + lrow + ls0);
      af1[f][1] = *(const bf16x8*)(aP1 + (f + 4) * 2048 + lrow + (ls0 ^ 64));
    }
    if (nl) STG_B(t1 + 2, 1);
    PH_PRE();
    MFMA_Q(af1, 4, 0); MFMA_Q(af1, 4, 1);
    PH_POST();

    // ---- phase 8: stage (t1+2).A0; counted vmcnt (t0+2 fully landed)
    if (nl) { STG_A(t1 + 2, 0); asm volatile("s_waitcnt vmcnt(6)" ::: "memory"); }
    else    { asm volatile("s_waitcnt vmcnt(0)" ::: "memory"); }
    PH_PRE();
    MFMA_Q(af1, 4, 2); MFMA_Q(af1, 4, 3);
    PH_POST();
  }

  // ---- epilogue: lane l holds C[a0+wr*128+fr*16+(l&15)][b0+wc*64+fc*16+(l>>4)*4 + r]
#pragma unroll
  for (int fc = 0; fc < 4; fc++) {
    long n0 = b0 + wc * 64 + fc * 16 + (l >> 4) * 4;
    f32x4 bb;
    if (bias) bb = *(const f32x4*)(bias + n0);
    else      bb = (f32x4){0.f, 0.f, 0.f, 0.f};
#pragma unroll
    for (int fr = 0; fr < 8; fr++) {
      long mrow = a0 + wr * 128 + fr * 16 + (l & 15);
      bf16x4 o;
#pragma unroll
      for (int r = 0; r < 4; r++) o[r] = (__bf16)(acc[fr][fc][r] + bb[r]);
      *(bf16x4*)(C + mrow * (long)N + n0) = o;
    }
  }
#undef STG_A
#undef STG_B
#undef MFMA_Q
#undef PH_PRE
#undef PH_POST
}

// ---------------- z1 assemble + GELU -> X (mean computed directly, len<=4) ---
__global__ __launch_bounds__(256) void k_z1(
    const bf16s* __restrict__ P,
    const float* __restrict__ LT, const float* __restrict__ b1,
    const int* __restrict__ starts, const int* __restrict__ ends,
    const int* __restrict__ lens, const int* __restrict__ meta,
    bf16s* __restrict__ X)
{
  int idx = blockIdx.x * 256 + threadIdx.x;  // B*NPAD*(H/4)
  int h4 = idx % (H_ / 4); int rest = idx / (H_ / 4);
  int nid = rest % NPAD; int b = rest / NPAD;
  int h = h4 * 4;
  int N = meta[0];
  long orow = (long)(b * NPAD + nid) * H_ + h;
  if (nid >= N) {
    bf16x4 z; z[0] = z[1] = z[2] = z[3] = (__bf16)0.f;
    *(bf16x4*)(X + orow) = z;
    return;
  }
  int sa = starts[nid], se = ends[nid], ln = lens[nid];
  float il = 1.0f / (float)ln;
  bf16x4 vs = *(const bf16x4*)(P + (long)(b * S_ + sa) * N3 + h);
  bf16x4 ve = *(const bf16x4*)(P + (long)(b * S_ + se) * N3 + H_ + h);
  float mv[4] = {0.f, 0.f, 0.f, 0.f};
  for (int i = sa; i <= se; i++) {
    bf16x4 vc = *(const bf16x4*)(P + (long)(b * S_ + i) * N3 + 2 * H_ + h);
#pragma unroll
    for (int j = 0; j < 4; j++) mv[j] += (float)vc[j];
  }
  f32x4 lt = *(const f32x4*)(LT + (long)ln * H_ + h);
  f32x4 bb = *(const f32x4*)(b1 + h);
  bf16x4 o;
#pragma unroll
  for (int j = 0; j < 4; j++) {
    float x = (float)vs[j] + (float)ve[j] + mv[j] * il + lt[j] + bb[j];
    float g = 0.5f * x * (1.0f + erff(x * 0.70710678118654752f));
    o[j] = (__bf16)g;
  }
  *(bf16x4*)(X + orow) = o;
}

// ---------------- normalize topics -> bf16 ----------------
__global__ __launch_bounds__(256) void k_topicn(const float* __restrict__ TH,
                                                bf16s* __restrict__ TN) {
  __shared__ float red[256];
  int r = blockIdx.x; int t = threadIdx.x;
  const float* row = TH + (long)r * H_;
  float v0 = row[t], v1 = row[t + 256], v2 = row[t + 512];
  red[t] = v0 * v0 + v1 * v1 + v2 * v2;
  __syncthreads();
  for (int off = 128; off; off >>= 1) {
    if (t < off) red[t] += red[t + off];
    __syncthreads();
  }
  float rn = 1.0f / fmaxf(sqrtf(red[0]), 1e-12f);
  bf16s* o = TN + (long)r * H_;
  o[t] = (__bf16)(v0 * rn); o[t + 256] = (__bf16)(v1 * rn); o[t + 512] = (__bf16)(v2 * rn);
}

// ------- sim (span x topic) + max over topics, with fused span rnorm -------
__global__ __launch_bounds__(256) void k_sim(
    const bf16s* __restrict__ Y, const bf16s* __restrict__ TN,
    const int* __restrict__ tmask, float* __restrict__ scores)
{
  int b = blockIdx.y;
  int wid = threadIdx.x >> 6, l = threadIdx.x & 63;
  int st = blockIdx.x * 4 + wid;
  int span = st * 16 + (l & 15);
  const bf16s* yrow = Y + (long)(b * NPAD + span) * H_ + (l >> 4) * 8;
  const bf16s* tbase = TN + (long)b * T_ * H_ + (l >> 4) * 8;
  f32x4 acc[4];
#pragma unroll
  for (int tt = 0; tt < 4; tt++) acc[tt] = (f32x4){0.f, 0.f, 0.f, 0.f};
  float ss = 0.f;
  for (int kk = 0; kk < H_ / 32; kk++) {
    bf16x8 av = *(const bf16x8*)(yrow + kk * 32);
#pragma unroll
    for (int j = 0; j < 8; j++) { float f = (float)av[j]; ss += f * f; }
#pragma unroll
    for (int tt = 0; tt < 4; tt++) {
      bf16x8 bv = *(const bf16x8*)(tbase + (long)(tt * 16 + (l & 15)) * H_ + kk * 32);
      acc[tt] = __builtin_amdgcn_mfma_f32_16x16x32_bf16(av, bv, acc[tt], 0, 0, 0);
    }
  }
  // full-row sumsq for span st*16+(l&15): combine the 4 k-groups
  ss += __shfl_xor(ss, 16);
  ss += __shfl_xor(ss, 32);
  float invn = 1.0f / fmaxf(sqrtf(ss), 1e-12f);
  const int* tm = tmask + b * T_;
  bool msk[4];
#pragma unroll
  for (int tt = 0; tt < 4; tt++) msk[tt] = tm[tt * 16 + (l & 15)] != 0;
  float best[4];
#pragma unroll
  for (int r = 0; r < 4; r++) {
    float v = -INFINITY;
#pragma unroll
    for (int tt = 0; tt < 4; tt++) if (msk[tt]) v = fmaxf(v, acc[tt][r]);
    best[r] = v;
  }
#pragma unroll
  for (int off = 8; off; off >>= 1)
#pragma unroll
    for (int r = 0; r < 4; r++) best[r] = fmaxf(best[r], __shfl_xor(best[r], off));
  float rr[4];
#pragma unroll
  for (int r = 0; r < 4; r++) rr[r] = __shfl(invn, (l >> 4) * 4 + r);
  if ((l & 15) == 0) {
    int srow = st * 16 + (l >> 4) * 4;
#pragma unroll
    for (int r = 0; r < 4; r++)
      scores[b * NPAD + srow + r] = best[r] * rr[r];
  }
}

// ---------------- token max ----------------
__global__ __launch_bounds__(256) void k_token(
    const int* __restrict__ text_mask,
    const int* __restrict__ R, const int* __restrict__ spoff,
    const int* __restrict__ meta, const float* __restrict__ scores,
    float* __restrict__ out)
{
  int idx = blockIdx.x * 256 + threadIdx.x;  // B*S
  int s = idx % S_, b = idx / S_;
  if (!text_mask[b * S_ + s]) { out[idx] = -INFINITY; return; }
  int n = meta[1];
  int r1 = R[s];
  int le = r1 - 1;                         // largest i with pos[i] <= s
  int ge = text_mask[s] ? (r1 - 1) : r1;   // smallest j with pos[j] >= s (row 0)
  float best = -INFINITY;
  if (le >= 0 && ge < n) {
    int i0 = max(0, ge - (L_ - 1));
    for (int i = i0; i <= le; i++) {
      int jmax = min(i + L_ - 1, n - 1);
      int off = spoff[i];
      for (int j = max(i, ge); j <= jmax; j++)
        best = fmaxf(best, scores[b * NPAD + off + (j - i)]);
    }
  }
  out[idx] = best;
}

// ---------------- ws-too-small sentinel ----------------
__global__ __launch_bounds__(256) void k_sentinel(float* __restrict__ out) {
  int i = blockIdx.x * 256 + threadIdx.x;
  if (i < BS) out[i] = 12345.0f;
}

// ---------------- launch ----------------
extern "C" void kernel_launch(void* const* d_in, const int* in_sizes, int n_in,
                              void* d_out, int out_size, void* d_ws, size_t ws_size,
                              hipStream_t stream) {
  const float* hid = (const float*)d_in[0];
  const float* th  = (const float*)d_in[1];
  const int* tmask = (const int*)d_in[2];
  const int* xmask = (const int*)d_in[3];
  const float* lemb = (const float*)d_in[4];
  const float* W1   = (const float*)d_in[5];
  const float* b1   = (const float*)d_in[6];
  const float* W2   = (const float*)d_in[7];
  const float* b2   = (const float*)d_in[8];
  float* out = (float*)d_out;

  char* w = (char*)d_ws;
  auto alloc = [&](size_t bytes) {
    char* p = w; w += (bytes + 255) & ~(size_t)255; return p;
  };
  // small buffers (~7 MB)
  bf16s* wbt   = (bf16s*)alloc((size_t)N3 * H_ * 2);
  bf16s* w2t   = (bf16s*)alloc((size_t)H_ * H_ * 2);
  float* LT    = (float*)alloc((size_t)(L_ + 1) * H_ * 4);
  bf16s* topn  = (bf16s*)alloc((size_t)B_ * T_ * H_ * 2);
  float* scores= (float*)alloc((size_t)B_ * NPAD * 4);
  int* R       = (int*)alloc(S_ * 4);
  int* pos     = (int*)alloc(S_ * 4);
  int* spoff   = (int*)alloc(S_ * 4);
  int* starts  = (int*)alloc(NPAD * 4);
  int* ends    = (int*)alloc(NPAD * 4);
  int* lens    = (int*)alloc(NPAD * 4);
  int* meta    = (int*)alloc(2 * 4);
  // region A: [hidb | P] (100.66 MB), later aliased by Y (100.66 MB)
  char* regionA = alloc((size_t)BS * H_ * 2 + (size_t)BS * N3 * 2);
  bf16s* hidb  = (bf16s*)regionA;
  bf16s* P     = (bf16s*)(regionA + (size_t)BS * H_ * 2);
  bf16s* Y     = (bf16s*)regionA;   // alias: valid after hidb & P are dead
  // region B: X (100.66 MB)
  bf16s* X     = (bf16s*)alloc((size_t)BNR * H_ * 2);

  size_t required = (size_t)(w - (char*)d_ws);
  if (required > ws_size) {
    k_sentinel<<<(BS + 255) / 256, 256, 0, stream>>>(out);
    return;
  }

  k_build_spans<<<1, 1024, 0, stream>>>(xmask, R, pos, spoff, starts, ends, lens, meta);
  k_cast_bf16<<<(BS * H_ / 4 + 255) / 256, 256, 0, stream>>>(hid, hidb, BS * H_ / 4);
  for (int c = 0; c < 3; c++)
    k_transpose_cast<<<dim3(12, 12), 256, 0, stream>>>(W1 + (size_t)c * H_ * H_, wbt + (size_t)c * H_ * H_);
  k_transpose_cast<<<dim3(12, 12), 256, 0, stream>>>(W2, w2t);
  k_lt<<<((L_ + 1) * H_ + 255) / 256, 256, 0, stream>>>(lemb, W1, LT);

  // GEMM1: P = hidb * wbt^T  (16384 x 2304, K=768)
  k_gemm8p<<<(BS / 256) * (N3 / 256), 512, 0, stream>>>(hidb, wbt, P, nullptr, N3, H_, N3 / 256);

  k_z1<<<(B_ * NPAD * (H_ / 4)) / 256, 256, 0, stream>>>(P, LT, b1, starts, ends, lens, meta, X);

  // GEMM2: Y = X * w2t^T + b2  (65536 x 768, K=768)
  k_gemm8p<<<(BNR / 256) * (H_ / 256), 512, 0, stream>>>(X, w2t, Y, b2, H_, H_, H_ / 256);

  k_topicn<<<B_ * T_, 256, 0, stream>>>(th, topn);
  k_sim<<<dim3(NPAD / 64, B_), 256, 0, stream>>>(Y, topn, tmask, scores);
  k_token<<<(B_ * S_) / 256, 256, 0, stream>>>(xmask, R, spoff, meta, scores, out);
  (void)in_sizes; (void)n_in; (void)out_size;
}

// Round 5
// 348.208 us; speedup vs baseline: 1.1196x; 1.0492x over previous
//
#include <hip/hip_runtime.h>
#include <hip/hip_bf16.h>
#include <math.h>

typedef __bf16 bf16s;
typedef __attribute__((ext_vector_type(8))) __bf16 bf16x8;
typedef __attribute__((ext_vector_type(4))) __bf16 bf16x4;
typedef __attribute__((ext_vector_type(4))) float f32x4;

#define B_   16
#define S_   1024
#define H_   768
#define T_   64
#define L_   4
#define LE_  32
#define NPAD 4096
#define BS   (B_*S_)    // 16384
#define BNR  (B_*NPAD)  // 65536 rows of X
#define N3   (3*H_)     // 2304

static __device__ __forceinline__ void gload_lds16(const void* g, void* l) {
  __builtin_amdgcn_global_load_lds(
      (const __attribute__((address_space(1))) void*)g,
      (__attribute__((address_space(3))) void*)l, 16, 0, 0);
}

// ---------------- span construction (1 block) ----------------
__global__ __launch_bounds__(1024) void k_build_spans(
    const int* __restrict__ text_mask,   // row 0 used
    int* __restrict__ R, int* __restrict__ pos, int* __restrict__ spoff,
    int* __restrict__ starts, int* __restrict__ ends, int* __restrict__ lens,
    int* __restrict__ meta)
{
  __shared__ int buf[S_];
  int t = threadIdx.x;
  int m = text_mask[t] ? 1 : 0;
  buf[t] = m;
  __syncthreads();
  for (int off = 1; off < S_; off <<= 1) {
    int v = buf[t];
    if (t >= off) v += buf[t - off];
    __syncthreads();
    buf[t] = v;
    __syncthreads();
  }
  int incl = buf[t];
  R[t] = incl;
  if (m) pos[incl - 1] = t;
  int n = buf[S_ - 1];
  __syncthreads();
  int cnt = (t < n) ? min(L_, n - t) : 0;
  buf[t] = cnt;
  __syncthreads();
  for (int off = 1; off < S_; off <<= 1) {
    int v = buf[t];
    if (t >= off) v += buf[t - off];
    __syncthreads();
    buf[t] = v;
    __syncthreads();
  }
  int inc2 = buf[t];
  int base = inc2 - cnt;
  spoff[t] = base;
  if (t == 0) { meta[0] = buf[S_ - 1]; meta[1] = n; }
  __syncthreads();
  if (t < n) {
    int p0 = pos[t];
    for (int k = 0; k < cnt; k++) {
      starts[base + k] = p0;
      ends[base + k]   = pos[t + k];
      lens[base + k]   = k + 1;
    }
  }
}

// ---------------- casts ----------------
__global__ __launch_bounds__(256) void k_cast_bf16(const float* __restrict__ src,
                                                   bf16s* __restrict__ dst, int n4) {
  int i = blockIdx.x * 256 + threadIdx.x;
  if (i >= n4) return;
  f32x4 v = ((const f32x4*)src)[i];
  bf16x4 o;
  o[0] = (__bf16)v[0]; o[1] = (__bf16)v[1]; o[2] = (__bf16)v[2]; o[3] = (__bf16)v[3];
  ((bf16x4*)dst)[i] = o;
}

__global__ __launch_bounds__(256) void k_zero(float* __restrict__ p, int n4) {
  int i = blockIdx.x * 256 + threadIdx.x;
  if (i < n4) ((f32x4*)p)[i] = (f32x4){0.f, 0.f, 0.f, 0.f};
}

// out[nn][k] = in[k][nn], 768x768 chunk, f32 -> bf16
__global__ __launch_bounds__(256) void k_transpose_cast(const float* __restrict__ in,
                                                        bf16s* __restrict__ out) {
  __shared__ float tile[64][65];
  int r0 = blockIdx.x * 64, c0 = blockIdx.y * 64;
  int t = threadIdx.x;
  int tr = t >> 4;          // 0..15
  int tc = (t & 15) * 4;    // 0..60
#pragma unroll
  for (int i = 0; i < 4; i++) {
    int row = tr + i * 16;
    f32x4 v = *(const f32x4*)(in + (long)(r0 + row) * H_ + c0 + tc);
    tile[row][tc+0] = v[0]; tile[row][tc+1] = v[1];
    tile[row][tc+2] = v[2]; tile[row][tc+3] = v[3];
  }
  __syncthreads();
#pragma unroll
  for (int i = 0; i < 4; i++) {
    int cc = tr + i * 16;
    bf16x4 o;
    o[0] = (__bf16)tile[tc+0][cc]; o[1] = (__bf16)tile[tc+1][cc];
    o[2] = (__bf16)tile[tc+2][cc]; o[3] = (__bf16)tile[tc+3][cc];
    *(bf16x4*)(out + (long)(c0 + cc) * H_ + r0 + tc) = o;
  }
}

// LT[l][h] = sum_e len_emb[l][e] * W1[N3+e][h]
__global__ __launch_bounds__(256) void k_lt(const float* __restrict__ len_emb,
                                            const float* __restrict__ W1,
                                            float* __restrict__ LT) {
  int idx = blockIdx.x * 256 + threadIdx.x;
  if (idx >= (L_ + 1) * H_) return;
  int l = idx / H_, h = idx % H_;
  float acc = 0.f;
#pragma unroll
  for (int e = 0; e < LE_; e++) acc += len_emb[l * LE_ + e] * W1[(long)(N3 + e) * H_ + h];
  LT[idx] = acc;
}

// ====== shared 8-phase GEMM core (256x256 tile, BK=64, counted vmcnt) ======
// Loop body computes acc[8][4] (f32x4) for C-tile [a0..a0+256) x [b0..b0+256).
// lane mapping: C row = a0+wr*128+fr*16+(l&15); col = b0+wc*64+fc*16+(l>>4)*4+r.
#define BKT 64
#define GEMM_CORE_BODY(A_, Bt_, K_) \
  int tid = threadIdx.x; \
  int wid = tid >> 6, l = tid & 63; \
  int wr = wid >> 2, wc = wid & 3; \
  int srow = tid >> 3; \
  int sslot = (tid & 7) ^ (srow & 7); \
  const bf16s* gA = (A_) + (a0 + srow) * (long)(K_) + sslot * 8; \
  const bf16s* gB = (Bt_) + (b0 + srow) * (long)(K_) + sslot * 8; \
  const char* aP0 = sA + wr * 16384; \
  const char* aP1 = aP0 + 32768; \
  const char* bP0 = sB + (wc >> 1) * 16384 + (wc & 1) * 8192; \
  const char* bP1 = bP0 + 32768; \
  int lrow = (l & 15) * 128; \
  int ls0 = (((l >> 4) ^ (l & 7)) * 16); \
  f32x4 acc[8][4]; \
  _Pragma("unroll") \
  for (int i = 0; i < 8; i++) \
    _Pragma("unroll") \
    for (int j = 0; j < 4; j++) acc[i][j] = (f32x4){0.f, 0.f, 0.f, 0.f}; \
  int NT = (K_) / BKT; \
  int NITER = NT / 2; \
  STG_B(0, 0); STG_B(0, 1); STG_A(0, 0); STG_A(0, 1); \
  STG_B(1, 0); STG_B(1, 1); STG_A(1, 0); \
  asm volatile("s_waitcnt vmcnt(6)" ::: "memory"); \
  __builtin_amdgcn_s_barrier(); \
  for (int it = 0; it < NITER; ++it) { \
    int t0 = 2 * it, t1 = t0 + 1; \
    bool nl = (it != NITER - 1); \
    bf16x8 af0[4][2], af1[4][2], bfv[4][2]; \
    _Pragma("unroll") \
    for (int f = 0; f < 4; ++f) { \
      af0[f][0] = *(const bf16x8*)(aP0 + f * 2048 + lrow + ls0); \
      af0[f][1] = *(const bf16x8*)(aP0 + f * 2048 + lrow + (ls0 ^ 64)); \
    } \
    _Pragma("unroll") \
    for (int c = 0; c < 4; ++c) { \
      bfv[c][0] = *(const bf16x8*)(bP0 + c * 2048 + lrow + ls0); \
      bfv[c][1] = *(const bf16x8*)(bP0 + c * 2048 + lrow + (ls0 ^ 64)); \
    } \
    STG_A(t1, 1); \
    PH_PRE(); \
    MFMA_Q(af0, 0, 0); MFMA_Q(af0, 0, 1); \
    PH_POST(); \
    if (nl) STG_B(t0 + 2, 0); \
    PH_PRE(); \
    MFMA_Q(af0, 0, 2); MFMA_Q(af0, 0, 3); \
    PH_POST(); \
    _Pragma("unroll") \
    for (int f = 0; f < 4; ++f) { \
      af1[f][0] = *(const bf16x8*)(aP0 + (f + 4) * 2048 + lrow + ls0); \
      af1[f][1] = *(const bf16x8*)(aP0 + (f + 4) * 2048 + lrow + (ls0 ^ 64)); \
    } \
    if (nl) STG_B(t0 + 2, 1); \
    PH_PRE(); \
    MFMA_Q(af1, 4, 0); MFMA_Q(af1, 4, 1); \
    PH_POST(); \
    if (nl) { STG_A(t0 + 2, 0); asm volatile("s_waitcnt vmcnt(6)" ::: "memory"); } \
    else    { asm volatile("s_waitcnt vmcnt(0)" ::: "memory"); } \
    PH_PRE(); \
    MFMA_Q(af1, 4, 2); MFMA_Q(af1, 4, 3); \
    PH_POST(); \
    _Pragma("unroll") \
    for (int f = 0; f < 4; ++f) { \
      af0[f][0] = *(const bf16x8*)(aP1 + f * 2048 + lrow + ls0); \
      af0[f][1] = *(const bf16x8*)(aP1 + f * 2048 + lrow + (ls0 ^ 64)); \
    } \
    _Pragma("unroll") \
    for (int c = 0; c < 4; ++c) { \
      bfv[c][0] = *(const bf16x8*)(bP1 + c * 2048 + lrow + ls0); \
      bfv[c][1] = *(const bf16x8*)(bP1 + c * 2048 + lrow + (ls0 ^ 64)); \
    } \
    if (nl) STG_A(t0 + 2, 1); \
    PH_PRE(); \
    MFMA_Q(af0, 0, 0); MFMA_Q(af0, 0, 1); \
    PH_POST(); \
    if (nl) STG_B(t1 + 2, 0); \
    PH_PRE(); \
    MFMA_Q(af0, 0, 2); MFMA_Q(af0, 0, 3); \
    PH_POST(); \
    _Pragma("unroll") \
    for (int f = 0; f < 4; ++f) { \
      af1[f][0] = *(const bf16x8*)(aP1 + (f + 4) * 2048 + lrow + ls0); \
      af1[f][1] = *(const bf16x8*)(aP1 + (f + 4) * 2048 + lrow + (ls0 ^ 64)); \
    } \
    if (nl) STG_B(t1 + 2, 1); \
    PH_PRE(); \
    MFMA_Q(af1, 4, 0); MFMA_Q(af1, 4, 1); \
    PH_POST(); \
    if (nl) { STG_A(t1 + 2, 0); asm volatile("s_waitcnt vmcnt(6)" ::: "memory"); } \
    else    { asm volatile("s_waitcnt vmcnt(0)" ::: "memory"); } \
    PH_PRE(); \
    MFMA_Q(af1, 4, 2); MFMA_Q(af1, 4, 3); \
    PH_POST(); \
  }

#define STG_A(kt_, h_) do { \
    const bf16s* s_ = gA + (long)(h_) * 128 * K + (long)(kt_) * BKT; \
    char* d_ = sA + ((kt_) & 1) * 32768 + (h_) * 16384 + wid * 1024; \
    gload_lds16(s_, d_); \
    gload_lds16(s_ + 64L * K, d_ + 8192); \
  } while (0)
#define STG_B(kt_, h_) do { \
    const bf16s* s_ = gB + (long)(h_) * 128 * K + (long)(kt_) * BKT; \
    char* d_ = sB + ((kt_) & 1) * 32768 + (h_) * 16384 + wid * 1024; \
    gload_lds16(s_, d_); \
    gload_lds16(s_ + 64L * K, d_ + 8192); \
  } while (0)
#define MFMA_Q(AF_, FR0_, FC_) do { \
    _Pragma("unroll") \
    for (int f_ = 0; f_ < 4; ++f_) { \
      acc[FR0_+f_][FC_] = __builtin_amdgcn_mfma_f32_16x16x32_bf16(bfv[FC_][0], AF_[f_][0], acc[FR0_+f_][FC_], 0, 0, 0); \
      acc[FR0_+f_][FC_] = __builtin_amdgcn_mfma_f32_16x16x32_bf16(bfv[FC_][1], AF_[f_][1], acc[FR0_+f_][FC_], 0, 0, 0); \
    } } while (0)
#define PH_PRE()  __builtin_amdgcn_s_barrier(); \
                  asm volatile("s_waitcnt lgkmcnt(0)" ::: "memory"); \
                  __builtin_amdgcn_s_setprio(1)
#define PH_POST() __builtin_amdgcn_s_setprio(0); \
                  __builtin_amdgcn_s_barrier()

// ---- variant 1: C written to global via LDS-staged coalesced epilogue ----
__global__ __launch_bounds__(512, 2) void k_gemm8p(
    const bf16s* __restrict__ A, const bf16s* __restrict__ Bt,
    bf16s* __restrict__ C, int N, int K, int NTN)
{
  __shared__ __align__(16) char sA[65536];
  __shared__ __align__(16) char sB[65536];
  int nwg = gridDim.x, bid = blockIdx.x;
  int q = nwg >> 3, rr = nwg & 7;
  int xcd = bid & 7, ix = bid >> 3;
  int nid = (xcd < rr ? xcd * (q + 1) : rr * (q + 1) + (xcd - rr) * q) + ix;
  long a0 = (long)(nid / NTN) * 256;
  long b0 = (long)(nid % NTN) * 256;

  GEMM_CORE_BODY(A, Bt, K)

  // LDS-staged coalesced C write (half-tiles of 128 rows through sA)
#pragma unroll
  for (int half = 0; half < 2; ++half) {
    if (wr == half) {
#pragma unroll
      for (int fc = 0; fc < 4; ++fc) {
        int col2 = (wc * 64 + fc * 16 + (l >> 4) * 4) * 2;
#pragma unroll
        for (int fr = 0; fr < 8; ++fr) {
          int row_l = fr * 16 + (l & 15);
          bf16x4 o;
#pragma unroll
          for (int r = 0; r < 4; ++r) o[r] = (__bf16)acc[fr][fc][r];
          *(bf16x4*)(sA + ((row_l * 512 + col2) ^ ((row_l & 7) << 4))) = o;
        }
      }
    }
    __syncthreads();
#pragma unroll
    for (int i = 0; i < 8; ++i) {
      int off = i * 8192 + tid * 16;
      int row_l = off >> 9;
      bf16x8 v = *(const bf16x8*)(sA + (off ^ ((row_l & 7) << 4)));
      *(bf16x8*)(C + (a0 + half * 128 + row_l) * (long)N + b0 + ((off & 511) >> 1)) = v;
    }
    __syncthreads();
  }
}

// ---- variant 2: norm-only GEMM: accumulate row sums of (acc+bias)^2 ----
__global__ __launch_bounds__(512, 2) void k_gemmnorm(
    const bf16s* __restrict__ A, const bf16s* __restrict__ Bt,
    const float* __restrict__ bias, float* __restrict__ ssbuf,
    int K, int NTN)
{
  __shared__ __align__(16) char sA[65536];
  __shared__ __align__(16) char sB[65536];
  int nwg = gridDim.x, bid = blockIdx.x;
  int q = nwg >> 3, rr = nwg & 7;
  int xcd = bid & 7, ix = bid >> 3;
  int nid = (xcd < rr ? xcd * (q + 1) : rr * (q + 1) + (xcd - rr) * q) + ix;
  long a0 = (long)(nid / NTN) * 256;
  long b0 = (long)(nid % NTN) * 256;

  GEMM_CORE_BODY(A, Bt, K)

  // per-row sum of squares over this block's 256-column slice
  f32x4 bb[4];
#pragma unroll
  for (int fc = 0; fc < 4; ++fc)
    bb[fc] = *(const f32x4*)(bias + b0 + wc * 64 + fc * 16 + (l >> 4) * 4);
#pragma unroll
  for (int fr = 0; fr < 8; ++fr) {
    float p = 0.f;
#pragma unroll
    for (int fc = 0; fc < 4; ++fc)
#pragma unroll
      for (int r = 0; r < 4; ++r) {
        float y = acc[fr][fc][r] + bb[fc][r];
        p += y * y;
      }
    p += __shfl_xor(p, 16);
    p += __shfl_xor(p, 32);
    if (l < 16) atomicAdd(&ssbuf[a0 + wr * 128 + fr * 16 + l], p);
  }
}

#undef STG_A
#undef STG_B
#undef MFMA_Q
#undef PH_PRE
#undef PH_POST

// ---------------- z1 assemble + GELU -> X (mean computed directly, len<=4) ---
__global__ __launch_bounds__(256) void k_z1(
    const bf16s* __restrict__ P,
    const float* __restrict__ LT, const float* __restrict__ b1,
    const int* __restrict__ starts, const int* __restrict__ ends,
    const int* __restrict__ lens, const int* __restrict__ meta,
    bf16s* __restrict__ X)
{
  int idx = blockIdx.x * 256 + threadIdx.x;  // B*NPAD*(H/4)
  int h4 = idx % (H_ / 4); int rest = idx / (H_ / 4);
  int nid = rest % NPAD; int b = rest / NPAD;
  int h = h4 * 4;
  int N = meta[0];
  long orow = (long)(b * NPAD + nid) * H_ + h;
  if (nid >= N) {
    bf16x4 z; z[0] = z[1] = z[2] = z[3] = (__bf16)0.f;
    *(bf16x4*)(X + orow) = z;
    return;
  }
  int sa = starts[nid], se = ends[nid], ln = lens[nid];
  float il = 1.0f / (float)ln;
  bf16x4 vs = *(const bf16x4*)(P + (long)(b * S_ + sa) * N3 + h);
  bf16x4 ve = *(const bf16x4*)(P + (long)(b * S_ + se) * N3 + H_ + h);
  float mv[4] = {0.f, 0.f, 0.f, 0.f};
  for (int i = sa; i <= se; i++) {
    bf16x4 vc = *(const bf16x4*)(P + (long)(b * S_ + i) * N3 + 2 * H_ + h);
#pragma unroll
    for (int j = 0; j < 4; j++) mv[j] += (float)vc[j];
  }
  f32x4 lt = *(const f32x4*)(LT + (long)ln * H_ + h);
  f32x4 bb = *(const f32x4*)(b1 + h);
  bf16x4 o;
#pragma unroll
  for (int j = 0; j < 4; j++) {
    float x = (float)vs[j] + (float)ve[j] + mv[j] * il + lt[j] + bb[j];
    float g = 0.5f * x * (1.0f + erff(x * 0.70710678118654752f));
    o[j] = (__bf16)g;
  }
  *(bf16x4*)(X + orow) = o;
}

// ------- normalize topics -> bf16; also c[t] = TN[t]·b2 -------
__global__ __launch_bounds__(256) void k_topicn(const float* __restrict__ TH,
                                                const float* __restrict__ b2,
                                                bf16s* __restrict__ TN,
                                                float* __restrict__ cvec) {
  __shared__ float red[256];
  int r = blockIdx.x; int t = threadIdx.x;
  const float* row = TH + (long)r * H_;
  float v0 = row[t], v1 = row[t + 256], v2 = row[t + 512];
  red[t] = v0 * v0 + v1 * v1 + v2 * v2;
  __syncthreads();
  for (int off = 128; off; off >>= 1) {
    if (t < off) red[t] += red[t + off];
    __syncthreads();
  }
  float rn = 1.0f / fmaxf(sqrtf(red[0]), 1e-12f);
  bf16s* o = TN + (long)r * H_;
  o[t] = (__bf16)(v0 * rn); o[t + 256] = (__bf16)(v1 * rn); o[t + 512] = (__bf16)(v2 * rn);
  __syncthreads();
  red[t] = v0 * b2[t] + v1 * b2[t + 256] + v2 * b2[t + 512];
  __syncthreads();
  for (int off = 128; off; off >>= 1) {
    if (t < off) red[t] += red[t + off];
    __syncthreads();
  }
  if (t == 0) cvec[r] = red[0] * rn;
}

// ------- sim from X: scores[b,n] = max_t (U[t]·X_n + c[t]) * rsqrt(ss[n]) ----
__global__ __launch_bounds__(256) void k_simx(
    const bf16s* __restrict__ X, const bf16s* __restrict__ U,
    const float* __restrict__ cvec, const float* __restrict__ ssbuf,
    const int* __restrict__ tmask, float* __restrict__ scores)
{
  int b = blockIdx.y;
  int wid = threadIdx.x >> 6, l = threadIdx.x & 63;
  int st = blockIdx.x * 4 + wid;
  int span = st * 16 + (l & 15);
  const bf16s* xrow = X + (long)(b * NPAD + span) * H_ + (l >> 4) * 8;
  const bf16s* ubase = U + (long)b * T_ * H_ + (l >> 4) * 8;
  f32x4 acc[4];
#pragma unroll
  for (int tt = 0; tt < 4; tt++) acc[tt] = (f32x4){0.f, 0.f, 0.f, 0.f};
  for (int kk = 0; kk < H_ / 32; kk++) {
    bf16x8 av = *(const bf16x8*)(xrow + kk * 32);
#pragma unroll
    for (int tt = 0; tt < 4; tt++) {
      bf16x8 bv = *(const bf16x8*)(ubase + (long)(tt * 16 + (l & 15)) * H_ + kk * 32);
      acc[tt] = __builtin_amdgcn_mfma_f32_16x16x32_bf16(av, bv, acc[tt], 0, 0, 0);
    }
  }
  const int* tm = tmask + b * T_;
  bool msk[4];
  float cv[4];
#pragma unroll
  for (int tt = 0; tt < 4; tt++) {
    int tcol = tt * 16 + (l & 15);
    msk[tt] = tm[tcol] != 0;
    cv[tt] = cvec[b * T_ + tcol];
  }
  float best[4];
#pragma unroll
  for (int r = 0; r < 4; r++) {
    float v = -INFINITY;
#pragma unroll
    for (int tt = 0; tt < 4; tt++) if (msk[tt]) v = fmaxf(v, acc[tt][r] + cv[tt]);
    best[r] = v;
  }
#pragma unroll
  for (int off = 8; off; off >>= 1)
#pragma unroll
    for (int r = 0; r < 4; r++) best[r] = fmaxf(best[r], __shfl_xor(best[r], off));
  if ((l & 15) == 0) {
    int srow = st * 16 + (l >> 4) * 4;
#pragma unroll
    for (int r = 0; r < 4; r++) {
      float ss = ssbuf[b * NPAD + srow + r];
      scores[b * NPAD + srow + r] = best[r] / fmaxf(sqrtf(ss), 1e-12f);
    }
  }
}

// ---------------- token max ----------------
__global__ __launch_bounds__(256) void k_token(
    const int* __restrict__ text_mask,
    const int* __restrict__ R, const int* __restrict__ spoff,
    const int* __restrict__ meta, const float* __restrict__ scores,
    float* __restrict__ out)
{
  int idx = blockIdx.x * 256 + threadIdx.x;  // B*S
  int s = idx % S_, b = idx / S_;
  if (!text_mask[b * S_ + s]) { out[idx] = -INFINITY; return; }
  int n = meta[1];
  int r1 = R[s];
  int le = r1 - 1;                         // largest i with pos[i] <= s
  int ge = text_mask[s] ? (r1 - 1) : r1;   // smallest j with pos[j] >= s (row 0)
  float best = -INFINITY;
  if (le >= 0 && ge < n) {
    int i0 = max(0, ge - (L_ - 1));
    for (int i = i0; i <= le; i++) {
      int jmax = min(i + L_ - 1, n - 1);
      int off = spoff[i];
      for (int j = max(i, ge); j <= jmax; j++)
        best = fmaxf(best, scores[b * NPAD + off + (j - i)]);
    }
  }
  out[idx] = best;
}

// ---------------- ws-too-small sentinel ----------------
__global__ __launch_bounds__(256) void k_sentinel(float* __restrict__ out) {
  int i = blockIdx.x * 256 + threadIdx.x;
  if (i < BS) out[i] = 12345.0f;
}

// ---------------- launch ----------------
extern "C" void kernel_launch(void* const* d_in, const int* in_sizes, int n_in,
                              void* d_out, int out_size, void* d_ws, size_t ws_size,
                              hipStream_t stream) {
  const float* hid = (const float*)d_in[0];
  const float* th  = (const float*)d_in[1];
  const int* tmask = (const int*)d_in[2];
  const int* xmask = (const int*)d_in[3];
  const float* lemb = (const float*)d_in[4];
  const float* W1   = (const float*)d_in[5];
  const float* b1   = (const float*)d_in[6];
  const float* W2   = (const float*)d_in[7];
  const float* b2   = (const float*)d_in[8];
  float* out = (float*)d_out;

  char* w = (char*)d_ws;
  auto alloc = [&](size_t bytes) {
    char* p = w; w += (bytes + 255) & ~(size_t)255; return p;
  };
  // small buffers (~10 MB)
  bf16s* wbt   = (bf16s*)alloc((size_t)N3 * H_ * 2);
  bf16s* w2t   = (bf16s*)alloc((size_t)H_ * H_ * 2);
  bf16s* w2c   = (bf16s*)alloc((size_t)H_ * H_ * 2);
  float* LT    = (float*)alloc((size_t)(L_ + 1) * H_ * 4);
  bf16s* topn  = (bf16s*)alloc((size_t)B_ * T_ * H_ * 2);
  bf16s* U     = (bf16s*)alloc((size_t)B_ * T_ * H_ * 2);
  float* cvec  = (float*)alloc((size_t)B_ * T_ * 4);
  float* ssbuf = (float*)alloc((size_t)BNR * 4);
  float* scores= (float*)alloc((size_t)B_ * NPAD * 4);
  int* R       = (int*)alloc(S_ * 4);
  int* pos     = (int*)alloc(S_ * 4);
  int* spoff   = (int*)alloc(S_ * 4);
  int* starts  = (int*)alloc(NPAD * 4);
  int* ends    = (int*)alloc(NPAD * 4);
  int* lens    = (int*)alloc(NPAD * 4);
  int* meta    = (int*)alloc(2 * 4);
  // region A: [hidb | P] (100.66 MB)
  char* regionA = alloc((size_t)BS * H_ * 2 + (size_t)BS * N3 * 2);
  bf16s* hidb  = (bf16s*)regionA;
  bf16s* P     = (bf16s*)(regionA + (size_t)BS * H_ * 2);
  // region B: X (100.66 MB)
  bf16s* X     = (bf16s*)alloc((size_t)BNR * H_ * 2);

  size_t required = (size_t)(w - (char*)d_ws);
  if (required > ws_size) {
    k_sentinel<<<(BS + 255) / 256, 256, 0, stream>>>(out);
    return;
  }

  k_build_spans<<<1, 1024, 0, stream>>>(xmask, R, pos, spoff, starts, ends, lens, meta);
  k_cast_bf16<<<(BS * H_ / 4 + 255) / 256, 256, 0, stream>>>(hid, hidb, BS * H_ / 4);
  for (int c = 0; c < 3; c++)
    k_transpose_cast<<<dim3(12, 12), 256, 0, stream>>>(W1 + (size_t)c * H_ * H_, wbt + (size_t)c * H_ * H_);
  k_transpose_cast<<<dim3(12, 12), 256, 0, stream>>>(W2, w2t);
  k_cast_bf16<<<(H_ * H_ / 4 + 255) / 256, 256, 0, stream>>>(W2, w2c, H_ * H_ / 4);
  k_lt<<<((L_ + 1) * H_ + 255) / 256, 256, 0, stream>>>(lemb, W1, LT);
  k_zero<<<(BNR / 4 + 255) / 256, 256, 0, stream>>>(ssbuf, BNR / 4);

  // GEMM1: P = hidb * wbt^T  (16384 x 2304, K=768)
  k_gemm8p<<<(BS / 256) * (N3 / 256), 512, 0, stream>>>(hidb, wbt, P, N3, H_, N3 / 256);

  k_z1<<<(B_ * NPAD * (H_ / 4)) / 256, 256, 0, stream>>>(P, LT, b1, starts, ends, lens, meta, X);

  k_topicn<<<B_ * T_, 256, 0, stream>>>(th, b2, topn, cvec);
  // U = TN @ W2^T  (1024 x 768, K=768): Bt[j'][j] = W2[j'][j] (plain cast)
  k_gemm8p<<<(B_ * T_ / 256) * (H_ / 256), 512, 0, stream>>>(topn, w2c, U, H_, H_, H_ / 256);

  // norm-only GEMM2: ssbuf[n] += row sums of (X@W2^T + b2)^2
  k_gemmnorm<<<(BNR / 256) * (H_ / 256), 512, 0, stream>>>(X, w2t, b2, ssbuf, H_, H_ / 256);

  k_simx<<<dim3(NPAD / 64, B_), 256, 0, stream>>>(X, U, cvec, ssbuf, tmask, scores);
  k_token<<<(B_ * S_) / 256, 256, 0, stream>>>(xmask, R, spoff, meta, scores, out);
  (void)in_sizes; (void)n_in; (void)out_size;
}

// Round 7
// 322.111 us; speedup vs baseline: 1.2103x; 1.0810x over previous
//
#include <hip/hip_runtime.h>
#include <hip/hip_bf16.h>
#include <math.h>

typedef __bf16 bf16s;
typedef __attribute__((ext_vector_type(8))) __bf16 bf16x8;
typedef __attribute__((ext_vector_type(4))) __bf16 bf16x4;
typedef __attribute__((ext_vector_type(4))) float f32x4;

#define B_   16
#define S_   1024
#define H_   768
#define T_   64
#define L_   4
#define LE_  32
#define NPAD 4096
#define BS   (B_*S_)    // 16384
#define BNR  (B_*NPAD)  // 65536 rows of X
#define N3   (3*H_)     // 2304

static __device__ __forceinline__ void gload_lds16(const void* g, void* l) {
  __builtin_amdgcn_global_load_lds(
      (const __attribute__((address_space(1))) void*)g,
      (__attribute__((address_space(3))) void*)l, 16, 0, 0);
}

// ---------------- span construction (1 block) ----------------
__global__ __launch_bounds__(1024) void k_build_spans(
    const int* __restrict__ text_mask,   // row 0 used
    int* __restrict__ R, int* __restrict__ pos, int* __restrict__ spoff,
    int* __restrict__ starts, int* __restrict__ ends, int* __restrict__ lens,
    int* __restrict__ meta)
{
  __shared__ int buf[S_];
  int t = threadIdx.x;
  int m = text_mask[t] ? 1 : 0;
  buf[t] = m;
  __syncthreads();
  for (int off = 1; off < S_; off <<= 1) {
    int v = buf[t];
    if (t >= off) v += buf[t - off];
    __syncthreads();
    buf[t] = v;
    __syncthreads();
  }
  int incl = buf[t];
  R[t] = incl;
  if (m) pos[incl - 1] = t;
  int n = buf[S_ - 1];
  __syncthreads();
  int cnt = (t < n) ? min(L_, n - t) : 0;
  buf[t] = cnt;
  __syncthreads();
  for (int off = 1; off < S_; off <<= 1) {
    int v = buf[t];
    if (t >= off) v += buf[t - off];
    __syncthreads();
    buf[t] = v;
    __syncthreads();
  }
  int inc2 = buf[t];
  int base = inc2 - cnt;
  spoff[t] = base;
  if (t == 0) { meta[0] = buf[S_ - 1]; meta[1] = n; }
  __syncthreads();
  if (t < n) {
    int p0 = pos[t];
    for (int k = 0; k < cnt; k++) {
      starts[base + k] = p0;
      ends[base + k]   = pos[t + k];
      lens[base + k]   = k + 1;
    }
  }
}

// ---------------- fused prep: casts + transposes + LT + topicn ----------------
// block ranges: [0,12288) cast hid; [12288,12864) transpose W1x3/W2;
// [12864,13440) cast W2->w2c; [13440,13455) LT; [13455,14479) topicn
__global__ __launch_bounds__(256) void k_prep(
    const float* __restrict__ hid, bf16s* __restrict__ hidb,
    const float* __restrict__ W1, bf16s* __restrict__ wbt,
    const float* __restrict__ W2, bf16s* __restrict__ w2t, bf16s* __restrict__ w2c,
    const float* __restrict__ lemb, float* __restrict__ LT,
    const float* __restrict__ TH, const float* __restrict__ b2,
    bf16s* __restrict__ TN, float* __restrict__ cvec)
{
  __shared__ float tile[64][65];
  __shared__ float red[256];
  int bid = blockIdx.x;
  int t = threadIdx.x;
  if (bid < 12288) {
    int i = bid * 256 + t;           // BS*H/4 groups
    f32x4 v = ((const f32x4*)hid)[i];
    bf16x4 o;
    o[0] = (__bf16)v[0]; o[1] = (__bf16)v[1]; o[2] = (__bf16)v[2]; o[3] = (__bf16)v[3];
    ((bf16x4*)hidb)[i] = o;
  } else if (bid < 12864) {
    int local = bid - 12288;
    int c = local / 144, rem = local % 144;
    const float* in = (c < 3) ? (W1 + (size_t)c * H_ * H_) : W2;
    bf16s* out = (c < 3) ? (wbt + (size_t)c * H_ * H_) : w2t;
    int r0 = (rem / 12) * 64, c0 = (rem % 12) * 64;
    int tr = t >> 4, tc = (t & 15) * 4;
#pragma unroll
    for (int i = 0; i < 4; i++) {
      int row = tr + i * 16;
      f32x4 v = *(const f32x4*)(in + (long)(r0 + row) * H_ + c0 + tc);
      tile[row][tc+0] = v[0]; tile[row][tc+1] = v[1];
      tile[row][tc+2] = v[2]; tile[row][tc+3] = v[3];
    }
    __syncthreads();
#pragma unroll
    for (int i = 0; i < 4; i++) {
      int cc = tr + i * 16;
      bf16x4 o;
      o[0] = (__bf16)tile[tc+0][cc]; o[1] = (__bf16)tile[tc+1][cc];
      o[2] = (__bf16)tile[tc+2][cc]; o[3] = (__bf16)tile[tc+3][cc];
      *(bf16x4*)(out + (long)(c0 + cc) * H_ + r0 + tc) = o;
    }
  } else if (bid < 13440) {
    int i = (bid - 12864) * 256 + t;   // H*H/4 groups
    f32x4 v = ((const f32x4*)W2)[i];
    bf16x4 o;
    o[0] = (__bf16)v[0]; o[1] = (__bf16)v[1]; o[2] = (__bf16)v[2]; o[3] = (__bf16)v[3];
    ((bf16x4*)w2c)[i] = o;
  } else if (bid < 13455) {
    int idx = (bid - 13440) * 256 + t;
    if (idx < (L_ + 1) * H_) {
      int l = idx / H_, h = idx % H_;
      float acc = 0.f;
#pragma unroll
      for (int e = 0; e < LE_; e++) acc += lemb[l * LE_ + e] * W1[(long)(N3 + e) * H_ + h];
      LT[idx] = acc;
    }
  } else {
    int r = bid - 13455;               // topic row 0..1023
    const float* row = TH + (long)r * H_;
    float v0 = row[t], v1 = row[t + 256], v2 = row[t + 512];
    red[t] = v0 * v0 + v1 * v1 + v2 * v2;
    __syncthreads();
    for (int off = 128; off; off >>= 1) {
      if (t < off) red[t] += red[t + off];
      __syncthreads();
    }
    float rn = 1.0f / fmaxf(sqrtf(red[0]), 1e-12f);
    bf16s* o = TN + (long)r * H_;
    o[t] = (__bf16)(v0 * rn); o[t + 256] = (__bf16)(v1 * rn); o[t + 512] = (__bf16)(v2 * rn);
    __syncthreads();
    red[t] = v0 * b2[t] + v1 * b2[t + 256] + v2 * b2[t + 512];
    __syncthreads();
    for (int off = 128; off; off >>= 1) {
      if (t < off) red[t] += red[t + off];
      __syncthreads();
    }
    if (t == 0) cvec[r] = red[0] * rn;
  }
}

// ====== chained 8-phase GEMM core: 3 segments (N-tiles) per block ======
// Per segment: 256x256 C-tile, BK=64, counted vmcnt(6), one prologue total.
// lane mapping per segment: C row = a0+wr*128+fr*16+(l&15); col = cseg+wc*64+fc*16+(l>>4)*4+r
#define BKT 64
#define STG_A(kt_, h_) do { \
    const bf16s* s_ = gA + (long)(h_) * 128 * K + (long)(kt_) * BKT; \
    char* d_ = sA + ((kt_) & 1) * 32768 + (h_) * 16384 + wid * 1024; \
    gload_lds16(s_, d_); \
    gload_lds16(s_ + 64L * K, d_ + 8192); \
  } while (0)
#define STG_B(ct_, kt_, h_) do { \
    const bf16s* s_ = gB + (long)(ct_) * 256 * K + (long)(h_) * 128 * K + (long)(kt_) * BKT; \
    char* d_ = sB + ((kt_) & 1) * 32768 + (h_) * 16384 + wid * 1024; \
    gload_lds16(s_, d_); \
    gload_lds16(s_ + 64L * K, d_ + 8192); \
  } while (0)
#define MFMA_Q(AF_, FR0_, FC_) do { \
    _Pragma("unroll") \
    for (int f_ = 0; f_ < 4; ++f_) { \
      acc[FR0_+f_][FC_] = __builtin_amdgcn_mfma_f32_16x16x32_bf16(bfv[FC_][0], AF_[f_][0], acc[FR0_+f_][FC_], 0, 0, 0); \
      acc[FR0_+f_][FC_] = __builtin_amdgcn_mfma_f32_16x16x32_bf16(bfv[FC_][1], AF_[f_][1], acc[FR0_+f_][FC_], 0, 0, 0); \
    } } while (0)
#define PH_PRE()  __builtin_amdgcn_s_barrier(); \
                  asm volatile("s_waitcnt lgkmcnt(0)" ::: "memory"); \
                  __builtin_amdgcn_s_setprio(1)
#define PH_POST() __builtin_amdgcn_s_setprio(0); \
                  __builtin_amdgcn_s_barrier()

// core: declares acc, runs prologue + 3 segments; EPILOG_(s) runs after each segment.
#define CHAIN_CORE(EPILOG_) \
  const char* aP0 = sA + wr * 16384; \
  const char* aP1 = aP0 + 32768; \
  const char* bP0 = sB + (wc >> 1) * 16384 + (wc & 1) * 8192; \
  const char* bP1 = bP0 + 32768; \
  int lrow = (l & 15) * 128; \
  int ls0 = (((l >> 4) ^ (l & 7)) * 16); \
  f32x4 acc[8][4]; \
  _Pragma("unroll") \
  for (int i_ = 0; i_ < 8; i_++) \
    _Pragma("unroll") \
    for (int j_ = 0; j_ < 4; j_++) acc[i_][j_] = (f32x4){0.f, 0.f, 0.f, 0.f}; \
  STG_B(0, 0, 0); STG_B(0, 0, 1); STG_A(0, 0); STG_A(0, 1); \
  STG_B(0, 1, 0); STG_B(0, 1, 1); STG_A(1, 0); \
  asm volatile("s_waitcnt vmcnt(6)" ::: "memory"); \
  __builtin_amdgcn_s_barrier(); \
  for (int s = 0; s < 3; ++s) { \
    for (int it = 0; it < 6; ++it) { \
      int kt0 = 2 * it; \
      bool nl = !(s == 2 && it == 5); \
      int ctn = (it == 5) ? s + 1 : s; \
      int kn0 = (it == 5) ? 0 : kt0 + 2; \
      int kn1 = (it == 5) ? 1 : kt0 + 3; \
      bf16x8 af0[4][2], af1[4][2], bfv[4][2]; \
      /* phase 1: read af0 + bfv from buf0 (tile kt0); stage A(kt0+1, half1) */ \
      _Pragma("unroll") \
      for (int f = 0; f < 4; ++f) { \
        af0[f][0] = *(const bf16x8*)(aP0 + f * 2048 + lrow + ls0); \
        af0[f][1] = *(const bf16x8*)(aP0 + f * 2048 + lrow + (ls0 ^ 64)); \
      } \
      _Pragma("unroll") \
      for (int c = 0; c < 4; ++c) { \
        bfv[c][0] = *(const bf16x8*)(bP0 + c * 2048 + lrow + ls0); \
        bfv[c][1] = *(const bf16x8*)(bP0 + c * 2048 + lrow + (ls0 ^ 64)); \
      } \
      STG_A(kt0 + 1, 1); \
      PH_PRE(); \
      MFMA_Q(af0, 0, 0); MFMA_Q(af0, 0, 1); \
      PH_POST(); \
      /* phase 2 */ \
      if (nl) STG_B(ctn, kn0, 0); \
      PH_PRE(); \
      MFMA_Q(af0, 0, 2); MFMA_Q(af0, 0, 3); \
      PH_POST(); \
      /* phase 3 */ \
      _Pragma("unroll") \
      for (int f = 0; f < 4; ++f) { \
        af1[f][0] = *(const bf16x8*)(aP0 + (f + 4) * 2048 + lrow + ls0); \
        af1[f][1] = *(const bf16x8*)(aP0 + (f + 4) * 2048 + lrow + (ls0 ^ 64)); \
      } \
      if (nl) STG_B(ctn, kn0, 1); \
      PH_PRE(); \
      MFMA_Q(af1, 4, 0); MFMA_Q(af1, 4, 1); \
      PH_POST(); \
      /* phase 4 */ \
      if (nl) { STG_A(kn0, 0); asm volatile("s_waitcnt vmcnt(6)" ::: "memory"); } \
      else    { asm volatile("s_waitcnt vmcnt(0)" ::: "memory"); } \
      PH_PRE(); \
      MFMA_Q(af1, 4, 2); MFMA_Q(af1, 4, 3); \
      PH_POST(); \
      /* phase 5: tile kt0+1 from buf1 */ \
      _Pragma("unroll") \
      for (int f = 0; f < 4; ++f) { \
        af0[f][0] = *(const bf16x8*)(aP1 + f * 2048 + lrow + ls0); \
        af0[f][1] = *(const bf16x8*)(aP1 + f * 2048 + lrow + (ls0 ^ 64)); \
      } \
      _Pragma("unroll") \
      for (int c = 0; c < 4; ++c) { \
        bfv[c][0] = *(const bf16x8*)(bP1 + c * 2048 + lrow + ls0); \
        bfv[c][1] = *(const bf16x8*)(bP1 + c * 2048 + lrow + (ls0 ^ 64)); \
      } \
      if (nl) STG_A(kn0, 1); \
      PH_PRE(); \
      MFMA_Q(af0, 0, 0); MFMA_Q(af0, 0, 1); \
      PH_POST(); \
      /* phase 6 */ \
      if (nl) STG_B(ctn, kn1, 0); \
      PH_PRE(); \
      MFMA_Q(af0, 0, 2); MFMA_Q(af0, 0, 3); \
      PH_POST(); \
      /* phase 7 */ \
      _Pragma("unroll") \
      for (int f = 0; f < 4; ++f) { \
        af1[f][0] = *(const bf16x8*)(aP1 + (f + 4) * 2048 + lrow + ls0); \
        af1[f][1] = *(const bf16x8*)(aP1 + (f + 4) * 2048 + lrow + (ls0 ^ 64)); \
      } \
      if (nl) STG_B(ctn, kn1, 1); \
      PH_PRE(); \
      MFMA_Q(af1, 4, 0); MFMA_Q(af1, 4, 1); \
      PH_POST(); \
      /* phase 8 */ \
      if (nl) { STG_A(kn1, 0); asm volatile("s_waitcnt vmcnt(6)" ::: "memory"); } \
      else    { asm volatile("s_waitcnt vmcnt(0)" ::: "memory"); } \
      PH_PRE(); \
      MFMA_Q(af1, 4, 2); MFMA_Q(af1, 4, 3); \
      PH_POST(); \
    } \
    EPILOG_(s); \
  }

// ---- GEMM1 + U-GEMM (chained, C written via 16KB sC coalesced epilogue) ----
// blocks [0,192): P = hidb @ wbt^T (16384x2304); blocks [192,196): U = topn @ w2c^T
__global__ __launch_bounds__(512, 1) void k_gemm1u(
    const bf16s* __restrict__ Ah, const bf16s* __restrict__ Bth, bf16s* __restrict__ Ch,
    const bf16s* __restrict__ Au, const bf16s* __restrict__ Btu, bf16s* __restrict__ Cu)
{
  __shared__ __align__(16) char sA[65536];
  __shared__ __align__(16) char sB[65536];
  __shared__ __align__(16) char sC[16384];
  const int K = H_;
  int bid = blockIdx.x;
  const bf16s *A, *Bt;
  bf16s* C;
  long a0, b0base;
  int NN;
  if (bid < 192) {
    int nid = (bid & 7) * 24 + (bid >> 3);   // XCD-chunked bijection over 192
    A = Ah; Bt = Bth; C = Ch; NN = N3;
    a0 = (long)(nid / 3) * 256;
    b0base = (long)(nid % 3) * 768;
  } else {
    A = Au; Bt = Btu; C = Cu; NN = H_;
    a0 = (long)(bid - 192) * 256;
    b0base = 0;
  }
  int tid = threadIdx.x;
  int wid = tid >> 6, l = tid & 63;
  int wr = wid >> 2, wc = wid & 3;
  int srow = tid >> 3;
  int sslot = (tid & 7) ^ (srow & 7);
  const bf16s* gA = A + (a0 + srow) * (long)K + sslot * 8;
  const bf16s* gB = Bt + (b0base + srow) * (long)K + sslot * 8;

#define EPI_C(s_) do { \
    long cb = b0base + (s_) * 256; \
    _Pragma("unroll") \
    for (int e = 0; e < 8; ++e) { \
      if (wr == (e >> 2)) { \
        int f0 = (e & 3) * 2; \
        _Pragma("unroll") \
        for (int ff = 0; ff < 2; ++ff) { \
          int fr = f0 + ff; \
          int row_l = ff * 16 + (l & 15); \
          _Pragma("unroll") \
          for (int fc = 0; fc < 4; ++fc) { \
            int col2 = (wc * 64 + fc * 16 + (l >> 4) * 4) * 2; \
            bf16x4 o; \
            _Pragma("unroll") \
            for (int r = 0; r < 4; ++r) o[r] = (__bf16)acc[fr][fc][r]; \
            *(bf16x4*)(sC + ((row_l * 512 + col2) ^ ((row_l & 7) << 4))) = o; \
          } \
        } \
      } \
      __syncthreads(); \
      _Pragma("unroll") \
      for (int pp = 0; pp < 2; ++pp) { \
        int off = pp * 8192 + tid * 16; \
        int row_l = off >> 9; \
        bf16x8 v = *(const bf16x8*)(sC + (off ^ ((row_l & 7) << 4))); \
        *(bf16x8*)(C + (a0 + e * 32 + row_l) * (long)NN + cb + ((off & 511) >> 1)) = v; \
      } \
      __syncthreads(); \
    } \
    _Pragma("unroll") \
    for (int i_ = 0; i_ < 8; i_++) \
      _Pragma("unroll") \
      for (int j_ = 0; j_ < 4; j_++) acc[i_][j_] = (f32x4){0.f, 0.f, 0.f, 0.f}; \
  } while (0)

  CHAIN_CORE(EPI_C)
#undef EPI_C
}

// ---- chained norm-only GEMM: ssbuf[row] = sum over 768 cols of (X@W2^T + b2)^2 ----
__global__ __launch_bounds__(512, 1) void k_gemmnorm(
    const bf16s* __restrict__ Ax, const bf16s* __restrict__ Btw,
    const float* __restrict__ bias, float* __restrict__ ssbuf)
{
  __shared__ __align__(16) char sA[65536];
  __shared__ __align__(16) char sB[65536];
  const int K = H_;
  int bid = blockIdx.x;
  int nid = (bid & 7) * 32 + (bid >> 3);     // 256 blocks = 1 mt each
  long a0 = (long)nid * 256;
  long b0base = 0;
  int tid = threadIdx.x;
  int wid = tid >> 6, l = tid & 63;
  int wr = wid >> 2, wc = wid & 3;
  int srow = tid >> 3;
  int sslot = (tid & 7) ^ (srow & 7);
  const bf16s* gA = Ax + (a0 + srow) * (long)K + sslot * 8;
  const bf16s* gB = Btw + (b0base + srow) * (long)K + sslot * 8;
  float ssp[8] = {0.f, 0.f, 0.f, 0.f, 0.f, 0.f, 0.f, 0.f};

#define EPI_N(s_) do { \
    f32x4 bb[4]; \
    _Pragma("unroll") \
    for (int fc = 0; fc < 4; ++fc) \
      bb[fc] = *(const f32x4*)(bias + (s_) * 256 + wc * 64 + fc * 16 + (l >> 4) * 4); \
    _Pragma("unroll") \
    for (int fr = 0; fr < 8; ++fr) { \
      float p = 0.f; \
      _Pragma("unroll") \
      for (int fc = 0; fc < 4; ++fc) { \
        _Pragma("unroll") \
        for (int r = 0; r < 4; ++r) { \
          float y = acc[fr][fc][r] + bb[fc][r]; \
          p += y * y; \
        } \
        acc[fr][fc] = (f32x4){0.f, 0.f, 0.f, 0.f}; \
      } \
      ssp[fr] += p; \
    } \
  } while (0)

  CHAIN_CORE(EPI_N)
#undef EPI_N

  // cross-wave reduction: 4 wc-waves each hold 192-of-768-column partial
  // sums for the same rows. Stage to LDS (sA is dead: pipeline drained),
  // then one coalesced store of the full row sums.  [r6 bug: plain store
  // without this reduction -> ssbuf = one wave's slice -> scores ~2x]
  float* sred = (float*)sA;
#pragma unroll
  for (int fr = 0; fr < 8; ++fr) {
    float p = ssp[fr];
    p += __shfl_xor(p, 16);
    p += __shfl_xor(p, 32);
    if (l < 16) sred[wc * 256 + wr * 128 + fr * 16 + l] = p;
  }
  __syncthreads();
  if (tid < 256) {
    ssbuf[a0 + tid] = sred[tid] + sred[256 + tid] + sred[512 + tid] + sred[768 + tid];
  }
}

#undef CHAIN_CORE
#undef STG_A
#undef STG_B
#undef MFMA_Q
#undef PH_PRE
#undef PH_POST

// ---------------- z1 assemble + GELU -> X (bf16x8, mean direct, len<=4) ----
__global__ __launch_bounds__(256) void k_z1(
    const bf16s* __restrict__ P,
    const float* __restrict__ LT, const float* __restrict__ b1,
    const int* __restrict__ starts, const int* __restrict__ ends,
    const int* __restrict__ lens, const int* __restrict__ meta,
    bf16s* __restrict__ X)
{
  int idx = blockIdx.x * 256 + threadIdx.x;  // BNR * 96
  int h8 = idx % 96; int rest = idx / 96;
  int nid = rest % NPAD; int b = rest / NPAD;
  int h = h8 * 8;
  int N = meta[0];
  long orow = (long)(b * NPAD + nid) * H_ + h;
  if (nid >= N) {
    bf16x8 z;
#pragma unroll
    for (int j = 0; j < 8; j++) z[j] = (__bf16)0.f;
    *(bf16x8*)(X + orow) = z;
    return;
  }
  int sa = starts[nid], se = ends[nid], ln = lens[nid];
  float il = 1.0f / (float)ln;
  bf16x8 vs = *(const bf16x8*)(P + (long)(b * S_ + sa) * N3 + h);
  bf16x8 ve = *(const bf16x8*)(P + (long)(b * S_ + se) * N3 + H_ + h);
  float mv[8] = {0.f, 0.f, 0.f, 0.f, 0.f, 0.f, 0.f, 0.f};
  for (int i = sa; i <= se; i++) {
    bf16x8 vc = *(const bf16x8*)(P + (long)(b * S_ + i) * N3 + 2 * H_ + h);
#pragma unroll
    for (int j = 0; j < 8; j++) mv[j] += (float)vc[j];
  }
  f32x4 lt0 = *(const f32x4*)(LT + (long)ln * H_ + h);
  f32x4 lt1 = *(const f32x4*)(LT + (long)ln * H_ + h + 4);
  f32x4 bb0 = *(const f32x4*)(b1 + h);
  f32x4 bb1 = *(const f32x4*)(b1 + h + 4);
  bf16x8 o;
#pragma unroll
  for (int j = 0; j < 8; j++) {
    float ltv = (j < 4) ? lt0[j] : lt1[j - 4];
    float bbv = (j < 4) ? bb0[j] : bb1[j - 4];
    float x = (float)vs[j] + (float)ve[j] + mv[j] * il + ltv + bbv;
    float g = 0.5f * x * (1.0f + erff(x * 0.70710678118654752f));
    o[j] = (__bf16)g;
  }
  *(bf16x8*)(X + orow) = o;
}

// ------- sim from X: scores[b,n] = max_t (U[t]·X_n + c[t]) * rsqrt(ss[n]) ----
__global__ __launch_bounds__(256) void k_simx(
    const bf16s* __restrict__ X, const bf16s* __restrict__ U,
    const float* __restrict__ cvec, const float* __restrict__ ssbuf,
    const int* __restrict__ tmask, float* __restrict__ scores)
{
  int b = blockIdx.y;
  int wid = threadIdx.x >> 6, l = threadIdx.x & 63;
  int st = blockIdx.x * 4 + wid;
  int span = st * 16 + (l & 15);
  const bf16s* xrow = X + (long)(b * NPAD + span) * H_ + (l >> 4) * 8;
  const bf16s* ubase = U + (long)b * T_ * H_ + (l >> 4) * 8;
  f32x4 acc[4];
#pragma unroll
  for (int tt = 0; tt < 4; tt++) acc[tt] = (f32x4){0.f, 0.f, 0.f, 0.f};
  for (int kk = 0; kk < H_ / 32; kk++) {
    bf16x8 av = *(const bf16x8*)(xrow + kk * 32);
#pragma unroll
    for (int tt = 0; tt < 4; tt++) {
      bf16x8 bv = *(const bf16x8*)(ubase + (long)(tt * 16 + (l & 15)) * H_ + kk * 32);
      acc[tt] = __builtin_amdgcn_mfma_f32_16x16x32_bf16(av, bv, acc[tt], 0, 0, 0);
    }
  }
  const int* tm = tmask + b * T_;
  bool msk[4];
  float cv[4];
#pragma unroll
  for (int tt = 0; tt < 4; tt++) {
    int tcol = tt * 16 + (l & 15);
    msk[tt] = tm[tcol] != 0;
    cv[tt] = cvec[b * T_ + tcol];
  }
  float best[4];
#pragma unroll
  for (int r = 0; r < 4; r++) {
    float v = -INFINITY;
#pragma unroll
    for (int tt = 0; tt < 4; tt++) if (msk[tt]) v = fmaxf(v, acc[tt][r] + cv[tt]);
    best[r] = v;
  }
#pragma unroll
  for (int off = 8; off; off >>= 1)
#pragma unroll
    for (int r = 0; r < 4; r++) best[r] = fmaxf(best[r], __shfl_xor(best[r], off));
  if ((l & 15) == 0) {
    int srow = st * 16 + (l >> 4) * 4;
#pragma unroll
    for (int r = 0; r < 4; r++) {
      float ss = ssbuf[b * NPAD + srow + r];
      scores[b * NPAD + srow + r] = best[r] / fmaxf(sqrtf(ss), 1e-12f);
    }
  }
}

// ---------------- token max ----------------
__global__ __launch_bounds__(256) void k_token(
    const int* __restrict__ text_mask,
    const int* __restrict__ R, const int* __restrict__ spoff,
    const int* __restrict__ meta, const float* __restrict__ scores,
    float* __restrict__ out)
{
  int idx = blockIdx.x * 256 + threadIdx.x;  // B*S
  int s = idx % S_, b = idx / S_;
  if (!text_mask[b * S_ + s]) { out[idx] = -INFINITY; return; }
  int n = meta[1];
  int r1 = R[s];
  int le = r1 - 1;                         // largest i with pos[i] <= s
  int ge = text_mask[s] ? (r1 - 1) : r1;   // smallest j with pos[j] >= s (row 0)
  float best = -INFINITY;
  if (le >= 0 && ge < n) {
    int i0 = max(0, ge - (L_ - 1));
    for (int i = i0; i <= le; i++) {
      int jmax = min(i + L_ - 1, n - 1);
      int off = spoff[i];
      for (int j = max(i, ge); j <= jmax; j++)
        best = fmaxf(best, scores[b * NPAD + off + (j - i)]);
    }
  }
  out[idx] = best;
}

// ---------------- ws-too-small sentinel ----------------
__global__ __launch_bounds__(256) void k_sentinel(float* __restrict__ out) {
  int i = blockIdx.x * 256 + threadIdx.x;
  if (i < BS) out[i] = 12345.0f;
}

// ---------------- launch ----------------
extern "C" void kernel_launch(void* const* d_in, const int* in_sizes, int n_in,
                              void* d_out, int out_size, void* d_ws, size_t ws_size,
                              hipStream_t stream) {
  const float* hid = (const float*)d_in[0];
  const float* th  = (const float*)d_in[1];
  const int* tmask = (const int*)d_in[2];
  const int* xmask = (const int*)d_in[3];
  const float* lemb = (const float*)d_in[4];
  const float* W1   = (const float*)d_in[5];
  const float* b1   = (const float*)d_in[6];
  const float* W2   = (const float*)d_in[7];
  const float* b2   = (const float*)d_in[8];
  float* out = (float*)d_out;

  char* w = (char*)d_ws;
  auto alloc = [&](size_t bytes) {
    char* p = w; w += (bytes + 255) & ~(size_t)255; return p;
  };
  // small buffers (~10 MB)
  bf16s* wbt   = (bf16s*)alloc((size_t)N3 * H_ * 2);
  bf16s* w2t   = (bf16s*)alloc((size_t)H_ * H_ * 2);
  bf16s* w2c   = (bf16s*)alloc((size_t)H_ * H_ * 2);
  float* LT    = (float*)alloc((size_t)(L_ + 1) * H_ * 4);
  bf16s* topn  = (bf16s*)alloc((size_t)B_ * T_ * H_ * 2);
  bf16s* U     = (bf16s*)alloc((size_t)B_ * T_ * H_ * 2);
  float* cvec  = (float*)alloc((size_t)B_ * T_ * 4);
  float* ssbuf = (float*)alloc((size_t)BNR * 4);
  float* scores= (float*)alloc((size_t)B_ * NPAD * 4);
  int* R       = (int*)alloc(S_ * 4);
  int* pos     = (int*)alloc(S_ * 4);
  int* spoff   = (int*)alloc(S_ * 4);
  int* starts  = (int*)alloc(NPAD * 4);
  int* ends    = (int*)alloc(NPAD * 4);
  int* lens    = (int*)alloc(NPAD * 4);
  int* meta    = (int*)alloc(2 * 4);
  // region A: [hidb | P] (100.66 MB)
  char* regionA = alloc((size_t)BS * H_ * 2 + (size_t)BS * N3 * 2);
  bf16s* hidb  = (bf16s*)regionA;
  bf16s* P     = (bf16s*)(regionA + (size_t)BS * H_ * 2);
  // region B: X (100.66 MB)
  bf16s* X     = (bf16s*)alloc((size_t)BNR * H_ * 2);

  size_t required = (size_t)(w - (char*)d_ws);
  if (required > ws_size) {
    k_sentinel<<<(BS + 255) / 256, 256, 0, stream>>>(out);
    return;
  }

  k_build_spans<<<1, 1024, 0, stream>>>(xmask, R, pos, spoff, starts, ends, lens, meta);
  k_prep<<<14479, 256, 0, stream>>>(hid, hidb, W1, wbt, W2, w2t, w2c,
                                    lemb, LT, th, b2, topn, cvec);

  // GEMM1 (P = hidb @ wbt^T, chained x3 over N) + U-GEMM (U = topn @ w2c^T)
  k_gemm1u<<<196, 512, 0, stream>>>(hidb, wbt, P, topn, w2c, U);

  k_z1<<<(BNR * 96) / 256, 256, 0, stream>>>(P, LT, b1, starts, ends, lens, meta, X);

  // norm-only GEMM2 chained over all 768 cols: ssbuf = rowwise ||X@W2^T + b2||^2
  k_gemmnorm<<<256, 512, 0, stream>>>(X, w2t, b2, ssbuf);

  k_simx<<<dim3(NPAD / 64, B_), 256, 0, stream>>>(X, U, cvec, ssbuf, tmask, scores);
  k_token<<<(B_ * S_) / 256, 256, 0, stream>>>(xmask, R, spoff, meta, scores, out);
  (void)in_sizes; (void)n_in; (void)out_size;
}

// Round 8
// 302.510 us; speedup vs baseline: 1.2887x; 1.0648x over previous
//
#include <hip/hip_runtime.h>
#include <hip/hip_bf16.h>
#include <math.h>

typedef __bf16 bf16s;
typedef __attribute__((ext_vector_type(8))) __bf16 bf16x8;
typedef __attribute__((ext_vector_type(4))) __bf16 bf16x4;
typedef __attribute__((ext_vector_type(4))) float f32x4;

#define B_   16
#define S_   1024
#define H_   768
#define T_   64
#define L_   4
#define LE_  32
#define NPAD 4096
#define BS   (B_*S_)    // 16384
#define BNR  (B_*NPAD)  // 65536 rows of X
#define N3   (3*H_)     // 2304

static __device__ __forceinline__ void gload_lds16(const void* g, void* l) {
  __builtin_amdgcn_global_load_lds(
      (const __attribute__((address_space(1))) void*)g,
      (__attribute__((address_space(3))) void*)l, 16, 0, 0);
}

// ---------------- span construction (1 block) ----------------
__global__ __launch_bounds__(1024) void k_build_spans(
    const int* __restrict__ text_mask,   // row 0 used
    int* __restrict__ R, int* __restrict__ pos, int* __restrict__ spoff,
    int* __restrict__ starts, int* __restrict__ ends, int* __restrict__ lens,
    int* __restrict__ meta)
{
  __shared__ int buf[S_];
  int t = threadIdx.x;
  int m = text_mask[t] ? 1 : 0;
  buf[t] = m;
  __syncthreads();
  for (int off = 1; off < S_; off <<= 1) {
    int v = buf[t];
    if (t >= off) v += buf[t - off];
    __syncthreads();
    buf[t] = v;
    __syncthreads();
  }
  int incl = buf[t];
  R[t] = incl;
  if (m) pos[incl - 1] = t;
  int n = buf[S_ - 1];
  __syncthreads();
  int cnt = (t < n) ? min(L_, n - t) : 0;
  buf[t] = cnt;
  __syncthreads();
  for (int off = 1; off < S_; off <<= 1) {
    int v = buf[t];
    if (t >= off) v += buf[t - off];
    __syncthreads();
    buf[t] = v;
    __syncthreads();
  }
  int inc2 = buf[t];
  int base = inc2 - cnt;
  spoff[t] = base;
  if (t == 0) { meta[0] = buf[S_ - 1]; meta[1] = n; }
  __syncthreads();
  if (t < n) {
    int p0 = pos[t];
    for (int k = 0; k < cnt; k++) {
      starts[base + k] = p0;
      ends[base + k]   = pos[t + k];
      lens[base + k]   = k + 1;
    }
  }
}

// ---------------- fused prep: casts + transposes + LT + topicn ----------------
__global__ __launch_bounds__(256) void k_prep(
    const float* __restrict__ hid, bf16s* __restrict__ hidb,
    const float* __restrict__ W1, bf16s* __restrict__ wbt,
    const float* __restrict__ W2, bf16s* __restrict__ w2t, bf16s* __restrict__ w2c,
    const float* __restrict__ lemb, float* __restrict__ LT,
    const float* __restrict__ TH, const float* __restrict__ b2,
    bf16s* __restrict__ TN, float* __restrict__ cvec)
{
  __shared__ float tile[64][65];
  __shared__ float red[256];
  int bid = blockIdx.x;
  int t = threadIdx.x;
  if (bid < 12288) {
    int i = bid * 256 + t;           // BS*H/4 groups
    f32x4 v = ((const f32x4*)hid)[i];
    bf16x4 o;
    o[0] = (__bf16)v[0]; o[1] = (__bf16)v[1]; o[2] = (__bf16)v[2]; o[3] = (__bf16)v[3];
    ((bf16x4*)hidb)[i] = o;
  } else if (bid < 12864) {
    int local = bid - 12288;
    int c = local / 144, rem = local % 144;
    const float* in = (c < 3) ? (W1 + (size_t)c * H_ * H_) : W2;
    bf16s* out = (c < 3) ? (wbt + (size_t)c * H_ * H_) : w2t;
    int r0 = (rem / 12) * 64, c0 = (rem % 12) * 64;
    int tr = t >> 4, tc = (t & 15) * 4;
#pragma unroll
    for (int i = 0; i < 4; i++) {
      int row = tr + i * 16;
      f32x4 v = *(const f32x4*)(in + (long)(r0 + row) * H_ + c0 + tc);
      tile[row][tc+0] = v[0]; tile[row][tc+1] = v[1];
      tile[row][tc+2] = v[2]; tile[row][tc+3] = v[3];
    }
    __syncthreads();
#pragma unroll
    for (int i = 0; i < 4; i++) {
      int cc = tr + i * 16;
      bf16x4 o;
      o[0] = (__bf16)tile[tc+0][cc]; o[1] = (__bf16)tile[tc+1][cc];
      o[2] = (__bf16)tile[tc+2][cc]; o[3] = (__bf16)tile[tc+3][cc];
      *(bf16x4*)(out + (long)(c0 + cc) * H_ + r0 + tc) = o;
    }
  } else if (bid < 13440) {
    int i = (bid - 12864) * 256 + t;   // H*H/4 groups
    f32x4 v = ((const f32x4*)W2)[i];
    bf16x4 o;
    o[0] = (__bf16)v[0]; o[1] = (__bf16)v[1]; o[2] = (__bf16)v[2]; o[3] = (__bf16)v[3];
    ((bf16x4*)w2c)[i] = o;
  } else if (bid < 13455) {
    int idx = (bid - 13440) * 256 + t;
    if (idx < (L_ + 1) * H_) {
      int l = idx / H_, h = idx % H_;
      float acc = 0.f;
#pragma unroll
      for (int e = 0; e < LE_; e++) acc += lemb[l * LE_ + e] * W1[(long)(N3 + e) * H_ + h];
      LT[idx] = acc;
    }
  } else {
    int r = bid - 13455;               // topic row 0..1023
    const float* row = TH + (long)r * H_;
    float v0 = row[t], v1 = row[t + 256], v2 = row[t + 512];
    red[t] = v0 * v0 + v1 * v1 + v2 * v2;
    __syncthreads();
    for (int off = 128; off; off >>= 1) {
      if (t < off) red[t] += red[t + off];
      __syncthreads();
    }
    float rn = 1.0f / fmaxf(sqrtf(red[0]), 1e-12f);
    bf16s* o = TN + (long)r * H_;
    o[t] = (__bf16)(v0 * rn); o[t + 256] = (__bf16)(v1 * rn); o[t + 512] = (__bf16)(v2 * rn);
    __syncthreads();
    red[t] = v0 * b2[t] + v1 * b2[t + 256] + v2 * b2[t + 512];
    __syncthreads();
    for (int off = 128; off; off >>= 1) {
      if (t < off) red[t] += red[t + off];
      __syncthreads();
    }
    if (t == 0) cvec[r] = red[0] * rn;
  }
}

// ====== single-tile 8-phase GEMM (r5-proven structure) ======
// C(256x256 tile) = A(MxK) * Bt(NxK)^T; bf16 in/out, f32 acc.
// LDS per matrix: [2 buf][2 half][128 rows][8 x 16B slots], stored slot = s^(row&7).
#define BKT 64
#define STG1_A(kt_, h_) do { \
    const bf16s* s_ = gA + (long)(h_) * 128 * K + (long)(kt_) * BKT; \
    char* d_ = sA + ((kt_) & 1) * 32768 + (h_) * 16384 + wid * 1024; \
    gload_lds16(s_, d_); \
    gload_lds16(s_ + 64L * K, d_ + 8192); \
  } while (0)
#define STG1_B(kt_, h_) do { \
    const bf16s* s_ = gB + (long)(h_) * 128 * K + (long)(kt_) * BKT; \
    char* d_ = sB + ((kt_) & 1) * 32768 + (h_) * 16384 + wid * 1024; \
    gload_lds16(s_, d_); \
    gload_lds16(s_ + 64L * K, d_ + 8192); \
  } while (0)
#define MFMA_Q(AF_, FR0_, FC_) do { \
    _Pragma("unroll") \
    for (int f_ = 0; f_ < 4; ++f_) { \
      acc[FR0_+f_][FC_] = __builtin_amdgcn_mfma_f32_16x16x32_bf16(bfv[FC_][0], AF_[f_][0], acc[FR0_+f_][FC_], 0, 0, 0); \
      acc[FR0_+f_][FC_] = __builtin_amdgcn_mfma_f32_16x16x32_bf16(bfv[FC_][1], AF_[f_][1], acc[FR0_+f_][FC_], 0, 0, 0); \
    } } while (0)
#define PH_PRE()  __builtin_amdgcn_s_barrier(); \
                  asm volatile("s_waitcnt lgkmcnt(0)" ::: "memory"); \
                  __builtin_amdgcn_s_setprio(1)
#define PH_POST() __builtin_amdgcn_s_setprio(0); \
                  __builtin_amdgcn_s_barrier()

// blocks map (bijective XCD swizzle over 588): nid<576 -> P-tile; else U-tile
__global__ __launch_bounds__(512, 2) void k_gemm8p(
    const bf16s* __restrict__ Ah, const bf16s* __restrict__ Bth, bf16s* __restrict__ Ch,
    const bf16s* __restrict__ Au, const bf16s* __restrict__ Btu, bf16s* __restrict__ Cu)
{
  __shared__ __align__(16) char sA[65536];
  __shared__ __align__(16) char sB[65536];
  const int K = H_;

  int nwg = gridDim.x, bid = blockIdx.x;
  int q = nwg >> 3, rr = nwg & 7;
  int xcd = bid & 7, ix = bid >> 3;
  int nid = (xcd < rr ? xcd * (q + 1) : rr * (q + 1) + (xcd - rr) * q) + ix;

  const bf16s *A, *Bt;
  bf16s* C;
  long a0, b0;
  int NN;
  if (nid < 576) {
    A = Ah; Bt = Bth; C = Ch; NN = N3;
    a0 = (long)(nid / 9) * 256;
    b0 = (long)(nid % 9) * 256;
  } else {
    int u = nid - 576;
    A = Au; Bt = Btu; C = Cu; NN = H_;
    a0 = (long)(u / 3) * 256;
    b0 = (long)(u % 3) * 256;
  }

  int tid = threadIdx.x;
  int wid = tid >> 6, l = tid & 63;
  int wr = wid >> 2, wc = wid & 3;          // 2x4 waves; wave tile 128x64

  int srow = tid >> 3;
  int sslot = (tid & 7) ^ (srow & 7);
  const bf16s* gA = A + (a0 + srow) * (long)K + sslot * 8;
  const bf16s* gB = Bt + (b0 + srow) * (long)K + sslot * 8;

  const char* aP0 = sA + wr * 16384;
  const char* aP1 = aP0 + 32768;
  const char* bP0 = sB + (wc >> 1) * 16384 + (wc & 1) * 8192;
  const char* bP1 = bP0 + 32768;
  int lrow = (l & 15) * 128;
  int ls0 = (((l >> 4) ^ (l & 7)) * 16);

  f32x4 acc[8][4];
#pragma unroll
  for (int i = 0; i < 8; i++)
#pragma unroll
    for (int j = 0; j < 4; j++) acc[i][j] = (f32x4){0.f, 0.f, 0.f, 0.f};

  int NT = K / BKT;        // 12
  int NITER = NT / 2;      // 6

  // prologue: tile0 {B0,B1,A0,A1}, tile1 {B0,B1,A0}; wait tile0
  STG1_B(0, 0); STG1_B(0, 1); STG1_A(0, 0); STG1_A(0, 1);
  STG1_B(1, 0); STG1_B(1, 1); STG1_A(1, 0);
  asm volatile("s_waitcnt vmcnt(6)" ::: "memory");
  __builtin_amdgcn_s_barrier();

  for (int it = 0; it < NITER; ++it) {
    int t0 = 2 * it, t1 = t0 + 1;
    bool nl = (it != NITER - 1);
    bf16x8 af0[4][2], af1[4][2], bfv[4][2];

    // phase 1: read af0 + bfv from buf0; stage t1.A1
#pragma unroll
    for (int f = 0; f < 4; ++f) {
      af0[f][0] = *(const bf16x8*)(aP0 + f * 2048 + lrow + ls0);
      af0[f][1] = *(const bf16x8*)(aP0 + f * 2048 + lrow + (ls0 ^ 64));
    }
#pragma unroll
    for (int c = 0; c < 4; ++c) {
      bfv[c][0] = *(const bf16x8*)(bP0 + c * 2048 + lrow + ls0);
      bfv[c][1] = *(const bf16x8*)(bP0 + c * 2048 + lrow + (ls0 ^ 64));
    }
    STG1_A(t1, 1);
    PH_PRE();
    MFMA_Q(af0, 0, 0); MFMA_Q(af0, 0, 1);
    PH_POST();

    // phase 2: stage (t0+2).B0
    if (nl) STG1_B(t0 + 2, 0);
    PH_PRE();
    MFMA_Q(af0, 0, 2); MFMA_Q(af0, 0, 3);
    PH_POST();

    // phase 3: read af1 from buf0; stage (t0+2).B1
#pragma unroll
    for (int f = 0; f < 4; ++f) {
      af1[f][0] = *(const bf16x8*)(aP0 + (f + 4) * 2048 + lrow + ls0);
      af1[f][1] = *(const bf16x8*)(aP0 + (f + 4) * 2048 + lrow + (ls0 ^ 64));
    }
    if (nl) STG1_B(t0 + 2, 1);
    PH_PRE();
    MFMA_Q(af1, 4, 0); MFMA_Q(af1, 4, 1);
    PH_POST();

    // phase 4: stage (t0+2).A0; counted vmcnt (t1 fully landed)
    if (nl) { STG1_A(t0 + 2, 0); asm volatile("s_waitcnt vmcnt(6)" ::: "memory"); }
    else    { asm volatile("s_waitcnt vmcnt(0)" ::: "memory"); }
    PH_PRE();
    MFMA_Q(af1, 4, 2); MFMA_Q(af1, 4, 3);
    PH_POST();

    // phase 5: read af0 + bfv from buf1 (tile t1); stage (t0+2).A1
#pragma unroll
    for (int f = 0; f < 4; ++f) {
      af0[f][0] = *(const bf16x8*)(aP1 + f * 2048 + lrow + ls0);
      af0[f][1] = *(const bf16x8*)(aP1 + f * 2048 + lrow + (ls0 ^ 64));
    }
#pragma unroll
    for (int c = 0; c < 4; ++c) {
      bfv[c][0] = *(const bf16x8*)(bP1 + c * 2048 + lrow + ls0);
      bfv[c][1] = *(const bf16x8*)(bP1 + c * 2048 + lrow + (ls0 ^ 64));
    }
    if (nl) STG1_A(t0 + 2, 1);
    PH_PRE();
    MFMA_Q(af0, 0, 0); MFMA_Q(af0, 0, 1);
    PH_POST();

    // phase 6: stage (t1+2).B0
    if (nl) STG1_B(t1 + 2, 0);
    PH_PRE();
    MFMA_Q(af0, 0, 2); MFMA_Q(af0, 0, 3);
    PH_POST();

    // phase 7: read af1 from buf1; stage (t1+2).B1
#pragma unroll
    for (int f = 0; f < 4; ++f) {
      af1[f][0] = *(const bf16x8*)(aP1 + (f + 4) * 2048 + lrow + ls0);
      af1[f][1] = *(const bf16x8*)(aP1 + (f + 4) * 2048 + lrow + (ls0 ^ 64));
    }
    if (nl) STG1_B(t1 + 2, 1);
    PH_PRE();
    MFMA_Q(af1, 4, 0); MFMA_Q(af1, 4, 1);
    PH_POST();

    // phase 8: stage (t1+2).A0; counted vmcnt
    if (nl) { STG1_A(t1 + 2, 0); asm volatile("s_waitcnt vmcnt(6)" ::: "memory"); }
    else    { asm volatile("s_waitcnt vmcnt(0)" ::: "memory"); }
    PH_PRE();
    MFMA_Q(af1, 4, 2); MFMA_Q(af1, 4, 3);
    PH_POST();
  }

  // epilogue (r5-proven direct stores): lane l holds
  // C[a0+wr*128+fr*16+(l&15)][b0+wc*64+fc*16+(l>>4)*4 + r]
#pragma unroll
  for (int fc = 0; fc < 4; fc++) {
    long n0 = b0 + wc * 64 + fc * 16 + (l >> 4) * 4;
#pragma unroll
    for (int fr = 0; fr < 8; fr++) {
      long mrow = a0 + wr * 128 + fr * 16 + (l & 15);
      bf16x4 o;
#pragma unroll
      for (int r = 0; r < 4; r++) o[r] = (__bf16)acc[fr][fc][r];
      *(bf16x4*)(C + mrow * (long)NN + n0) = o;
    }
  }
}

// ====== chained 3-segment core for gemmnorm (r7-proven) ======
#define STG_A(kt_, h_) do { \
    const bf16s* s_ = gA + (long)(h_) * 128 * K + (long)(kt_) * BKT; \
    char* d_ = sA + ((kt_) & 1) * 32768 + (h_) * 16384 + wid * 1024; \
    gload_lds16(s_, d_); \
    gload_lds16(s_ + 64L * K, d_ + 8192); \
  } while (0)
#define STG_B(ct_, kt_, h_) do { \
    const bf16s* s_ = gB + (long)(ct_) * 256 * K + (long)(h_) * 128 * K + (long)(kt_) * BKT; \
    char* d_ = sB + ((kt_) & 1) * 32768 + (h_) * 16384 + wid * 1024; \
    gload_lds16(s_, d_); \
    gload_lds16(s_ + 8192); \
  } while (0)
// NOTE: the second gload of STG_B must load s_+64*K; fixed below via explicit macro.
#undef STG_B
#define STG_B(ct_, kt_, h_) do { \
    const bf16s* s_ = gB + (long)(ct_) * 256 * K + (long)(h_) * 128 * K + (long)(kt_) * BKT; \
    char* d_ = sB + ((kt_) & 1) * 32768 + (h_) * 16384 + wid * 1024; \
    gload_lds16(s_, d_); \
    gload_lds16(s_ + 64L * K, d_ + 8192); \
  } while (0)

#define CHAIN_CORE(EPILOG_) \
  const char* aP0 = sA + wr * 16384; \
  const char* aP1 = aP0 + 32768; \
  const char* bP0 = sB + (wc >> 1) * 16384 + (wc & 1) * 8192; \
  const char* bP1 = bP0 + 32768; \
  int lrow = (l & 15) * 128; \
  int ls0 = (((l >> 4) ^ (l & 7)) * 16); \
  f32x4 acc[8][4]; \
  _Pragma("unroll") \
  for (int i_ = 0; i_ < 8; i_++) \
    _Pragma("unroll") \
    for (int j_ = 0; j_ < 4; j_++) acc[i_][j_] = (f32x4){0.f, 0.f, 0.f, 0.f}; \
  STG_B(0, 0, 0); STG_B(0, 0, 1); STG_A(0, 0); STG_A(0, 1); \
  STG_B(0, 1, 0); STG_B(0, 1, 1); STG_A(1, 0); \
  asm volatile("s_waitcnt vmcnt(6)" ::: "memory"); \
  __builtin_amdgcn_s_barrier(); \
  for (int s = 0; s < 3; ++s) { \
    for (int it = 0; it < 6; ++it) { \
      int kt0 = 2 * it; \
      bool nl = !(s == 2 && it == 5); \
      int ctn = (it == 5) ? s + 1 : s; \
      int kn0 = (it == 5) ? 0 : kt0 + 2; \
      int kn1 = (it == 5) ? 1 : kt0 + 3; \
      bf16x8 af0[4][2], af1[4][2], bfv[4][2]; \
      _Pragma("unroll") \
      for (int f = 0; f < 4; ++f) { \
        af0[f][0] = *(const bf16x8*)(aP0 + f * 2048 + lrow + ls0); \
        af0[f][1] = *(const bf16x8*)(aP0 + f * 2048 + lrow + (ls0 ^ 64)); \
      } \
      _Pragma("unroll") \
      for (int c = 0; c < 4; ++c) { \
        bfv[c][0] = *(const bf16x8*)(bP0 + c * 2048 + lrow + ls0); \
        bfv[c][1] = *(const bf16x8*)(bP0 + c * 2048 + lrow + (ls0 ^ 64)); \
      } \
      STG_A(kt0 + 1, 1); \
      PH_PRE(); \
      MFMA_Q(af0, 0, 0); MFMA_Q(af0, 0, 1); \
      PH_POST(); \
      if (nl) STG_B(ctn, kn0, 0); \
      PH_PRE(); \
      MFMA_Q(af0, 0, 2); MFMA_Q(af0, 0, 3); \
      PH_POST(); \
      _Pragma("unroll") \
      for (int f = 0; f < 4; ++f) { \
        af1[f][0] = *(const bf16x8*)(aP0 + (f + 4) * 2048 + lrow + ls0); \
        af1[f][1] = *(const bf16x8*)(aP0 + (f + 4) * 2048 + lrow + (ls0 ^ 64)); \
      } \
      if (nl) STG_B(ctn, kn0, 1); \
      PH_PRE(); \
      MFMA_Q(af1, 4, 0); MFMA_Q(af1, 4, 1); \
      PH_POST(); \
      if (nl) { STG_A(kn0, 0); asm volatile("s_waitcnt vmcnt(6)" ::: "memory"); } \
      else    { asm volatile("s_waitcnt vmcnt(0)" ::: "memory"); } \
      PH_PRE(); \
      MFMA_Q(af1, 4, 2); MFMA_Q(af1, 4, 3); \
      PH_POST(); \
      _Pragma("unroll") \
      for (int f = 0; f < 4; ++f) { \
        af0[f][0] = *(const bf16x8*)(aP1 + f * 2048 + lrow + ls0); \
        af0[f][1] = *(const bf16x8*)(aP1 + f * 2048 + lrow + (ls0 ^ 64)); \
      } \
      _Pragma("unroll") \
      for (int c = 0; c < 4; ++c) { \
        bfv[c][0] = *(const bf16x8*)(bP1 + c * 2048 + lrow + ls0); \
        bfv[c][1] = *(const bf16x8*)(bP1 + c * 2048 + lrow + (ls0 ^ 64)); \
      } \
      if (nl) STG_A(kn0, 1); \
      PH_PRE(); \
      MFMA_Q(af0, 0, 0); MFMA_Q(af0, 0, 1); \
      PH_POST(); \
      if (nl) STG_B(ctn, kn1, 0); \
      PH_PRE(); \
      MFMA_Q(af0, 0, 2); MFMA_Q(af0, 0, 3); \
      PH_POST(); \
      _Pragma("unroll") \
      for (int f = 0; f < 4; ++f) { \
        af1[f][0] = *(const bf16x8*)(aP1 + (f + 4) * 2048 + lrow + ls0); \
        af1[f][1] = *(const bf16x8*)(aP1 + (f + 4) * 2048 + lrow + (ls0 ^ 64)); \
      } \
      if (nl) STG_B(ctn, kn1, 1); \
      PH_PRE(); \
      MFMA_Q(af1, 4, 0); MFMA_Q(af1, 4, 1); \
      PH_POST(); \
      if (nl) { STG_A(kn1, 0); asm volatile("s_waitcnt vmcnt(6)" ::: "memory"); } \
      else    { asm volatile("s_waitcnt vmcnt(0)" ::: "memory"); } \
      PH_PRE(); \
      MFMA_Q(af1, 4, 2); MFMA_Q(af1, 4, 3); \
      PH_POST(); \
    } \
    EPILOG_(s); \
  }

// ---- chained norm-only GEMM: ssbuf[row] = sum over 768 cols of (X@W2^T + b2)^2 ----
__global__ __launch_bounds__(512, 1) void k_gemmnorm(
    const bf16s* __restrict__ Ax, const bf16s* __restrict__ Btw,
    const float* __restrict__ bias, float* __restrict__ ssbuf)
{
  __shared__ __align__(16) char sA[65536];
  __shared__ __align__(16) char sB[65536];
  const int K = H_;
  int bid = blockIdx.x;
  int nid = (bid & 7) * 32 + (bid >> 3);     // 256 blocks = 1 mt each
  long a0 = (long)nid * 256;
  long b0base = 0;
  int tid = threadIdx.x;
  int wid = tid >> 6, l = tid & 63;
  int wr = wid >> 2, wc = wid & 3;
  int srow = tid >> 3;
  int sslot = (tid & 7) ^ (srow & 7);
  const bf16s* gA = Ax + (a0 + srow) * (long)K + sslot * 8;
  const bf16s* gB = Btw + (b0base + srow) * (long)K + sslot * 8;
  float ssp[8] = {0.f, 0.f, 0.f, 0.f, 0.f, 0.f, 0.f, 0.f};

#define EPI_N(s_) do { \
    f32x4 bb[4]; \
    _Pragma("unroll") \
    for (int fc = 0; fc < 4; ++fc) \
      bb[fc] = *(const f32x4*)(bias + (s_) * 256 + wc * 64 + fc * 16 + (l >> 4) * 4); \
    _Pragma("unroll") \
    for (int fr = 0; fr < 8; ++fr) { \
      float p = 0.f; \
      _Pragma("unroll") \
      for (int fc = 0; fc < 4; ++fc) { \
        _Pragma("unroll") \
        for (int r = 0; r < 4; ++r) { \
          float y = acc[fr][fc][r] + bb[fc][r]; \
          p += y * y; \
        } \
        acc[fr][fc] = (f32x4){0.f, 0.f, 0.f, 0.f}; \
      } \
      ssp[fr] += p; \
    } \
  } while (0)

  CHAIN_CORE(EPI_N)
#undef EPI_N

  // cross-wave reduction: 4 wc-waves hold partial column-slice sums per row.
  float* sred = (float*)sA;
#pragma unroll
  for (int fr = 0; fr < 8; ++fr) {
    float p = ssp[fr];
    p += __shfl_xor(p, 16);
    p += __shfl_xor(p, 32);
    if (l < 16) sred[wc * 256 + wr * 128 + fr * 16 + l] = p;
  }
  __syncthreads();
  if (tid < 256) {
    ssbuf[a0 + tid] = sred[tid] + sred[256 + tid] + sred[512 + tid] + sred[768 + tid];
  }
}

#undef CHAIN_CORE
#undef STG_A
#undef STG_B
#undef STG1_A
#undef STG1_B
#undef MFMA_Q
#undef PH_PRE
#undef PH_POST

// ---------------- z1: per (batch, start-pos) group, running-sum mean ----------
// Block = one (b,i) group, 192 threads (3 waves), thread t = h4 slice.
// Reads start slice once, mean rows once (running sum shared across spans),
// end slice per span. Tail blocks zero-fill X rows [N, NPAD).
__global__ __launch_bounds__(192) void k_z1(
    const bf16s* __restrict__ P,
    const float* __restrict__ LT, const float* __restrict__ b1,
    const int* __restrict__ pos, const int* __restrict__ spoff,
    const int* __restrict__ meta, bf16s* __restrict__ X)
{
  int bid = blockIdx.x;
  int t = threadIdx.x;            // 0..191
  int h = t * 4;
  if (bid < BS) {
    int b = bid >> 10, i = bid & (S_ - 1);
    int n = meta[1];
    if (i >= n) return;
    int cnt = min(L_, n - i);
    int sa = pos[i];
    int base = spoff[i];
    const bf16s* Pb = P + (long)b * S_ * N3;
    bf16x4 vs = *(const bf16x4*)(Pb + (long)sa * N3 + h);
    f32x4 bb = *(const f32x4*)(b1 + h);
    float run[4] = {0.f, 0.f, 0.f, 0.f};
    int r = sa;
    for (int k = 0; k < cnt; ++k) {
      int se = pos[i + k];
      for (; r <= se; ++r) {
        bf16x4 vm = *(const bf16x4*)(Pb + (long)r * N3 + 2 * H_ + h);
#pragma unroll
        for (int j = 0; j < 4; j++) run[j] += (float)vm[j];
      }
      bf16x4 ve = *(const bf16x4*)(Pb + (long)se * N3 + H_ + h);
      f32x4 lt = *(const f32x4*)(LT + (long)(k + 1) * H_ + h);
      float il = 1.0f / (float)(k + 1);
      bf16x4 o;
#pragma unroll
      for (int j = 0; j < 4; j++) {
        float x = (float)vs[j] + (float)ve[j] + run[j] * il + lt[j] + bb[j];
        float g = 0.5f * x * (1.0f + erff(x * 0.70710678118654752f));
        o[j] = (__bf16)g;
      }
      *(bf16x4*)(X + ((long)b * NPAD + base + k) * H_ + h) = o;
    }
  } else {
    // zero-fill pad rows [N, NPAD) across all batches (grid-stride)
    int N = meta[0];
    int pad = NPAD - N;
    if (pad <= 0) return;
    long total = (long)B_ * pad * 192;
    for (long idx = (long)(bid - BS) * 192 + t; idx < total; idx += 512L * 192) {
      int h4 = (int)(idx % 192);
      long rrw = idx / 192;
      int pr = (int)(rrw % pad);
      int bb2 = (int)(rrw / pad);
      bf16x4 z; z[0] = z[1] = z[2] = z[3] = (__bf16)0.f;
      *(bf16x4*)(X + ((long)bb2 * NPAD + N + pr) * H_ + h4 * 4) = z;
    }
  }
}

// ------- sim from X: scores[b,n] = max_t (U[t]·X_n + c[t]) * rsqrt(ss[n]) ----
__global__ __launch_bounds__(256) void k_simx(
    const bf16s* __restrict__ X, const bf16s* __restrict__ U,
    const float* __restrict__ cvec, const float* __restrict__ ssbuf,
    const int* __restrict__ tmask, float* __restrict__ scores)
{
  int b = blockIdx.y;
  int wid = threadIdx.x >> 6, l = threadIdx.x & 63;
  int st = blockIdx.x * 4 + wid;
  int span = st * 16 + (l & 15);
  const bf16s* xrow = X + (long)(b * NPAD + span) * H_ + (l >> 4) * 8;
  const bf16s* ubase = U + (long)b * T_ * H_ + (l >> 4) * 8;
  f32x4 acc[4];
#pragma unroll
  for (int tt = 0; tt < 4; tt++) acc[tt] = (f32x4){0.f, 0.f, 0.f, 0.f};
  for (int kk = 0; kk < H_ / 32; kk++) {
    bf16x8 av = *(const bf16x8*)(xrow + kk * 32);
#pragma unroll
    for (int tt = 0; tt < 4; tt++) {
      bf16x8 bv = *(const bf16x8*)(ubase + (long)(tt * 16 + (l & 15)) * H_ + kk * 32);
      acc[tt] = __builtin_amdgcn_mfma_f32_16x16x32_bf16(av, bv, acc[tt], 0, 0, 0);
    }
  }
  const int* tm = tmask + b * T_;
  bool msk[4];
  float cv[4];
#pragma unroll
  for (int tt = 0; tt < 4; tt++) {
    int tcol = tt * 16 + (l & 15);
    msk[tt] = tm[tcol] != 0;
    cv[tt] = cvec[b * T_ + tcol];
  }
  float best[4];
#pragma unroll
  for (int r = 0; r < 4; r++) {
    float v = -INFINITY;
#pragma unroll
    for (int tt = 0; tt < 4; tt++) if (msk[tt]) v = fmaxf(v, acc[tt][r] + cv[tt]);
    best[r] = v;
  }
#pragma unroll
  for (int off = 8; off; off >>= 1)
#pragma unroll
    for (int r = 0; r < 4; r++) best[r] = fmaxf(best[r], __shfl_xor(best[r], off));
  if ((l & 15) == 0) {
    int srow = st * 16 + (l >> 4) * 4;
#pragma unroll
    for (int r = 0; r < 4; r++) {
      float ss = ssbuf[b * NPAD + srow + r];
      scores[b * NPAD + srow + r] = best[r] / fmaxf(sqrtf(ss), 1e-12f);
    }
  }
}

// ---------------- token max ----------------
__global__ __launch_bounds__(256) void k_token(
    const int* __restrict__ text_mask,
    const int* __restrict__ R, const int* __restrict__ spoff,
    const int* __restrict__ meta, const float* __restrict__ scores,
    float* __restrict__ out)
{
  int idx = blockIdx.x * 256 + threadIdx.x;  // B*S
  int s = idx % S_, b = idx / S_;
  if (!text_mask[b * S_ + s]) { out[idx] = -INFINITY; return; }
  int n = meta[1];
  int r1 = R[s];
  int le = r1 - 1;                         // largest i with pos[i] <= s
  int ge = text_mask[s] ? (r1 - 1) : r1;   // smallest j with pos[j] >= s (row 0)
  float best = -INFINITY;
  if (le >= 0 && ge < n) {
    int i0 = max(0, ge - (L_ - 1));
    for (int i = i0; i <= le; i++) {
      int jmax = min(i + L_ - 1, n - 1);
      int off = spoff[i];
      for (int j = max(i, ge); j <= jmax; j++)
        best = fmaxf(best, scores[b * NPAD + off + (j - i)]);
    }
  }
  out[idx] = best;
}

// ---------------- ws-too-small sentinel ----------------
__global__ __launch_bounds__(256) void k_sentinel(float* __restrict__ out) {
  int i = blockIdx.x * 256 + threadIdx.x;
  if (i < BS) out[i] = 12345.0f;
}

// ---------------- launch ----------------
extern "C" void kernel_launch(void* const* d_in, const int* in_sizes, int n_in,
                              void* d_out, int out_size, void* d_ws, size_t ws_size,
                              hipStream_t stream) {
  const float* hid = (const float*)d_in[0];
  const float* th  = (const float*)d_in[1];
  const int* tmask = (const int*)d_in[2];
  const int* xmask = (const int*)d_in[3];
  const float* lemb = (const float*)d_in[4];
  const float* W1   = (const float*)d_in[5];
  const float* b1   = (const float*)d_in[6];
  const float* W2   = (const float*)d_in[7];
  const float* b2   = (const float*)d_in[8];
  float* out = (float*)d_out;

  char* w = (char*)d_ws;
  auto alloc = [&](size_t bytes) {
    char* p = w; w += (bytes + 255) & ~(size_t)255; return p;
  };
  // small buffers (~10 MB)
  bf16s* wbt   = (bf16s*)alloc((size_t)N3 * H_ * 2);
  bf16s* w2t   = (bf16s*)alloc((size_t)H_ * H_ * 2);
  bf16s* w2c   = (bf16s*)alloc((size_t)H_ * H_ * 2);
  float* LT    = (float*)alloc((size_t)(L_ + 1) * H_ * 4);
  bf16s* topn  = (bf16s*)alloc((size_t)B_ * T_ * H_ * 2);
  bf16s* U     = (bf16s*)alloc((size_t)B_ * T_ * H_ * 2);
  float* cvec  = (float*)alloc((size_t)B_ * T_ * 4);
  float* ssbuf = (float*)alloc((size_t)BNR * 4);
  float* scores= (float*)alloc((size_t)B_ * NPAD * 4);
  int* R       = (int*)alloc(S_ * 4);
  int* pos     = (int*)alloc(S_ * 4);
  int* spoff   = (int*)alloc(S_ * 4);
  int* starts  = (int*)alloc(NPAD * 4);
  int* ends    = (int*)alloc(NPAD * 4);
  int* lens    = (int*)alloc(NPAD * 4);
  int* meta    = (int*)alloc(2 * 4);
  // region A: [hidb | P] (100.66 MB)
  char* regionA = alloc((size_t)BS * H_ * 2 + (size_t)BS * N3 * 2);
  bf16s* hidb  = (bf16s*)regionA;
  bf16s* P     = (bf16s*)(regionA + (size_t)BS * H_ * 2);
  // region B: X (100.66 MB)
  bf16s* X     = (bf16s*)alloc((size_t)BNR * H_ * 2);

  size_t required = (size_t)(w - (char*)d_ws);
  if (required > ws_size) {
    k_sentinel<<<(BS + 255) / 256, 256, 0, stream>>>(out);
    return;
  }

  k_build_spans<<<1, 1024, 0, stream>>>(xmask, R, pos, spoff, starts, ends, lens, meta);
  k_prep<<<14479, 256, 0, stream>>>(hid, hidb, W1, wbt, W2, w2t, w2c,
                                    lemb, LT, th, b2, topn, cvec);

  // GEMM1 (P = hidb @ wbt^T, 576 tiles) + U-GEMM (U = topn @ w2c^T, 12 tiles)
  k_gemm8p<<<588, 512, 0, stream>>>(hidb, wbt, P, topn, w2c, U);

  k_z1<<<BS + 512, 192, 0, stream>>>(P, LT, b1, pos, spoff, meta, X);

  // norm-only GEMM2 chained over all 768 cols: ssbuf = rowwise ||X@W2^T + b2||^2
  k_gemmnorm<<<256, 512, 0, stream>>>(X, w2t, b2, ssbuf);

  k_simx<<<dim3(NPAD / 64, B_), 256, 0, stream>>>(X, U, cvec, ssbuf, tmask, scores);
  k_token<<<(B_ * S_) / 256, 256, 0, stream>>>(xmask, R, spoff, meta, scores, out);
  (void)in_sizes; (void)n_in; (void)out_size;
}

// Round 9
// 302.354 us; speedup vs baseline: 1.2893x; 1.0005x over previous
//
#include <hip/hip_runtime.h>
#include <hip/hip_bf16.h>
#include <math.h>

typedef __bf16 bf16s;
typedef __attribute__((ext_vector_type(8))) __bf16 bf16x8;
typedef __attribute__((ext_vector_type(4))) __bf16 bf16x4;
typedef __attribute__((ext_vector_type(4))) float f32x4;

#define B_   16
#define S_   1024
#define H_   768
#define T_   64
#define L_   4
#define LE_  32
#define NPAD 4096
#define BS   (B_*S_)    // 16384
#define BNR  (B_*NPAD)  // 65536 rows of X
#define N3   (3*H_)     // 2304

static __device__ __forceinline__ void gload_lds16(const void* g, void* l) {
  __builtin_amdgcn_global_load_lds(
      (const __attribute__((address_space(1))) void*)g,
      (__attribute__((address_space(3))) void*)l, 16, 0, 0);
}

// ---------------- span construction (1 block) ----------------
__global__ __launch_bounds__(1024) void k_build_spans(
    const int* __restrict__ text_mask,   // row 0 used
    int* __restrict__ R, int* __restrict__ pos, int* __restrict__ spoff,
    int* __restrict__ starts, int* __restrict__ ends, int* __restrict__ lens,
    int* __restrict__ meta)
{
  __shared__ int buf[S_];
  int t = threadIdx.x;
  int m = text_mask[t] ? 1 : 0;
  buf[t] = m;
  __syncthreads();
  for (int off = 1; off < S_; off <<= 1) {
    int v = buf[t];
    if (t >= off) v += buf[t - off];
    __syncthreads();
    buf[t] = v;
    __syncthreads();
  }
  int incl = buf[t];
  R[t] = incl;
  if (m) pos[incl - 1] = t;
  int n = buf[S_ - 1];
  __syncthreads();
  int cnt = (t < n) ? min(L_, n - t) : 0;
  buf[t] = cnt;
  __syncthreads();
  for (int off = 1; off < S_; off <<= 1) {
    int v = buf[t];
    if (t >= off) v += buf[t - off];
    __syncthreads();
    buf[t] = v;
    __syncthreads();
  }
  int inc2 = buf[t];
  int base = inc2 - cnt;
  spoff[t] = base;
  if (t == 0) { meta[0] = buf[S_ - 1]; meta[1] = n; }
  __syncthreads();
  if (t < n) {
    int p0 = pos[t];
    for (int k = 0; k < cnt; k++) {
      starts[base + k] = p0;
      ends[base + k]   = pos[t + k];
      lens[base + k]   = k + 1;
    }
  }
}

// ---------------- fused prep: casts + transposes + LT + topicn ----------------
__global__ __launch_bounds__(256) void k_prep(
    const float* __restrict__ hid, bf16s* __restrict__ hidb,
    const float* __restrict__ W1, bf16s* __restrict__ wbt,
    const float* __restrict__ W2, bf16s* __restrict__ w2t, bf16s* __restrict__ w2c,
    const float* __restrict__ lemb, float* __restrict__ LT,
    const float* __restrict__ TH, const float* __restrict__ b2,
    bf16s* __restrict__ TN, float* __restrict__ cvec)
{
  __shared__ float tile[64][65];
  __shared__ float red[256];
  int bid = blockIdx.x;
  int t = threadIdx.x;
  if (bid < 12288) {
    int i = bid * 256 + t;           // BS*H/4 groups
    f32x4 v = ((const f32x4*)hid)[i];
    bf16x4 o;
    o[0] = (__bf16)v[0]; o[1] = (__bf16)v[1]; o[2] = (__bf16)v[2]; o[3] = (__bf16)v[3];
    ((bf16x4*)hidb)[i] = o;
  } else if (bid < 12864) {
    int local = bid - 12288;
    int c = local / 144, rem = local % 144;
    const float* in = (c < 3) ? (W1 + (size_t)c * H_ * H_) : W2;
    bf16s* out = (c < 3) ? (wbt + (size_t)c * H_ * H_) : w2t;
    int r0 = (rem / 12) * 64, c0 = (rem % 12) * 64;
    int tr = t >> 4, tc = (t & 15) * 4;
#pragma unroll
    for (int i = 0; i < 4; i++) {
      int row = tr + i * 16;
      f32x4 v = *(const f32x4*)(in + (long)(r0 + row) * H_ + c0 + tc);
      tile[row][tc+0] = v[0]; tile[row][tc+1] = v[1];
      tile[row][tc+2] = v[2]; tile[row][tc+3] = v[3];
    }
    __syncthreads();
#pragma unroll
    for (int i = 0; i < 4; i++) {
      int cc = tr + i * 16;
      bf16x4 o;
      o[0] = (__bf16)tile[tc+0][cc]; o[1] = (__bf16)tile[tc+1][cc];
      o[2] = (__bf16)tile[tc+2][cc]; o[3] = (__bf16)tile[tc+3][cc];
      *(bf16x4*)(out + (long)(c0 + cc) * H_ + r0 + tc) = o;
    }
  } else if (bid < 13440) {
    int i = (bid - 12864) * 256 + t;   // H*H/4 groups
    f32x4 v = ((const f32x4*)W2)[i];
    bf16x4 o;
    o[0] = (__bf16)v[0]; o[1] = (__bf16)v[1]; o[2] = (__bf16)v[2]; o[3] = (__bf16)v[3];
    ((bf16x4*)w2c)[i] = o;
  } else if (bid < 13455) {
    int idx = (bid - 13440) * 256 + t;
    if (idx < (L_ + 1) * H_) {
      int l = idx / H_, h = idx % H_;
      float acc = 0.f;
#pragma unroll
      for (int e = 0; e < LE_; e++) acc += lemb[l * LE_ + e] * W1[(long)(N3 + e) * H_ + h];
      LT[idx] = acc;
    }
  } else {
    int r = bid - 13455;               // topic row 0..1023
    const float* row = TH + (long)r * H_;
    float v0 = row[t], v1 = row[t + 256], v2 = row[t + 512];
    red[t] = v0 * v0 + v1 * v1 + v2 * v2;
    __syncthreads();
    for (int off = 128; off; off >>= 1) {
      if (t < off) red[t] += red[t + off];
      __syncthreads();
    }
    float rn = 1.0f / fmaxf(sqrtf(red[0]), 1e-12f);
    bf16s* o = TN + (long)r * H_;
    o[t] = (__bf16)(v0 * rn); o[t + 256] = (__bf16)(v1 * rn); o[t + 512] = (__bf16)(v2 * rn);
    __syncthreads();
    red[t] = v0 * b2[t] + v1 * b2[t + 256] + v2 * b2[t + 512];
    __syncthreads();
    for (int off = 128; off; off >>= 1) {
      if (t < off) red[t] += red[t + off];
      __syncthreads();
    }
    if (t == 0) cvec[r] = red[0] * rn;
  }
}

// ====== single-tile 8-phase GEMM core macros ======
#define BKT 64
#define STG1_A(kt_, h_) do { \
    const bf16s* s_ = gA + (long)(h_) * 128 * K + (long)(kt_) * BKT; \
    char* d_ = sA + ((kt_) & 1) * 32768 + (h_) * 16384 + wid * 1024; \
    gload_lds16(s_, d_); \
    gload_lds16(s_ + 64L * K, d_ + 8192); \
  } while (0)
#define STG1_B(kt_, h_) do { \
    const bf16s* s_ = gB + (long)(h_) * 128 * K + (long)(kt_) * BKT; \
    char* d_ = sB + ((kt_) & 1) * 32768 + (h_) * 16384 + wid * 1024; \
    gload_lds16(s_, d_); \
    gload_lds16(s_ + 64L * K, d_ + 8192); \
  } while (0)
#define MFMA_Q(AF_, FR0_, FC_) do { \
    _Pragma("unroll") \
    for (int f_ = 0; f_ < 4; ++f_) { \
      acc[FR0_+f_][FC_] = __builtin_amdgcn_mfma_f32_16x16x32_bf16(bfv[FC_][0], AF_[f_][0], acc[FR0_+f_][FC_], 0, 0, 0); \
      acc[FR0_+f_][FC_] = __builtin_amdgcn_mfma_f32_16x16x32_bf16(bfv[FC_][1], AF_[f_][1], acc[FR0_+f_][FC_], 0, 0, 0); \
    } } while (0)
#define PH_PRE()  __builtin_amdgcn_s_barrier(); \
                  asm volatile("s_waitcnt lgkmcnt(0)" ::: "memory"); \
                  __builtin_amdgcn_s_setprio(1)
#define PH_POST() __builtin_amdgcn_s_setprio(0); \
                  __builtin_amdgcn_s_barrier()

// ---- GEMM1 + U-GEMM: 512 blocks; blocks 0..75 run 2 work items (makespan fix:
// 588 items at 1 block/CU would take 3 rounds; 512 blocks x <=2 items take 2).
__global__ __launch_bounds__(512, 2) void k_gemm8p(
    const bf16s* __restrict__ Ah, const bf16s* __restrict__ Bth, bf16s* __restrict__ Ch,
    const bf16s* __restrict__ Au, const bf16s* __restrict__ Btu, bf16s* __restrict__ Cu)
{
  __shared__ __align__(16) char sA[65536];
  __shared__ __align__(16) char sB[65536];
  const int K = H_;

  int tid = threadIdx.x;
  int wid = tid >> 6, l = tid & 63;
  int wr = wid >> 2, wc = wid & 3;          // 2x4 waves; wave tile 128x64
  int srow = tid >> 3;
  int sslot = (tid & 7) ^ (srow & 7);

  const char* aP0 = sA + wr * 16384;
  const char* aP1 = aP0 + 32768;
  const char* bP0 = sB + (wc >> 1) * 16384 + (wc & 1) * 8192;
  const char* bP1 = bP0 + 32768;
  int lrow = (l & 15) * 128;
  int ls0 = (((l >> 4) ^ (l & 7)) * 16);

  int nseg = (blockIdx.x < 76) ? 2 : 1;
#pragma unroll 1
  for (int seg = 0; seg < nseg; ++seg) {
    int raw = (seg == 0) ? blockIdx.x : 512 + blockIdx.x;
    // bijective XCD-chunked swizzle over 588 work items
    const int nwg = 588;
    int q = nwg >> 3, rr = nwg & 7;
    int xcd = raw & 7, ix = raw >> 3;
    int nid = (xcd < rr ? xcd * (q + 1) : rr * (q + 1) + (xcd - rr) * q) + ix;

    const bf16s *A, *Bt;
    bf16s* C;
    long a0, b0;
    int NN;
    if (nid < 576) {
      A = Ah; Bt = Bth; C = Ch; NN = N3;
      a0 = (long)(nid / 9) * 256;
      b0 = (long)(nid % 9) * 256;
    } else {
      int u = nid - 576;
      A = Au; Bt = Btu; C = Cu; NN = H_;
      a0 = (long)(u / 3) * 256;
      b0 = (long)(u % 3) * 256;
    }
    const bf16s* gA = A + (a0 + srow) * (long)K + sslot * 8;
    const bf16s* gB = Bt + (b0 + srow) * (long)K + sslot * 8;

    f32x4 acc[8][4];
#pragma unroll
    for (int i = 0; i < 8; i++)
#pragma unroll
      for (int j = 0; j < 4; j++) acc[i][j] = (f32x4){0.f, 0.f, 0.f, 0.f};

    // prologue: tile0 {B0,B1,A0,A1}, tile1 {B0,B1,A0}; wait tile0
    STG1_B(0, 0); STG1_B(0, 1); STG1_A(0, 0); STG1_A(0, 1);
    STG1_B(1, 0); STG1_B(1, 1); STG1_A(1, 0);
    asm volatile("s_waitcnt vmcnt(6)" ::: "memory");
    __builtin_amdgcn_s_barrier();

    for (int it = 0; it < 6; ++it) {
      int t0 = 2 * it, t1 = t0 + 1;
      bool nl = (it != 5);
      bf16x8 af0[4][2], af1[4][2], bfv[4][2];

      // phase 1: read af0 + bfv from buf0; stage t1.A1
#pragma unroll
      for (int f = 0; f < 4; ++f) {
        af0[f][0] = *(const bf16x8*)(aP0 + f * 2048 + lrow + ls0);
        af0[f][1] = *(const bf16x8*)(aP0 + f * 2048 + lrow + (ls0 ^ 64));
      }
#pragma unroll
      for (int c = 0; c < 4; ++c) {
        bfv[c][0] = *(const bf16x8*)(bP0 + c * 2048 + lrow + ls0);
        bfv[c][1] = *(const bf16x8*)(bP0 + c * 2048 + lrow + (ls0 ^ 64));
      }
      STG1_A(t1, 1);
      PH_PRE();
      MFMA_Q(af0, 0, 0); MFMA_Q(af0, 0, 1);
      PH_POST();

      // phase 2: stage (t0+2).B0
      if (nl) STG1_B(t0 + 2, 0);
      PH_PRE();
      MFMA_Q(af0, 0, 2); MFMA_Q(af0, 0, 3);
      PH_POST();

      // phase 3: read af1 from buf0; stage (t0+2).B1
#pragma unroll
      for (int f = 0; f < 4; ++f) {
        af1[f][0] = *(const bf16x8*)(aP0 + (f + 4) * 2048 + lrow + ls0);
        af1[f][1] = *(const bf16x8*)(aP0 + (f + 4) * 2048 + lrow + (ls0 ^ 64));
      }
      if (nl) STG1_B(t0 + 2, 1);
      PH_PRE();
      MFMA_Q(af1, 4, 0); MFMA_Q(af1, 4, 1);
      PH_POST();

      // phase 4: stage (t0+2).A0; counted vmcnt (t1 fully landed)
      if (nl) { STG1_A(t0 + 2, 0); asm volatile("s_waitcnt vmcnt(6)" ::: "memory"); }
      else    { asm volatile("s_waitcnt vmcnt(0)" ::: "memory"); }
      PH_PRE();
      MFMA_Q(af1, 4, 2); MFMA_Q(af1, 4, 3);
      PH_POST();

      // phase 5: read af0 + bfv from buf1 (tile t1); stage (t0+2).A1
#pragma unroll
      for (int f = 0; f < 4; ++f) {
        af0[f][0] = *(const bf16x8*)(aP1 + f * 2048 + lrow + ls0);
        af0[f][1] = *(const bf16x8*)(aP1 + f * 2048 + lrow + (ls0 ^ 64));
      }
#pragma unroll
      for (int c = 0; c < 4; ++c) {
        bfv[c][0] = *(const bf16x8*)(bP1 + c * 2048 + lrow + ls0);
        bfv[c][1] = *(const bf16x8*)(bP1 + c * 2048 + lrow + (ls0 ^ 64));
      }
      if (nl) STG1_A(t0 + 2, 1);
      PH_PRE();
      MFMA_Q(af0, 0, 0); MFMA_Q(af0, 0, 1);
      PH_POST();

      // phase 6: stage (t1+2).B0
      if (nl) STG1_B(t1 + 2, 0);
      PH_PRE();
      MFMA_Q(af0, 0, 2); MFMA_Q(af0, 0, 3);
      PH_POST();

      // phase 7: read af1 from buf1; stage (t1+2).B1
#pragma unroll
      for (int f = 0; f < 4; ++f) {
        af1[f][0] = *(const bf16x8*)(aP1 + (f + 4) * 2048 + lrow + ls0);
        af1[f][1] = *(const bf16x8*)(aP1 + (f + 4) * 2048 + lrow + (ls0 ^ 64));
      }
      if (nl) STG1_B(t1 + 2, 1);
      PH_PRE();
      MFMA_Q(af1, 4, 0); MFMA_Q(af1, 4, 1);
      PH_POST();

      // phase 8: stage (t1+2).A0; counted vmcnt
      if (nl) { STG1_A(t1 + 2, 0); asm volatile("s_waitcnt vmcnt(6)" ::: "memory"); }
      else    { asm volatile("s_waitcnt vmcnt(0)" ::: "memory"); }
      PH_PRE();
      MFMA_Q(af1, 4, 2); MFMA_Q(af1, 4, 3);
      PH_POST();
    }

    // epilogue (direct stores, no LDS): lane l holds
    // C[a0+wr*128+fr*16+(l&15)][b0+wc*64+fc*16+(l>>4)*4 + r]
#pragma unroll
    for (int fc = 0; fc < 4; fc++) {
      long n0 = b0 + wc * 64 + fc * 16 + (l >> 4) * 4;
#pragma unroll
      for (int fr = 0; fr < 8; fr++) {
        long mrow = a0 + wr * 128 + fr * 16 + (l & 15);
        bf16x4 o;
#pragma unroll
        for (int r = 0; r < 4; r++) o[r] = (__bf16)acc[fr][fc][r];
        *(bf16x4*)(C + mrow * (long)NN + n0) = o;
      }
    }
  }
}

// ====== chained 3-segment core for gemmnorm (r7-proven) ======
#define STG_A(kt_, h_) do { \
    const bf16s* s_ = gA + (long)(h_) * 128 * K + (long)(kt_) * BKT; \
    char* d_ = sA + ((kt_) & 1) * 32768 + (h_) * 16384 + wid * 1024; \
    gload_lds16(s_, d_); \
    gload_lds16(s_ + 64L * K, d_ + 8192); \
  } while (0)
#define STG_B(ct_, kt_, h_) do { \
    const bf16s* s_ = gB + (long)(ct_) * 256 * K + (long)(h_) * 128 * K + (long)(kt_) * BKT; \
    char* d_ = sB + ((kt_) & 1) * 32768 + (h_) * 16384 + wid * 1024; \
    gload_lds16(s_, d_); \
    gload_lds16(s_ + 64L * K, d_ + 8192); \
  } while (0)

#define CHAIN_CORE(EPILOG_) \
  const char* aP0 = sA + wr * 16384; \
  const char* aP1 = aP0 + 32768; \
  const char* bP0 = sB + (wc >> 1) * 16384 + (wc & 1) * 8192; \
  const char* bP1 = bP0 + 32768; \
  int lrow = (l & 15) * 128; \
  int ls0 = (((l >> 4) ^ (l & 7)) * 16); \
  f32x4 acc[8][4]; \
  _Pragma("unroll") \
  for (int i_ = 0; i_ < 8; i_++) \
    _Pragma("unroll") \
    for (int j_ = 0; j_ < 4; j_++) acc[i_][j_] = (f32x4){0.f, 0.f, 0.f, 0.f}; \
  STG_B(0, 0, 0); STG_B(0, 0, 1); STG_A(0, 0); STG_A(0, 1); \
  STG_B(0, 1, 0); STG_B(0, 1, 1); STG_A(1, 0); \
  asm volatile("s_waitcnt vmcnt(6)" ::: "memory"); \
  __builtin_amdgcn_s_barrier(); \
  for (int s = 0; s < 3; ++s) { \
    for (int it = 0; it < 6; ++it) { \
      int kt0 = 2 * it; \
      bool nl = !(s == 2 && it == 5); \
      int ctn = (it == 5) ? s + 1 : s; \
      int kn0 = (it == 5) ? 0 : kt0 + 2; \
      int kn1 = (it == 5) ? 1 : kt0 + 3; \
      bf16x8 af0[4][2], af1[4][2], bfv[4][2]; \
      _Pragma("unroll") \
      for (int f = 0; f < 4; ++f) { \
        af0[f][0] = *(const bf16x8*)(aP0 + f * 2048 + lrow + ls0); \
        af0[f][1] = *(const bf16x8*)(aP0 + f * 2048 + lrow + (ls0 ^ 64)); \
      } \
      _Pragma("unroll") \
      for (int c = 0; c < 4; ++c) { \
        bfv[c][0] = *(const bf16x8*)(bP0 + c * 2048 + lrow + ls0); \
        bfv[c][1] = *(const bf16x8*)(bP0 + c * 2048 + lrow + (ls0 ^ 64)); \
      } \
      STG_A(kt0 + 1, 1); \
      PH_PRE(); \
      MFMA_Q(af0, 0, 0); MFMA_Q(af0, 0, 1); \
      PH_POST(); \
      if (nl) STG_B(ctn, kn0, 0); \
      PH_PRE(); \
      MFMA_Q(af0, 0, 2); MFMA_Q(af0, 0, 3); \
      PH_POST(); \
      _Pragma("unroll") \
      for (int f = 0; f < 4; ++f) { \
        af1[f][0] = *(const bf16x8*)(aP0 + (f + 4) * 2048 + lrow + ls0); \
        af1[f][1] = *(const bf16x8*)(aP0 + (f + 4) * 2048 + lrow + (ls0 ^ 64)); \
      } \
      if (nl) STG_B(ctn, kn0, 1); \
      PH_PRE(); \
      MFMA_Q(af1, 4, 0); MFMA_Q(af1, 4, 1); \
      PH_POST(); \
      if (nl) { STG_A(kn0, 0); asm volatile("s_waitcnt vmcnt(6)" ::: "memory"); } \
      else    { asm volatile("s_waitcnt vmcnt(0)" ::: "memory"); } \
      PH_PRE(); \
      MFMA_Q(af1, 4, 2); MFMA_Q(af1, 4, 3); \
      PH_POST(); \
      _Pragma("unroll") \
      for (int f = 0; f < 4; ++f) { \
        af0[f][0] = *(const bf16x8*)(aP1 + f * 2048 + lrow + ls0); \
        af0[f][1] = *(const bf16x8*)(aP1 + f * 2048 + lrow + (ls0 ^ 64)); \
      } \
      _Pragma("unroll") \
      for (int c = 0; c < 4; ++c) { \
        bfv[c][0] = *(const bf16x8*)(bP1 + c * 2048 + lrow + ls0); \
        bfv[c][1] = *(const bf16x8*)(bP1 + c * 2048 + lrow + (ls0 ^ 64)); \
      } \
      if (nl) STG_A(kn0, 1); \
      PH_PRE(); \
      MFMA_Q(af0, 0, 0); MFMA_Q(af0, 0, 1); \
      PH_POST(); \
      if (nl) STG_B(ctn, kn1, 0); \
      PH_PRE(); \
      MFMA_Q(af0, 0, 2); MFMA_Q(af0, 0, 3); \
      PH_POST(); \
      _Pragma("unroll") \
      for (int f = 0; f < 4; ++f) { \
        af1[f][0] = *(const bf16x8*)(aP1 + (f + 4) * 2048 + lrow + ls0); \
        af1[f][1] = *(const bf16x8*)(aP1 + (f + 4) * 2048 + lrow + (ls0 ^ 64)); \
      } \
      if (nl) STG_B(ctn, kn1, 1); \
      PH_PRE(); \
      MFMA_Q(af1, 4, 0); MFMA_Q(af1, 4, 1); \
      PH_POST(); \
      if (nl) { STG_A(kn1, 0); asm volatile("s_waitcnt vmcnt(6)" ::: "memory"); } \
      else    { asm volatile("s_waitcnt vmcnt(0)" ::: "memory"); } \
      PH_PRE(); \
      MFMA_Q(af1, 4, 2); MFMA_Q(af1, 4, 3); \
      PH_POST(); \
    } \
    EPILOG_(s); \
  }

// ---- chained norm-only GEMM: ssbuf[row] = sum over 768 cols of (X@W2^T + b2)^2 ----
__global__ __launch_bounds__(512, 1) void k_gemmnorm(
    const bf16s* __restrict__ Ax, const bf16s* __restrict__ Btw,
    const float* __restrict__ bias, float* __restrict__ ssbuf)
{
  __shared__ __align__(16) char sA[65536];
  __shared__ __align__(16) char sB[65536];
  const int K = H_;
  int bid = blockIdx.x;
  int nid = (bid & 7) * 32 + (bid >> 3);     // 256 blocks = 1 mt each
  long a0 = (long)nid * 256;
  long b0base = 0;
  int tid = threadIdx.x;
  int wid = tid >> 6, l = tid & 63;
  int wr = wid >> 2, wc = wid & 3;
  int srow = tid >> 3;
  int sslot = (tid & 7) ^ (srow & 7);
  const bf16s* gA = Ax + (a0 + srow) * (long)K + sslot * 8;
  const bf16s* gB = Btw + (b0base + srow) * (long)K + sslot * 8;
  float ssp[8] = {0.f, 0.f, 0.f, 0.f, 0.f, 0.f, 0.f, 0.f};

#define EPI_N(s_) do { \
    f32x4 bb[4]; \
    _Pragma("unroll") \
    for (int fc = 0; fc < 4; ++fc) \
      bb[fc] = *(const f32x4*)(bias + (s_) * 256 + wc * 64 + fc * 16 + (l >> 4) * 4); \
    _Pragma("unroll") \
    for (int fr = 0; fr < 8; ++fr) { \
      float p = 0.f; \
      _Pragma("unroll") \
      for (int fc = 0; fc < 4; ++fc) { \
        _Pragma("unroll") \
        for (int r = 0; r < 4; ++r) { \
          float y = acc[fr][fc][r] + bb[fc][r]; \
          p += y * y; \
        } \
        acc[fr][fc] = (f32x4){0.f, 0.f, 0.f, 0.f}; \
      } \
      ssp[fr] += p; \
    } \
  } while (0)

  CHAIN_CORE(EPI_N)
#undef EPI_N

  // cross-wave reduction: 4 wc-waves hold partial column-slice sums per row.
  float* sred = (float*)sA;
#pragma unroll
  for (int fr = 0; fr < 8; ++fr) {
    float p = ssp[fr];
    p += __shfl_xor(p, 16);
    p += __shfl_xor(p, 32);
    if (l < 16) sred[wc * 256 + wr * 128 + fr * 16 + l] = p;
  }
  __syncthreads();
  if (tid < 256) {
    ssbuf[a0 + tid] = sred[tid] + sred[256 + tid] + sred[512 + tid] + sred[768 + tid];
  }
}

#undef CHAIN_CORE
#undef STG_A
#undef STG_B
#undef STG1_A
#undef STG1_B
#undef MFMA_Q
#undef PH_PRE
#undef PH_POST

// ---------------- z1: per (batch, start-pos) group, running-sum mean ----------
__global__ __launch_bounds__(192) void k_z1(
    const bf16s* __restrict__ P,
    const float* __restrict__ LT, const float* __restrict__ b1,
    const int* __restrict__ pos, const int* __restrict__ spoff,
    const int* __restrict__ meta, bf16s* __restrict__ X)
{
  int bid = blockIdx.x;
  int t = threadIdx.x;            // 0..191
  int h = t * 4;
  if (bid < BS) {
    int b = bid >> 10, i = bid & (S_ - 1);
    int n = meta[1];
    if (i >= n) return;
    int cnt = min(L_, n - i);
    int sa = pos[i];
    int base = spoff[i];
    const bf16s* Pb = P + (long)b * S_ * N3;
    bf16x4 vs = *(const bf16x4*)(Pb + (long)sa * N3 + h);
    f32x4 bb = *(const f32x4*)(b1 + h);
    float run[4] = {0.f, 0.f, 0.f, 0.f};
    int r = sa;
    for (int k = 0; k < cnt; ++k) {
      int se = pos[i + k];
      for (; r <= se; ++r) {
        bf16x4 vm = *(const bf16x4*)(Pb + (long)r * N3 + 2 * H_ + h);
#pragma unroll
        for (int j = 0; j < 4; j++) run[j] += (float)vm[j];
      }
      bf16x4 ve = *(const bf16x4*)(Pb + (long)se * N3 + H_ + h);
      f32x4 lt = *(const f32x4*)(LT + (long)(k + 1) * H_ + h);
      float il = 1.0f / (float)(k + 1);
      bf16x4 o;
#pragma unroll
      for (int j = 0; j < 4; j++) {
        float x = (float)vs[j] + (float)ve[j] + run[j] * il + lt[j] + bb[j];
        float g = 0.5f * x * (1.0f + erff(x * 0.70710678118654752f));
        o[j] = (__bf16)g;
      }
      *(bf16x4*)(X + ((long)b * NPAD + base + k) * H_ + h) = o;
    }
  } else {
    // zero-fill pad rows [N, NPAD) across all batches (grid-stride)
    int N = meta[0];
    int pad = NPAD - N;
    if (pad <= 0) return;
    long total = (long)B_ * pad * 192;
    for (long idx = (long)(bid - BS) * 192 + t; idx < total; idx += 512L * 192) {
      int h4 = (int)(idx % 192);
      long rrw = idx / 192;
      int pr = (int)(rrw % pad);
      int bb2 = (int)(rrw / pad);
      bf16x4 z; z[0] = z[1] = z[2] = z[3] = (__bf16)0.f;
      *(bf16x4*)(X + ((long)bb2 * NPAD + N + pr) * H_ + h4 * 4) = z;
    }
  }
}

// ------- sim from X: scores[b,n] = max_t (U[t]·X_n + c[t]) * rsqrt(ss[n]) ----
__global__ __launch_bounds__(256) void k_simx(
    const bf16s* __restrict__ X, const bf16s* __restrict__ U,
    const float* __restrict__ cvec, const float* __restrict__ ssbuf,
    const int* __restrict__ tmask, float* __restrict__ scores)
{
  int b = blockIdx.y;
  int wid = threadIdx.x >> 6, l = threadIdx.x & 63;
  int st = blockIdx.x * 4 + wid;
  int span = st * 16 + (l & 15);
  const bf16s* xrow = X + (long)(b * NPAD + span) * H_ + (l >> 4) * 8;
  const bf16s* ubase = U + (long)b * T_ * H_ + (l >> 4) * 8;
  f32x4 acc[4];
#pragma unroll
  for (int tt = 0; tt < 4; tt++) acc[tt] = (f32x4){0.f, 0.f, 0.f, 0.f};
  for (int kk = 0; kk < H_ / 32; kk++) {
    bf16x8 av = *(const bf16x8*)(xrow + kk * 32);
#pragma unroll
    for (int tt = 0; tt < 4; tt++) {
      bf16x8 bv = *(const bf16x8*)(ubase + (long)(tt * 16 + (l & 15)) * H_ + kk * 32);
      acc[tt] = __builtin_amdgcn_mfma_f32_16x16x32_bf16(av, bv, acc[tt], 0, 0, 0);
    }
  }
  const int* tm = tmask + b * T_;
  bool msk[4];
  float cv[4];
#pragma unroll
  for (int tt = 0; tt < 4; tt++) {
    int tcol = tt * 16 + (l & 15);
    msk[tt] = tm[tcol] != 0;
    cv[tt] = cvec[b * T_ + tcol];
  }
  float best[4];
#pragma unroll
  for (int r = 0; r < 4; r++) {
    float v = -INFINITY;
#pragma unroll
    for (int tt = 0; tt < 4; tt++) if (msk[tt]) v = fmaxf(v, acc[tt][r] + cv[tt]);
    best[r] = v;
  }
#pragma unroll
  for (int off = 8; off; off >>= 1)
#pragma unroll
    for (int r = 0; r < 4; r++) best[r] = fmaxf(best[r], __shfl_xor(best[r], off));
  if ((l & 15) == 0) {
    int srow = st * 16 + (l >> 4) * 4;
#pragma unroll
    for (int r = 0; r < 4; r++) {
      float ss = ssbuf[b * NPAD + srow + r];
      scores[b * NPAD + srow + r] = best[r] / fmaxf(sqrtf(ss), 1e-12f);
    }
  }
}

// ---------------- token max ----------------
__global__ __launch_bounds__(256) void k_token(
    const int* __restrict__ text_mask,
    const int* __restrict__ R, const int* __restrict__ spoff,
    const int* __restrict__ meta, const float* __restrict__ scores,
    float* __restrict__ out)
{
  int idx = blockIdx.x * 256 + threadIdx.x;  // B*S
  int s = idx % S_, b = idx / S_;
  if (!text_mask[b * S_ + s]) { out[idx] = -INFINITY; return; }
  int n = meta[1];
  int r1 = R[s];
  int le = r1 - 1;                         // largest i with pos[i] <= s
  int ge = text_mask[s] ? (r1 - 1) : r1;   // smallest j with pos[j] >= s (row 0)
  float best = -INFINITY;
  if (le >= 0 && ge < n) {
    int i0 = max(0, ge - (L_ - 1));
    for (int i = i0; i <= le; i++) {
      int jmax = min(i + L_ - 1, n - 1);
      int off = spoff[i];
      for (int j = max(i, ge); j <= jmax; j++)
        best = fmaxf(best, scores[b * NPAD + off + (j - i)]);
    }
  }
  out[idx] = best;
}

// ---------------- ws-too-small sentinel ----------------
__global__ __launch_bounds__(256) void k_sentinel(float* __restrict__ out) {
  int i = blockIdx.x * 256 + threadIdx.x;
  if (i < BS) out[i] = 12345.0f;
}

// ---------------- launch ----------------
extern "C" void kernel_launch(void* const* d_in, const int* in_sizes, int n_in,
                              void* d_out, int out_size, void* d_ws, size_t ws_size,
                              hipStream_t stream) {
  const float* hid = (const float*)d_in[0];
  const float* th  = (const float*)d_in[1];
  const int* tmask = (const int*)d_in[2];
  const int* xmask = (const int*)d_in[3];
  const float* lemb = (const float*)d_in[4];
  const float* W1   = (const float*)d_in[5];
  const float* b1   = (const float*)d_in[6];
  const float* W2   = (const float*)d_in[7];
  const float* b2   = (const float*)d_in[8];
  float* out = (float*)d_out;

  char* w = (char*)d_ws;
  auto alloc = [&](size_t bytes) {
    char* p = w; w += (bytes + 255) & ~(size_t)255; return p;
  };
  // small buffers (~10 MB)
  bf16s* wbt   = (bf16s*)alloc((size_t)N3 * H_ * 2);
  bf16s* w2t   = (bf16s*)alloc((size_t)H_ * H_ * 2);
  bf16s* w2c   = (bf16s*)alloc((size_t)H_ * H_ * 2);
  float* LT    = (float*)alloc((size_t)(L_ + 1) * H_ * 4);
  bf16s* topn  = (bf16s*)alloc((size_t)B_ * T_ * H_ * 2);
  bf16s* U     = (bf16s*)alloc((size_t)B_ * T_ * H_ * 2);
  float* cvec  = (float*)alloc((size_t)B_ * T_ * 4);
  float* ssbuf = (float*)alloc((size_t)BNR * 4);
  float* scores= (float*)alloc((size_t)B_ * NPAD * 4);
  int* R       = (int*)alloc(S_ * 4);
  int* pos     = (int*)alloc(S_ * 4);
  int* spoff   = (int*)alloc(S_ * 4);
  int* starts  = (int*)alloc(NPAD * 4);
  int* ends    = (int*)alloc(NPAD * 4);
  int* lens    = (int*)alloc(NPAD * 4);
  int* meta    = (int*)alloc(2 * 4);
  // region A: [hidb | P] (100.66 MB)
  char* regionA = alloc((size_t)BS * H_ * 2 + (size_t)BS * N3 * 2);
  bf16s* hidb  = (bf16s*)regionA;
  bf16s* P     = (bf16s*)(regionA + (size_t)BS * H_ * 2);
  // region B: X (100.66 MB)
  bf16s* X     = (bf16s*)alloc((size_t)BNR * H_ * 2);

  size_t required = (size_t)(w - (char*)d_ws);
  if (required > ws_size) {
    k_sentinel<<<(BS + 255) / 256, 256, 0, stream>>>(out);
    return;
  }

  k_build_spans<<<1, 1024, 0, stream>>>(xmask, R, pos, spoff, starts, ends, lens, meta);
  k_prep<<<14479, 256, 0, stream>>>(hid, hidb, W1, wbt, W2, w2t, w2c,
                                    lemb, LT, th, b2, topn, cvec);

  // GEMM1 (576 P-tiles) + U-GEMM (12 tiles) over 512 blocks, <=2 items each
  k_gemm8p<<<512, 512, 0, stream>>>(hidb, wbt, P, topn, w2c, U);

  k_z1<<<BS + 512, 192, 0, stream>>>(P, LT, b1, pos, spoff, meta, X);

  // norm-only GEMM2 chained over all 768 cols: ssbuf = rowwise ||X@W2^T + b2||^2
  k_gemmnorm<<<256, 512, 0, stream>>>(X, w2t, b2, ssbuf);

  k_simx<<<dim3(NPAD / 64, B_), 256, 0, stream>>>(X, U, cvec, ssbuf, tmask, scores);
  k_token<<<(B_ * S_) / 256, 256, 0, stream>>>(xmask, R, spoff, meta, scores, out);
  (void)in_sizes; (void)n_in; (void)out_size;
}